// Round 8
// baseline (1830.129 us; speedup 1.0000x reference)
//
#include <hip/hip_runtime.h>
#include <hip/hip_fp16.h>
#include <math.h>

#define HDIM 128

typedef _Float16 f16x8 __attribute__((ext_vector_type(8)));
typedef float f32x4 __attribute__((ext_vector_type(4)));

struct alignas(8) half4 { __half2 lo, hi; };

__device__ __forceinline__ float4 h4_to_f4(half4 h) {
    float2 a = __half22float2(h.lo), b = __half22float2(h.hi);
    return make_float4(a.x, a.y, b.x, b.y);
}
__device__ __forceinline__ half4 f4_to_h4(float4 f) {
    half4 h;
    h.lo = __float22half2_rn(make_float2(f.x, f.y));
    h.hi = __float22half2_rn(make_float2(f.z, f.w));
    return h;
}
// nontemporal 8-byte edge load: (src, weight_bits)
__device__ __forceinline__ int2 ld_nt_int2(const int2* p) {
    long long v = __builtin_nontemporal_load((const long long*)p);
    int2 r; r.x = (int)(v & 0xffffffffLL); r.y = (int)(v >> 32); return r;
}

// ---------------- degree / CSR build ----------------

__global__ void degs_kernel(const int* __restrict__ src, const int* __restrict__ dst,
                            int* __restrict__ degS, int* __restrict__ degD, int E) {
    int e = blockIdx.x * blockDim.x + threadIdx.x;
    if (e < E) {
        atomicAdd(&degS[src[e]], 1);
        atomicAdd(&degD[dst[e]], 1);
    }
}

__global__ void dinv_kernel(const int* __restrict__ degS, float* __restrict__ dinv, int N) {
    int i = blockIdx.x * blockDim.x + threadIdx.x;
    if (i < N) { int d = degS[i]; dinv[i] = d > 0 ? rsqrtf((float)d) : 0.f; }
}

// single-block exclusive scan of degD -> rp[0..N], rp[N] = E
__global__ __launch_bounds__(1024)
void scan_kernel(const int* __restrict__ deg, int* __restrict__ rp, int N) {
    __shared__ int part[1024];
    int tid = threadIdx.x;
    int chunk = (N + 1023) / 1024;
    int start = tid * chunk;
    int end = start + chunk; if (end > N) end = N;
    int s = 0;
    for (int i = start; i < end; ++i) s += deg[i];
    part[tid] = s;
    __syncthreads();
    for (int off = 1; off < 1024; off <<= 1) {
        int v = (tid >= off) ? part[tid - off] : 0;
        __syncthreads();
        part[tid] += v;
        __syncthreads();
    }
    int run = (tid == 0) ? 0 : part[tid - 1];
    for (int i = start; i < end; ++i) { rp[i] = run; run += deg[i]; }
    if (start < N && end == N) rp[N] = run;
}

__global__ void scatter_kernel(const int* __restrict__ src, const int* __restrict__ dst,
                               const float* __restrict__ dinv, const int* __restrict__ rp,
                               int* __restrict__ cursor, int2* __restrict__ ev, int E) {
    int e = blockIdx.x * blockDim.x + threadIdx.x;
    if (e >= E) return;
    int s = src[e], d = dst[e];
    float w = -dinv[s] * dinv[d];
    int pos = atomicAdd(&cursor[d], 1);
    ev[rp[d] + pos] = make_int2(s, __float_as_int(w));
}

// ---------------- pull propagation, channel-chunked for XCD-L2 residency ---
// fp16 tables are chunk-major: tbl[(chunk*N + node)*16 + c], chunk = 0..7.
// chunk = blockIdx & 7  -> one chunk per XCD (round-robin dispatch heuristic):
// per-chunk table = N*16*2B = 1.6 MB -> fits 4 MB XCD L2 (in + out = 3.2 MB).
// Per wave: one node, 16 edges in flight (4 lanes/edge, 4 ch each).
template <int GBN, int PBN>
__global__ __launch_bounds__(256)
void pull16(const __half* __restrict__ tbl, const int* __restrict__ rp,
            const int2* __restrict__ ev, const __half* __restrict__ prev,
            const float* __restrict__ bnp, __half* __restrict__ outp,
            float alpha, int N) {
    int chunk = blockIdx.x & 7;
    int node = (blockIdx.x >> 3) * 4 + (threadIdx.x >> 6);
    if (node >= N) return;
    int lane = threadIdx.x & 63;
    int eg = lane >> 2;           // edge slot 0..15
    int c4 = (lane & 3) * 4;      // channel offset within chunk (0/4/8/12)
    const __half* tc = tbl + (size_t)chunk * N * 16;

    float4 sc = make_float4(1.f, 1.f, 1.f, 1.f);
    float4 sh = make_float4(0.f, 0.f, 0.f, 0.f);
    if (GBN || PBN) {
        sc = *(const float4*)(bnp + chunk * 16 + c4);
        sh = *(const float4*)(bnp + 128 + chunk * 16 + c4);
    }

    int b = rp[node], e = rp[node + 1];
    float4 acc = {0.f, 0.f, 0.f, 0.f};
    for (int j = b; j < e; j += 16) {
        int idx = j + eg;
        if (idx < e) {
            int2 s0 = ld_nt_int2(&ev[idx]);
            float w0 = __int_as_float(s0.y);
            float4 r0 = h4_to_f4(*(const half4*)(tc + (size_t)s0.x * 16 + c4));
            if (GBN) {
                r0.x = r0.x * sc.x + sh.x; r0.y = r0.y * sc.y + sh.y;
                r0.z = r0.z * sc.z + sh.z; r0.w = r0.w * sc.w + sh.w;
            }
            acc.x += w0 * r0.x; acc.y += w0 * r0.y;
            acc.z += w0 * r0.z; acc.w += w0 * r0.w;
        }
    }
    // reduce across the 16 edge slots (lane bits 2..5)
#pragma unroll
    for (int mask = 4; mask <= 32; mask <<= 1) {
        acc.x += __shfl_xor(acc.x, mask);
        acc.y += __shfl_xor(acc.y, mask);
        acc.z += __shfl_xor(acc.z, mask);
        acc.w += __shfl_xor(acc.w, mask);
    }
    if (lane < 4) {
        size_t o = ((size_t)chunk * N + node) * 16 + c4;
        float4 r;
        r.x = alpha * acc.x; r.y = alpha * acc.y;
        r.z = alpha * acc.z; r.w = alpha * acc.w;
        if (!GBN) {
            float4 pv = h4_to_f4(*(const half4*)(prev + o));
            if (PBN) {
                pv.x = pv.x * sc.x + sh.x; pv.y = pv.y * sc.y + sh.y;
                pv.z = pv.z * sc.z + sh.z; pv.w = pv.w * sc.w + sh.w;
            }
            r.x -= pv.x; r.y -= pv.y; r.z -= pv.z; r.w -= pv.w;
        }
        *(half4*)(outp + o) = f4_to_h4(r);
    }
}

__global__ void pull3(const float* __restrict__ t, const float* __restrict__ prev,
                      const int* __restrict__ rp, const int2* __restrict__ ev,
                      float* __restrict__ outp, float alpha, int N) {
    int node = blockIdx.x * blockDim.x + threadIdx.x;
    if (node >= N) return;
    int b = rp[node], e = rp[node + 1];
    float a0 = 0.f, a1 = 0.f, a2 = 0.f;
    for (int j = b; j < e; ++j) {
        int2 sw = ev[j];
        float w = __int_as_float(sw.y);
        const float* r = t + (size_t)sw.x * 3;
        a0 += w * r[0]; a1 += w * r[1]; a2 += w * r[2];
    }
    float r0 = alpha * a0, r1 = alpha * a1, r2 = alpha * a2;
    if (prev) {
        r0 -= prev[node * 3 + 0];
        r1 -= prev[node * 3 + 1];
        r2 -= prev[node * 3 + 2];
    }
    outp[node * 3 + 0] = r0;
    outp[node * 3 + 1] = r1;
    outp[node * 3 + 2] = r2;
}

// ---------------- weight prep: fold BN(T0) into W, transpose, fp16 --------
__global__ void wprep_kernel(const float* __restrict__ W, const float* __restrict__ bnp,
                             _Float16* __restrict__ Wt) {
    int idx = blockIdx.x * 256 + threadIdx.x;   // 65536
    int n = idx >> 9, sk = idx & 511;
    int sel = sk >> 7, k = sk & 127;
    float v = W[sel * 16384 + k * 128 + n];
    if (sel == 0) v *= bnp[k];
    Wt[idx] = (_Float16)v;
}

// bias2[n] = b[n] + sum_k bnp_shift[k] * W[0][k][n]
__global__ void bias2_kernel(const float* __restrict__ W, const float* __restrict__ bnp,
                             const float* __restrict__ b, float* __restrict__ bias2) {
    int n = threadIdx.x;
    float s = b[n];
    for (int k = 0; k < 128; ++k) s += bnp[128 + k] * W[k * 128 + n];
    bias2[n] = s;
}

// ---------------- MFMA Cheb GEMM (chunk-major fp16 A tables) ---------------
// A element (row r, channel k) at T[((k>>4)*N + r)*16 + (k&15)].
// Per kt: batch 8 A-loads + 16 B-frags, then 32 MFMAs.
template <int ACT, int STATS, int OUTH>
__global__ __launch_bounds__(256)
void gemm_mfma(const __half* __restrict__ T0, const __half* __restrict__ T1,
               const __half* __restrict__ T2, const __half* __restrict__ T3,
               const _Float16* __restrict__ Wt, const float* __restrict__ bias2,
               __half* __restrict__ outh, float* __restrict__ outf,
               float* __restrict__ stats, int N) {
    __shared__ float s_sum[128];
    __shared__ float s_sq[128];
    int tid = threadIdx.x;
    if (STATS) {
        if (tid < 128) { s_sum[tid] = 0.f; s_sq[tid] = 0.f; }
        __syncthreads();
    }
    int wave = tid >> 6, lane = tid & 63;
    int wr = wave >> 1, wc = wave & 1;
    int m = lane & 15, quad = lane >> 4;
    int row0 = blockIdx.x * 64 + wr * 32;

    int r0m = min(row0 + m, N - 1);
    int r1m = min(row0 + 16 + m, N - 1);

    const __half* Ts[4] = {T0, T1, T2, T3};
    f32x4 acc[2][4];
#pragma unroll
    for (int rt = 0; rt < 2; ++rt)
#pragma unroll
        for (int ct = 0; ct < 4; ++ct) acc[rt][ct] = (f32x4){0.f, 0.f, 0.f, 0.f};

    const _Float16* Wn = Wt + (size_t)(wc * 64 + m) * 512;   // row n = wc*64+ct*16+m

#pragma unroll
    for (int kt = 0; kt < 4; ++kt) {
        int ch = kt * 2 + (quad >> 1);      // 16-ch chunk 0..7
        int off = (quad & 1) * 8;           // within-chunk offset
        int ko = kt * 32 + quad * 8;        // flat k (for B)
        size_t ba0 = ((size_t)ch * N + r0m) * 16 + off;
        size_t ba1 = ((size_t)ch * N + r1m) * 16 + off;
        f16x8 a0[4], a1[4];
#pragma unroll
        for (int sel = 0; sel < 4; ++sel) {
            const _Float16* Tp = (const _Float16*)Ts[sel];
            a0[sel] = *(const f16x8*)(Tp + ba0);
            a1[sel] = *(const f16x8*)(Tp + ba1);
        }
        f16x8 bf[4][4];
#pragma unroll
        for (int sel = 0; sel < 4; ++sel) {
            const _Float16* Wb = Wn + sel * 128 + ko;
#pragma unroll
            for (int ct = 0; ct < 4; ++ct)
                bf[sel][ct] = *(const f16x8*)(Wb + (size_t)ct * 16 * 512);
        }
#pragma unroll
        for (int sel = 0; sel < 4; ++sel) {
#pragma unroll
            for (int ct = 0; ct < 4; ++ct) {
                acc[0][ct] = __builtin_amdgcn_mfma_f32_16x16x32_f16(a0[sel], bf[sel][ct], acc[0][ct], 0, 0, 0);
                acc[1][ct] = __builtin_amdgcn_mfma_f32_16x16x32_f16(a1[sel], bf[sel][ct], acc[1][ct], 0, 0, 0);
            }
        }
    }

    // epilogue: D tile (rt,ct): row = row0 + rt*16 + quad*4 + r, col = wc*64 + ct*16 + m
    float csum[4] = {}, csq[4] = {};
#pragma unroll
    for (int ct = 0; ct < 4; ++ct) {
        int col = wc * 64 + ct * 16 + m;
        int cch = wc * 4 + ct;              // 16-ch chunk of this col tile
        float bv = bias2[col];
#pragma unroll
        for (int rt = 0; rt < 2; ++rt) {
#pragma unroll
            for (int r = 0; r < 4; ++r) {
                int drow = row0 + rt * 16 + quad * 4 + r;
                if (drow < N) {
                    float v = acc[rt][ct][r] + bv;
                    if (ACT == 1) v = v >= 0.f ? v : 0.01f * v;
                    else if (ACT == 2) v = fmaxf(v, 0.f);
                    if (OUTH) outh[((size_t)cch * N + drow) * 16 + m] = __float2half(v);
                    else      outf[(size_t)drow * HDIM + col] = v;
                    if (STATS) { csum[ct] += v; csq[ct] += v * v; }
                }
            }
        }
    }
    if (STATS) {
#pragma unroll
        for (int ct = 0; ct < 4; ++ct) {
            int col = wc * 64 + ct * 16 + m;
            atomicAdd(&s_sum[col], csum[ct]);
            atomicAdd(&s_sq[col], csq[ct]);
        }
        __syncthreads();
        if (tid < 128) {
            atomicAdd(&stats[tid], s_sum[tid]);
            atomicAdd(&stats[128 + tid], s_sq[tid]);
        }
    }
}

// ---------------- layer-1 (input dim 3) fused GEMM, grid-stride ----------------
// writes Za chunk-major fp16
__global__ __launch_bounds__(256)
void gemm1_kernel(const float* __restrict__ x, const float* __restrict__ t1,
                  const float* __restrict__ t2, const float* __restrict__ t3,
                  const float* __restrict__ W1, const float* __restrict__ b1,
                  __half* __restrict__ out, float* __restrict__ stats, int N) {
    __shared__ float s_sum[128];
    __shared__ float s_sq[128];
    int tid = threadIdx.x;
    int c = tid & 127;
    if (tid < 128) { s_sum[tid] = 0.f; s_sq[tid] = 0.f; }
    __syncthreads();
    float wreg[12];
#pragma unroll
    for (int i = 0; i < 12; ++i) wreg[i] = W1[i * 128 + c];
    float bias = b1[c];
    const float* Ts[4] = {x, t1, t2, t3};
    float lsum = 0.f, lsq = 0.f;
    size_t cbase = ((size_t)(c >> 4)) * N * 16 + (c & 15);
    for (int row = blockIdx.x * 2 + (tid >> 7); row < N; row += gridDim.x * 2) {
        float v = bias;
#pragma unroll
        for (int k = 0; k < 4; ++k) {
            const float* t = Ts[k];
#pragma unroll
            for (int d = 0; d < 3; ++d)
                v += t[row * 3 + d] * wreg[k * 3 + d];
        }
        v = v >= 0.f ? v : 0.01f * v;   // leaky_relu
        out[cbase + (size_t)row * 16] = __float2half(v);
        lsum += v; lsq += v * v;
    }
    atomicAdd(&s_sum[c], lsum);
    atomicAdd(&s_sq[c], lsq);
    __syncthreads();
    if (tid < 128) {
        atomicAdd(&stats[tid], s_sum[tid]);
        atomicAdd(&stats[128 + tid], s_sq[tid]);
    }
}

// ---------------- BN finalize: stats -> (scale, shift) ----------------
__global__ void bnfin_kernel(const float* __restrict__ stats, const float* __restrict__ g,
                             const float* __restrict__ be, float* __restrict__ bnp, float invN) {
    int c = threadIdx.x;  // 128 threads
    float m = stats[c] * invN;
    float v = stats[128 + c] * invN - m * m;
    float sc = g[c] * rsqrtf(v + 1e-5f);
    bnp[c] = sc;
    bnp[128 + c] = be[c] - m * sc;
}

// ---------------- final: L2-normalize row + project to 3 ----------------
__global__ void final_kernel(const float* __restrict__ Z, const float* __restrict__ Wm,
                             const float* __restrict__ bm, float* __restrict__ out, int N) {
    int gid = blockIdx.x * blockDim.x + threadIdx.x;
    int node = gid >> 6;
    int lane = threadIdx.x & 63;
    if (node >= N) return;
    const float* z = Z + (size_t)node * HDIM;
    float z0 = z[lane], z1 = z[lane + 64];
    float sq = z0 * z0 + z1 * z1;
    float d0 = z0 * Wm[lane * 3 + 0] + z1 * Wm[(lane + 64) * 3 + 0];
    float d1 = z0 * Wm[lane * 3 + 1] + z1 * Wm[(lane + 64) * 3 + 1];
    float d2 = z0 * Wm[lane * 3 + 2] + z1 * Wm[(lane + 64) * 3 + 2];
#pragma unroll
    for (int off = 32; off > 0; off >>= 1) {
        sq += __shfl_down(sq, off);
        d0 += __shfl_down(d0, off);
        d1 += __shfl_down(d1, off);
        d2 += __shfl_down(d2, off);
    }
    if (lane == 0) {
        float inv = 1.f / fmaxf(sqrtf(sq), 1e-12f);
        out[node * 3 + 0] = d0 * inv + bm[0];
        out[node * 3 + 1] = d1 * inv + bm[1];
        out[node * 3 + 2] = d2 * inv + bm[2];
    }
}

// ---------------- host ----------------

extern "C" void kernel_launch(void* const* d_in, const int* in_sizes, int n_in,
                              void* d_out, int out_size, void* d_ws, size_t ws_size,
                              hipStream_t stream) {
    const float* x  = (const float*)d_in[0];
    const int*   ei = (const int*)d_in[1];
    const float* W1 = (const float*)d_in[2];
    const float* b1 = (const float*)d_in[3];
    const float* W2 = (const float*)d_in[4];
    const float* b2 = (const float*)d_in[5];
    const float* W3 = (const float*)d_in[6];
    const float* b3 = (const float*)d_in[7];
    const float* W4 = (const float*)d_in[8];
    const float* b4 = (const float*)d_in[9];
    const float* g1 = (const float*)d_in[10];
    const float* be1 = (const float*)d_in[11];
    const float* g2 = (const float*)d_in[12];
    const float* be2 = (const float*)d_in[13];
    const float* g3 = (const float*)d_in[14];
    const float* be3 = (const float*)d_in[15];
    const float* Wm = (const float*)d_in[16];
    const float* bm = (const float*)d_in[17];
    float* out = (float*)d_out;

    const int N = in_sizes[0] / 3;
    const int E = in_sizes[1] / 2;
    const size_t NH = (size_t)N * HDIM;
    const int* src = ei;
    const int* dst = ei + E;

    // ---- workspace layout ----
    char* base = (char*)d_ws;
    int* degS   = (int*)base;            base += (size_t)N * 4;
    int* degD   = (int*)base;            base += (size_t)N * 4;
    int* cursor = (int*)base;            base += (size_t)N * 4;
    int* rp     = (int*)base;            base += (size_t)(N + 2) * 4;
    int2* ev    = (int2*)base;           base += (size_t)E * 8;
    float* dinv = (float*)base;          base += (size_t)N * 4;
    __half* Za  = (__half*)base;         base += NH * 2;
    __half* Zb  = (__half*)base;         base += NH * 2;
    __half* T1  = (__half*)base;         base += NH * 2;
    __half* T2  = (__half*)base;         base += NH * 2;
    __half* T3  = (__half*)base;         base += NH * 2;
    float* Zf   = (float*)base;          base += NH * 4;   // layer-4 out, fp32 plain
    float* x1   = (float*)base;          base += (size_t)N * 3 * 4;
    float* x2   = (float*)base;          base += (size_t)N * 3 * 4;
    float* x3   = (float*)base;          base += (size_t)N * 3 * 4;
    float* stats = (float*)base;         base += 256 * 4;
    float* bnp1  = (float*)base;         base += 256 * 4;
    float* bnp2  = (float*)base;         base += 256 * 4;
    float* bnp3  = (float*)base;         base += 256 * 4;
    _Float16* Wt = (_Float16*)base;      base += (size_t)65536 * 2;
    float* bias2 = (float*)base;         base += 128 * 4;

    const int EB = (E + 255) / 256;
    const int NB = (N + 255) / 256;
    const int GB = (N + 63) / 64;         // mfma gemm row tiles
    const int PB8 = ((N + 3) / 4) * 8;    // pull16 blocks (4 nodes x 8 chunks)
    const float invN = 1.f / (float)N;

    // --- CSR build + edge weights ---
    hipMemsetAsync(degS, 0, (size_t)N * 3 * 4, stream);   // degS, degD, cursor
    degs_kernel<<<EB, 256, 0, stream>>>(src, dst, degS, degD, E);
    dinv_kernel<<<NB, 256, 0, stream>>>(degS, dinv, N);
    scan_kernel<<<1, 1024, 0, stream>>>(degD, rp, N);
    scatter_kernel<<<EB, 256, 0, stream>>>(src, dst, dinv, rp, cursor, ev, E);

    // --- layer 1 (dim 3) -> Za (fp16 chunk-major), bnp1 ---
    pull3<<<NB, 256, 0, stream>>>(x,  nullptr, rp, ev, x1, 1.f, N);
    pull3<<<NB, 256, 0, stream>>>(x1, x,       rp, ev, x2, 2.f, N);
    pull3<<<NB, 256, 0, stream>>>(x2, x1,      rp, ev, x3, 2.f, N);
    hipMemsetAsync(stats, 0, 256 * 4, stream);
    gemm1_kernel<<<512, 256, 0, stream>>>(x, x1, x2, x3, W1, b1, Za, stats, N);
    bnfin_kernel<<<1, 128, 0, stream>>>(stats, g1, be1, bnp1, invN);

    // --- layer 2 (leaky + BN): input BN(Za,bnp1) -> Zb, bnp2 ---
    wprep_kernel<<<256, 256, 0, stream>>>(W2, bnp1, Wt);
    bias2_kernel<<<1, 128, 0, stream>>>(W2, bnp1, b2, bias2);
    pull16<1, 0><<<PB8, 256, 0, stream>>>(Za, rp, ev, nullptr, bnp1, T1, 1.f, N);
    pull16<0, 1><<<PB8, 256, 0, stream>>>(T1, rp, ev, Za, bnp1, T2, 2.f, N);
    pull16<0, 0><<<PB8, 256, 0, stream>>>(T2, rp, ev, T1, nullptr, T3, 2.f, N);
    hipMemsetAsync(stats, 0, 256 * 4, stream);
    gemm_mfma<1, 1, 1><<<GB, 256, 0, stream>>>(Za, T1, T2, T3, Wt, bias2, Zb, nullptr, stats, N);
    bnfin_kernel<<<1, 128, 0, stream>>>(stats, g2, be2, bnp2, invN);

    // --- layer 3 (relu + BN): input BN(Zb,bnp2) -> Za, bnp3 ---
    wprep_kernel<<<256, 256, 0, stream>>>(W3, bnp2, Wt);
    bias2_kernel<<<1, 128, 0, stream>>>(W3, bnp2, b3, bias2);
    pull16<1, 0><<<PB8, 256, 0, stream>>>(Zb, rp, ev, nullptr, bnp2, T1, 1.f, N);
    pull16<0, 1><<<PB8, 256, 0, stream>>>(T1, rp, ev, Zb, bnp2, T2, 2.f, N);
    pull16<0, 0><<<PB8, 256, 0, stream>>>(T2, rp, ev, T1, nullptr, T3, 2.f, N);
    hipMemsetAsync(stats, 0, 256 * 4, stream);
    gemm_mfma<2, 1, 1><<<GB, 256, 0, stream>>>(Zb, T1, T2, T3, Wt, bias2, Za, nullptr, stats, N);
    bnfin_kernel<<<1, 128, 0, stream>>>(stats, g3, be3, bnp3, invN);

    // --- layer 4 (no act/BN): input BN(Za,bnp3) -> Zf (fp32 plain) ---
    wprep_kernel<<<256, 256, 0, stream>>>(W4, bnp3, Wt);
    bias2_kernel<<<1, 128, 0, stream>>>(W4, bnp3, b4, bias2);
    pull16<1, 0><<<PB8, 256, 0, stream>>>(Za, rp, ev, nullptr, bnp3, T1, 1.f, N);
    pull16<0, 1><<<PB8, 256, 0, stream>>>(T1, rp, ev, Za, bnp3, T2, 2.f, N);
    pull16<0, 0><<<PB8, 256, 0, stream>>>(T2, rp, ev, T1, nullptr, T3, 2.f, N);
    gemm_mfma<0, 0, 0><<<GB, 256, 0, stream>>>(Za, T1, T2, T3, Wt, bias2, nullptr, Zf, nullptr, N);

    // --- normalize + project ---
    final_kernel<<<(N * 64 + 255) / 256, 256, 0, stream>>>(Zf, Wm, bm, out, N);
}

// Round 9
// 1819.094 us; speedup vs baseline: 1.0061x; 1.0061x over previous
//
#include <hip/hip_runtime.h>
#include <hip/hip_fp16.h>
#include <math.h>

#define HDIM 128

typedef _Float16 f16x8 __attribute__((ext_vector_type(8)));
typedef float f32x4 __attribute__((ext_vector_type(4)));

// nontemporal 8-byte edge load: (src, weight_bits)
__device__ __forceinline__ int2 ld_nt_int2(const int2* p) {
    long long v = __builtin_nontemporal_load((const long long*)p);
    int2 r; r.x = (int)(v & 0xffffffffLL); r.y = (int)(v >> 32); return r;
}

// ---------------- degree / CSR build ----------------

__global__ void degs_kernel(const int* __restrict__ src, const int* __restrict__ dst,
                            int* __restrict__ degS, int* __restrict__ degD, int E) {
    int e = blockIdx.x * blockDim.x + threadIdx.x;
    if (e < E) {
        atomicAdd(&degS[src[e]], 1);
        atomicAdd(&degD[dst[e]], 1);
    }
}

__global__ void dinv_kernel(const int* __restrict__ degS, float* __restrict__ dinv, int N) {
    int i = blockIdx.x * blockDim.x + threadIdx.x;
    if (i < N) { int d = degS[i]; dinv[i] = d > 0 ? rsqrtf((float)d) : 0.f; }
}

// single-block exclusive scan of degD -> rp[0..N], rp[N] = E
__global__ __launch_bounds__(1024)
void scan_kernel(const int* __restrict__ deg, int* __restrict__ rp, int N) {
    __shared__ int part[1024];
    int tid = threadIdx.x;
    int chunk = (N + 1023) / 1024;
    int start = tid * chunk;
    int end = start + chunk; if (end > N) end = N;
    int s = 0;
    for (int i = start; i < end; ++i) s += deg[i];
    part[tid] = s;
    __syncthreads();
    for (int off = 1; off < 1024; off <<= 1) {
        int v = (tid >= off) ? part[tid - off] : 0;
        __syncthreads();
        part[tid] += v;
        __syncthreads();
    }
    int run = (tid == 0) ? 0 : part[tid - 1];
    for (int i = start; i < end; ++i) { rp[i] = run; run += deg[i]; }
    if (start < N && end == N) rp[N] = run;
}

__global__ void scatter_kernel(const int* __restrict__ src, const int* __restrict__ dst,
                               const float* __restrict__ dinv, const int* __restrict__ rp,
                               int* __restrict__ cursor, int2* __restrict__ ev, int E) {
    int e = blockIdx.x * blockDim.x + threadIdx.x;
    if (e >= E) return;
    int s = src[e], d = dst[e];
    float w = -dinv[s] * dinv[d];
    int pos = atomicAdd(&cursor[d], 1);
    ev[rp[d] + pos] = make_int2(s, __float_as_int(w));
}

// ---------------- pull propagation, 32-ch chunks for XCD-L2 residency ------
// fp16 tables chunk-major: tbl[(chunk*N + node)*32 + c], chunk = 0..3.
// chunk = blockIdx & 3 (round-robin XCD heuristic); per-chunk table = 3.2 MB.
// Wave = 1 node; 16 lanes/edge (half2 = 2ch each), 4 edge slots, 2 chains.
// ev loads + prev loads + out stores are nontemporal (protect L2 table).
template <int GBN, int PBN>
__global__ __launch_bounds__(256)
void pull32(const __half* __restrict__ tbl, const int* __restrict__ rp,
            const int2* __restrict__ ev, const __half* __restrict__ prev,
            const float* __restrict__ bnp, __half* __restrict__ outp,
            float alpha, int N) {
    int chunk = blockIdx.x & 3;
    int node = (blockIdx.x >> 2) * 4 + (threadIdx.x >> 6);
    if (node >= N) return;
    int lane = threadIdx.x & 63;
    int eg = lane >> 4;            // edge slot 0..3
    int cpos = (lane & 15) * 2;    // channel pair within chunk
    const __half* tc = tbl + (size_t)chunk * N * 32;

    float2 sc = make_float2(1.f, 1.f), sh = make_float2(0.f, 0.f);
    if (GBN || PBN) {
        sc = *(const float2*)(bnp + chunk * 32 + cpos);
        sh = *(const float2*)(bnp + 128 + chunk * 32 + cpos);
    }

    int b = rp[node], e = rp[node + 1];
    float2 a0 = make_float2(0.f, 0.f), a1 = make_float2(0.f, 0.f);
    for (int j = b; j < e; j += 8) {
        int i0 = j + eg, i1 = j + 4 + eg;
        if (i0 < e) {
            int2 s0 = ld_nt_int2(&ev[i0]);
            float w0 = __int_as_float(s0.y);
            float2 r0 = __half22float2(*(const __half2*)(tc + (size_t)s0.x * 32 + cpos));
            if (GBN) { r0.x = r0.x * sc.x + sh.x; r0.y = r0.y * sc.y + sh.y; }
            a0.x += w0 * r0.x; a0.y += w0 * r0.y;
        }
        if (i1 < e) {
            int2 s1 = ld_nt_int2(&ev[i1]);
            float w1 = __int_as_float(s1.y);
            float2 r1 = __half22float2(*(const __half2*)(tc + (size_t)s1.x * 32 + cpos));
            if (GBN) { r1.x = r1.x * sc.x + sh.x; r1.y = r1.y * sc.y + sh.y; }
            a1.x += w1 * r1.x; a1.y += w1 * r1.y;
        }
    }
    float sx = a0.x + a1.x, sy = a0.y + a1.y;
    sx += __shfl_xor(sx, 16); sy += __shfl_xor(sy, 16);
    sx += __shfl_xor(sx, 32); sy += __shfl_xor(sy, 32);

    if (lane < 16) {
        size_t o = ((size_t)chunk * N + node) * 32 + cpos;
        float rx = alpha * sx, ry = alpha * sy;
        if (!GBN) {
            unsigned pu = __builtin_nontemporal_load((const unsigned*)(prev + o));
            __half2 ph = *(__half2*)&pu;
            float2 pv = __half22float2(ph);
            if (PBN) { pv.x = pv.x * sc.x + sh.x; pv.y = pv.y * sc.y + sh.y; }
            rx -= pv.x; ry -= pv.y;
        }
        __half2 h = __float22half2_rn(make_float2(rx, ry));
        __builtin_nontemporal_store(*(unsigned*)&h, (unsigned*)(outp + o));
    }
}

__global__ void pull3(const float* __restrict__ t, const float* __restrict__ prev,
                      const int* __restrict__ rp, const int2* __restrict__ ev,
                      float* __restrict__ outp, float alpha, int N) {
    int node = blockIdx.x * blockDim.x + threadIdx.x;
    if (node >= N) return;
    int b = rp[node], e = rp[node + 1];
    float a0 = 0.f, a1 = 0.f, a2 = 0.f;
    for (int j = b; j < e; ++j) {
        int2 sw = ev[j];
        float w = __int_as_float(sw.y);
        const float* r = t + (size_t)sw.x * 3;
        a0 += w * r[0]; a1 += w * r[1]; a2 += w * r[2];
    }
    float r0 = alpha * a0, r1 = alpha * a1, r2 = alpha * a2;
    if (prev) {
        r0 -= prev[node * 3 + 0];
        r1 -= prev[node * 3 + 1];
        r2 -= prev[node * 3 + 2];
    }
    outp[node * 3 + 0] = r0;
    outp[node * 3 + 1] = r1;
    outp[node * 3 + 2] = r2;
}

// ---------------- weight prep: fold BN(T0) into W, transpose, fp16 --------
__global__ void wprep_kernel(const float* __restrict__ W, const float* __restrict__ bnp,
                             _Float16* __restrict__ Wt) {
    int idx = blockIdx.x * 256 + threadIdx.x;   // 65536
    int n = idx >> 9, sk = idx & 511;
    int sel = sk >> 7, k = sk & 127;
    float v = W[sel * 16384 + k * 128 + n];
    if (sel == 0) v *= bnp[k];
    Wt[idx] = (_Float16)v;
}

// bias2[n] = b[n] + sum_k bnp_shift[k] * W[0][k][n]
__global__ void bias2_kernel(const float* __restrict__ W, const float* __restrict__ bnp,
                             const float* __restrict__ b, float* __restrict__ bias2) {
    int n = threadIdx.x;
    float s = b[n];
    for (int k = 0; k < 128; ++k) s += bnp[128 + k] * W[k * 128 + n];
    bias2[n] = s;
}

// ---------------- MFMA Cheb GEMM (32-ch chunk-major fp16 A tables) ---------
// A element (row r, ch k) at T[((k>>5)*N + r)*32 + (k&31)].
// Block = 32 rows x 128 cols; 4 waves 2x2 (wave = 16 rows x 64 cols).
// kt chunk == kt (32-ch chunks). A-loads batched per 2 kt (8 in flight).
template <int ACT, int STATS, int OUTH>
__global__ __launch_bounds__(256)
void gemm_mfma(const __half* __restrict__ T0, const __half* __restrict__ T1,
               const __half* __restrict__ T2, const __half* __restrict__ T3,
               const _Float16* __restrict__ Wt, const float* __restrict__ bias2,
               __half* __restrict__ outh, float* __restrict__ outf,
               float* __restrict__ stats, int N) {
    __shared__ float s_sum[128];
    __shared__ float s_sq[128];
    int tid = threadIdx.x;
    if (STATS) {
        if (tid < 128) { s_sum[tid] = 0.f; s_sq[tid] = 0.f; }
        __syncthreads();
    }
    int wave = tid >> 6, lane = tid & 63;
    int wr = wave >> 1, wc = wave & 1;
    int m = lane & 15, quad = lane >> 4;
    int row0 = blockIdx.x * 32 + wr * 16;

    int r0m = min(row0 + m, N - 1);

    const __half* Ts[4] = {T0, T1, T2, T3};
    f32x4 acc[4];
#pragma unroll
    for (int ct = 0; ct < 4; ++ct) acc[ct] = (f32x4){0.f, 0.f, 0.f, 0.f};

    const _Float16* Wn = Wt + (size_t)(wc * 64 + m) * 512;   // row n = wc*64+ct*16+m

#pragma unroll
    for (int ktp = 0; ktp < 2; ++ktp) {
        int kt0 = ktp * 2, kt1 = ktp * 2 + 1;
        f16x8 a0[4], a1[4];
        size_t ba0 = ((size_t)kt0 * N + r0m) * 32 + quad * 8;
        size_t ba1 = ((size_t)kt1 * N + r0m) * 32 + quad * 8;
#pragma unroll
        for (int sel = 0; sel < 4; ++sel) {
            const _Float16* Tp = (const _Float16*)Ts[sel];
            a0[sel] = *(const f16x8*)(Tp + ba0);
            a1[sel] = *(const f16x8*)(Tp + ba1);
        }
        int ko0 = kt0 * 32 + quad * 8;
        int ko1 = kt1 * 32 + quad * 8;
#pragma unroll
        for (int sel = 0; sel < 4; ++sel) {
            const _Float16* Wb0 = Wn + sel * 128 + ko0;
            const _Float16* Wb1 = Wn + sel * 128 + ko1;
#pragma unroll
            for (int ct = 0; ct < 4; ++ct) {
                f16x8 b0 = *(const f16x8*)(Wb0 + (size_t)ct * 16 * 512);
                f16x8 b1 = *(const f16x8*)(Wb1 + (size_t)ct * 16 * 512);
                acc[ct] = __builtin_amdgcn_mfma_f32_16x16x32_f16(a0[sel], b0, acc[ct], 0, 0, 0);
                acc[ct] = __builtin_amdgcn_mfma_f32_16x16x32_f16(a1[sel], b1, acc[ct], 0, 0, 0);
            }
        }
    }

    // epilogue: D tile ct: row = row0 + quad*4 + r, col = wc*64 + ct*16 + m
    float csum[4] = {}, csq[4] = {};
#pragma unroll
    for (int ct = 0; ct < 4; ++ct) {
        int col = wc * 64 + ct * 16 + m;
        int cch = wc * 2 + (ct >> 1);          // 32-ch chunk of this col
        int coff = (ct & 1) * 16 + m;          // offset within chunk
        float bv = bias2[col];
#pragma unroll
        for (int r = 0; r < 4; ++r) {
            int drow = row0 + quad * 4 + r;
            if (drow < N) {
                float v = acc[ct][r] + bv;
                if (ACT == 1) v = v >= 0.f ? v : 0.01f * v;
                else if (ACT == 2) v = fmaxf(v, 0.f);
                if (OUTH) outh[((size_t)cch * N + drow) * 32 + coff] = __float2half(v);
                else      outf[(size_t)drow * HDIM + col] = v;
                if (STATS) { csum[ct] += v; csq[ct] += v * v; }
            }
        }
    }
    if (STATS) {
#pragma unroll
        for (int ct = 0; ct < 4; ++ct) {
            int col = wc * 64 + ct * 16 + m;
            atomicAdd(&s_sum[col], csum[ct]);
            atomicAdd(&s_sq[col], csq[ct]);
        }
        __syncthreads();
        if (tid < 128) {
            atomicAdd(&stats[tid], s_sum[tid]);
            atomicAdd(&stats[128 + tid], s_sq[tid]);
        }
    }
}

// ---------------- layer-1 (input dim 3) fused GEMM, grid-stride ------------
// writes Za chunk-major (32-ch chunks) fp16
__global__ __launch_bounds__(256)
void gemm1_kernel(const float* __restrict__ x, const float* __restrict__ t1,
                  const float* __restrict__ t2, const float* __restrict__ t3,
                  const float* __restrict__ W1, const float* __restrict__ b1,
                  __half* __restrict__ out, float* __restrict__ stats, int N) {
    __shared__ float s_sum[128];
    __shared__ float s_sq[128];
    int tid = threadIdx.x;
    int c = tid & 127;
    if (tid < 128) { s_sum[tid] = 0.f; s_sq[tid] = 0.f; }
    __syncthreads();
    float wreg[12];
#pragma unroll
    for (int i = 0; i < 12; ++i) wreg[i] = W1[i * 128 + c];
    float bias = b1[c];
    const float* Ts[4] = {x, t1, t2, t3};
    float lsum = 0.f, lsq = 0.f;
    size_t cbase = ((size_t)(c >> 5)) * N * 32 + (c & 31);
    for (int row = blockIdx.x * 2 + (tid >> 7); row < N; row += gridDim.x * 2) {
        float v = bias;
#pragma unroll
        for (int k = 0; k < 4; ++k) {
            const float* t = Ts[k];
#pragma unroll
            for (int d = 0; d < 3; ++d)
                v += t[row * 3 + d] * wreg[k * 3 + d];
        }
        v = v >= 0.f ? v : 0.01f * v;   // leaky_relu
        out[cbase + (size_t)row * 32] = __float2half(v);
        lsum += v; lsq += v * v;
    }
    atomicAdd(&s_sum[c], lsum);
    atomicAdd(&s_sq[c], lsq);
    __syncthreads();
    if (tid < 128) {
        atomicAdd(&stats[tid], s_sum[tid]);
        atomicAdd(&stats[128 + tid], s_sq[tid]);
    }
}

// ---------------- BN finalize: stats -> (scale, shift) ----------------
__global__ void bnfin_kernel(const float* __restrict__ stats, const float* __restrict__ g,
                             const float* __restrict__ be, float* __restrict__ bnp, float invN) {
    int c = threadIdx.x;  // 128 threads
    float m = stats[c] * invN;
    float v = stats[128 + c] * invN - m * m;
    float sc = g[c] * rsqrtf(v + 1e-5f);
    bnp[c] = sc;
    bnp[128 + c] = be[c] - m * sc;
}

// ---------------- final: L2-normalize row + project to 3 ----------------
__global__ void final_kernel(const float* __restrict__ Z, const float* __restrict__ Wm,
                             const float* __restrict__ bm, float* __restrict__ out, int N) {
    int gid = blockIdx.x * blockDim.x + threadIdx.x;
    int node = gid >> 6;
    int lane = threadIdx.x & 63;
    if (node >= N) return;
    const float* z = Z + (size_t)node * HDIM;
    float z0 = z[lane], z1 = z[lane + 64];
    float sq = z0 * z0 + z1 * z1;
    float d0 = z0 * Wm[lane * 3 + 0] + z1 * Wm[(lane + 64) * 3 + 0];
    float d1 = z0 * Wm[lane * 3 + 1] + z1 * Wm[(lane + 64) * 3 + 1];
    float d2 = z0 * Wm[lane * 3 + 2] + z1 * Wm[(lane + 64) * 3 + 2];
#pragma unroll
    for (int off = 32; off > 0; off >>= 1) {
        sq += __shfl_down(sq, off);
        d0 += __shfl_down(d0, off);
        d1 += __shfl_down(d1, off);
        d2 += __shfl_down(d2, off);
    }
    if (lane == 0) {
        float inv = 1.f / fmaxf(sqrtf(sq), 1e-12f);
        out[node * 3 + 0] = d0 * inv + bm[0];
        out[node * 3 + 1] = d1 * inv + bm[1];
        out[node * 3 + 2] = d2 * inv + bm[2];
    }
}

// ---------------- host ----------------

extern "C" void kernel_launch(void* const* d_in, const int* in_sizes, int n_in,
                              void* d_out, int out_size, void* d_ws, size_t ws_size,
                              hipStream_t stream) {
    const float* x  = (const float*)d_in[0];
    const int*   ei = (const int*)d_in[1];
    const float* W1 = (const float*)d_in[2];
    const float* b1 = (const float*)d_in[3];
    const float* W2 = (const float*)d_in[4];
    const float* b2 = (const float*)d_in[5];
    const float* W3 = (const float*)d_in[6];
    const float* b3 = (const float*)d_in[7];
    const float* W4 = (const float*)d_in[8];
    const float* b4 = (const float*)d_in[9];
    const float* g1 = (const float*)d_in[10];
    const float* be1 = (const float*)d_in[11];
    const float* g2 = (const float*)d_in[12];
    const float* be2 = (const float*)d_in[13];
    const float* g3 = (const float*)d_in[14];
    const float* be3 = (const float*)d_in[15];
    const float* Wm = (const float*)d_in[16];
    const float* bm = (const float*)d_in[17];
    float* out = (float*)d_out;

    const int N = in_sizes[0] / 3;
    const int E = in_sizes[1] / 2;
    const size_t NH = (size_t)N * HDIM;
    const int* src = ei;
    const int* dst = ei + E;

    // ---- workspace layout ----
    char* base = (char*)d_ws;
    int* degS   = (int*)base;            base += (size_t)N * 4;
    int* degD   = (int*)base;            base += (size_t)N * 4;
    int* cursor = (int*)base;            base += (size_t)N * 4;
    int* rp     = (int*)base;            base += (size_t)(N + 2) * 4;
    int2* ev    = (int2*)base;           base += (size_t)E * 8;
    float* dinv = (float*)base;          base += (size_t)N * 4;
    __half* Za  = (__half*)base;         base += NH * 2;
    __half* Zb  = (__half*)base;         base += NH * 2;
    __half* T1  = (__half*)base;         base += NH * 2;
    __half* T2  = (__half*)base;         base += NH * 2;
    __half* T3  = (__half*)base;         base += NH * 2;
    float* Zf   = (float*)base;          base += NH * 4;   // layer-4 out, fp32 row-major
    float* x1   = (float*)base;          base += (size_t)N * 3 * 4;
    float* x2   = (float*)base;          base += (size_t)N * 3 * 4;
    float* x3   = (float*)base;          base += (size_t)N * 3 * 4;
    float* stats = (float*)base;         base += 256 * 4;
    float* bnp1  = (float*)base;         base += 256 * 4;
    float* bnp2  = (float*)base;         base += 256 * 4;
    float* bnp3  = (float*)base;         base += 256 * 4;
    _Float16* Wt = (_Float16*)base;      base += (size_t)65536 * 2;
    float* bias2 = (float*)base;         base += 128 * 4;

    const int EB = (E + 255) / 256;
    const int NB = (N + 255) / 256;
    const int GB = (N + 31) / 32;         // mfma gemm row tiles (32 rows)
    const int PB4 = ((N + 3) / 4) * 4;    // pull32 blocks (4 nodes x 4 chunks)
    const float invN = 1.f / (float)N;

    // --- CSR build + edge weights ---
    hipMemsetAsync(degS, 0, (size_t)N * 3 * 4, stream);   // degS, degD, cursor
    degs_kernel<<<EB, 256, 0, stream>>>(src, dst, degS, degD, E);
    dinv_kernel<<<NB, 256, 0, stream>>>(degS, dinv, N);
    scan_kernel<<<1, 1024, 0, stream>>>(degD, rp, N);
    scatter_kernel<<<EB, 256, 0, stream>>>(src, dst, dinv, rp, cursor, ev, E);

    // --- layer 1 (dim 3) -> Za (fp16 chunk-major), bnp1 ---
    pull3<<<NB, 256, 0, stream>>>(x,  nullptr, rp, ev, x1, 1.f, N);
    pull3<<<NB, 256, 0, stream>>>(x1, x,       rp, ev, x2, 2.f, N);
    pull3<<<NB, 256, 0, stream>>>(x2, x1,      rp, ev, x3, 2.f, N);
    hipMemsetAsync(stats, 0, 256 * 4, stream);
    gemm1_kernel<<<512, 256, 0, stream>>>(x, x1, x2, x3, W1, b1, Za, stats, N);
    bnfin_kernel<<<1, 128, 0, stream>>>(stats, g1, be1, bnp1, invN);

    // --- layer 2 (leaky + BN): input BN(Za,bnp1) -> Zb, bnp2 ---
    wprep_kernel<<<256, 256, 0, stream>>>(W2, bnp1, Wt);
    bias2_kernel<<<1, 128, 0, stream>>>(W2, bnp1, b2, bias2);
    pull32<1, 0><<<PB4, 256, 0, stream>>>(Za, rp, ev, nullptr, bnp1, T1, 1.f, N);
    pull32<0, 1><<<PB4, 256, 0, stream>>>(T1, rp, ev, Za, bnp1, T2, 2.f, N);
    pull32<0, 0><<<PB4, 256, 0, stream>>>(T2, rp, ev, T1, nullptr, T3, 2.f, N);
    hipMemsetAsync(stats, 0, 256 * 4, stream);
    gemm_mfma<1, 1, 1><<<GB, 256, 0, stream>>>(Za, T1, T2, T3, Wt, bias2, Zb, nullptr, stats, N);
    bnfin_kernel<<<1, 128, 0, stream>>>(stats, g2, be2, bnp2, invN);

    // --- layer 3 (relu + BN): input BN(Zb,bnp2) -> Za, bnp3 ---
    wprep_kernel<<<256, 256, 0, stream>>>(W3, bnp2, Wt);
    bias2_kernel<<<1, 128, 0, stream>>>(W3, bnp2, b3, bias2);
    pull32<1, 0><<<PB4, 256, 0, stream>>>(Zb, rp, ev, nullptr, bnp2, T1, 1.f, N);
    pull32<0, 1><<<PB4, 256, 0, stream>>>(T1, rp, ev, Zb, bnp2, T2, 2.f, N);
    pull32<0, 0><<<PB4, 256, 0, stream>>>(T2, rp, ev, T1, nullptr, T3, 2.f, N);
    hipMemsetAsync(stats, 0, 256 * 4, stream);
    gemm_mfma<2, 1, 1><<<GB, 256, 0, stream>>>(Zb, T1, T2, T3, Wt, bias2, Za, nullptr, stats, N);
    bnfin_kernel<<<1, 128, 0, stream>>>(stats, g3, be3, bnp3, invN);

    // --- layer 4 (no act/BN): input BN(Za,bnp3) -> Zf (fp32 row-major) ---
    wprep_kernel<<<256, 256, 0, stream>>>(W4, bnp3, Wt);
    bias2_kernel<<<1, 128, 0, stream>>>(W4, bnp3, b4, bias2);
    pull32<1, 0><<<PB4, 256, 0, stream>>>(Za, rp, ev, nullptr, bnp3, T1, 1.f, N);
    pull32<0, 1><<<PB4, 256, 0, stream>>>(T1, rp, ev, Za, bnp3, T2, 2.f, N);
    pull32<0, 0><<<PB4, 256, 0, stream>>>(T2, rp, ev, T1, nullptr, T3, 2.f, N);
    gemm_mfma<0, 0, 0><<<GB, 256, 0, stream>>>(Za, T1, T2, T3, Wt, bias2, nullptr, Zf, nullptr, N);

    // --- normalize + project ---
    final_kernel<<<(N * 64 + 255) / 256, 256, 0, stream>>>(Zf, Wm, bm, out, N);
}

// Round 10
// 1002.005 us; speedup vs baseline: 1.8265x; 1.8155x over previous
//
#include <hip/hip_runtime.h>
#include <hip/hip_fp16.h>
#include <math.h>

#define HDIM 128

typedef _Float16 f16x8 __attribute__((ext_vector_type(8)));
typedef float f32x4 __attribute__((ext_vector_type(4)));

// ---------------- degree / CSR build ----------------

__global__ void degs_kernel(const int* __restrict__ src, const int* __restrict__ dst,
                            int* __restrict__ degS, int* __restrict__ degD, int E) {
    int e = blockIdx.x * blockDim.x + threadIdx.x;
    if (e < E) {
        atomicAdd(&degS[src[e]], 1);
        atomicAdd(&degD[dst[e]], 1);
    }
}

__global__ void dinv_kernel(const int* __restrict__ degS, float* __restrict__ dinv, int N) {
    int i = blockIdx.x * blockDim.x + threadIdx.x;
    if (i < N) { int d = degS[i]; dinv[i] = d > 0 ? rsqrtf((float)d) : 0.f; }
}

// single-block exclusive scan of degD -> rp[0..N], rp[N] = E
__global__ __launch_bounds__(1024)
void scan_kernel(const int* __restrict__ deg, int* __restrict__ rp, int N) {
    __shared__ int part[1024];
    int tid = threadIdx.x;
    int chunk = (N + 1023) / 1024;
    int start = tid * chunk;
    int end = start + chunk; if (end > N) end = N;
    int s = 0;
    for (int i = start; i < end; ++i) s += deg[i];
    part[tid] = s;
    __syncthreads();
    for (int off = 1; off < 1024; off <<= 1) {
        int v = (tid >= off) ? part[tid - off] : 0;
        __syncthreads();
        part[tid] += v;
        __syncthreads();
    }
    int run = (tid == 0) ? 0 : part[tid - 1];
    for (int i = start; i < end; ++i) { rp[i] = run; run += deg[i]; }
    if (start < N && end == N) rp[N] = run;
}

__global__ void scatter_kernel(const int* __restrict__ src, const int* __restrict__ dst,
                               const float* __restrict__ dinv, const int* __restrict__ rp,
                               int* __restrict__ cursor, int2* __restrict__ ev, int E) {
    int e = blockIdx.x * blockDim.x + threadIdx.x;
    if (e >= E) return;
    int s = src[e], d = dst[e];
    float w = -dinv[s] * dinv[d];
    int pos = atomicAdd(&cursor[d], 1);
    ev[rp[d] + pos] = make_int2(s, __float_as_int(w));
}

// ---------------- pull propagation v2 (16B f16x8 gathers) -------------------
// out[i] = alpha * sum_e w * g(t[src]) - p(prev[i]); row-major fp16 tables.
// Wave = 1 node; 16 lanes/edge (8 ch each, 16 B), 4 edge slots x 2 chains
// = 8 gathers in flight, half the gather instructions of the 8B version.
template <int GBN, int PBN>
__global__ __launch_bounds__(256)
void pull128(const __half* __restrict__ t, const int* __restrict__ rp,
             const int2* __restrict__ ev, const __half* __restrict__ prev,
             const float* __restrict__ bnp, __half* __restrict__ outp,
             float alpha, int N) {
    int node = blockIdx.x * 4 + (threadIdx.x >> 6);
    if (node >= N) return;
    int lane = threadIdx.x & 63;
    int c8 = (lane & 15) * 8;     // 8-channel group
    int slot = lane >> 4;         // edge slot 0..3
    const _Float16* tp = (const _Float16*)t;

    float scv[8], shv[8];
    if (GBN || PBN) {
#pragma unroll
        for (int i = 0; i < 8; ++i) { scv[i] = bnp[c8 + i]; shv[i] = bnp[128 + c8 + i]; }
    }

    int b = rp[node], e = rp[node + 1];
    float acc0[8] = {}, acc1[8] = {};
    int j = b;
    for (; j + 8 <= e; j += 8) {
        int2 s0 = ev[j + slot];
        int2 s1 = ev[j + 4 + slot];
        f16x8 r0 = *(const f16x8*)(tp + (size_t)s0.x * HDIM + c8);
        f16x8 r1 = *(const f16x8*)(tp + (size_t)s1.x * HDIM + c8);
        float w0 = __int_as_float(s0.y), w1 = __int_as_float(s1.y);
#pragma unroll
        for (int i = 0; i < 8; ++i) {
            float v0 = (float)r0[i], v1 = (float)r1[i];
            if (GBN) { v0 = v0 * scv[i] + shv[i]; v1 = v1 * scv[i] + shv[i]; }
            acc0[i] += w0 * v0; acc1[i] += w1 * v1;
        }
    }
    for (; j < e; j += 4) {
        int idx = j + slot;
        if (idx < e) {
            int2 s0 = ev[idx];
            f16x8 r0 = *(const f16x8*)(tp + (size_t)s0.x * HDIM + c8);
            float w0 = __int_as_float(s0.y);
#pragma unroll
            for (int i = 0; i < 8; ++i) {
                float v0 = (float)r0[i];
                if (GBN) v0 = v0 * scv[i] + shv[i];
                acc0[i] += w0 * v0;
            }
        }
    }
    float s[8];
#pragma unroll
    for (int i = 0; i < 8; ++i) {
        s[i] = acc0[i] + acc1[i];
        s[i] += __shfl_xor(s[i], 16);
        s[i] += __shfl_xor(s[i], 32);
    }
    if (lane < 16) {
        size_t o = (size_t)node * HDIM + c8;
        float r[8];
#pragma unroll
        for (int i = 0; i < 8; ++i) r[i] = alpha * s[i];
        if (!GBN) {
            f16x8 pv = *(const f16x8*)((const _Float16*)prev + o);
#pragma unroll
            for (int i = 0; i < 8; ++i) {
                float p = (float)pv[i];
                if (PBN) p = p * scv[i] + shv[i];
                r[i] -= p;
            }
        }
        f16x8 h;
#pragma unroll
        for (int i = 0; i < 8; ++i) h[i] = (_Float16)r[i];
        *(f16x8*)((_Float16*)outp + o) = h;
    }
}

__global__ void pull3(const float* __restrict__ t, const float* __restrict__ prev,
                      const int* __restrict__ rp, const int2* __restrict__ ev,
                      float* __restrict__ outp, float alpha, int N) {
    int node = blockIdx.x * blockDim.x + threadIdx.x;
    if (node >= N) return;
    int b = rp[node], e = rp[node + 1];
    float a0 = 0.f, a1 = 0.f, a2 = 0.f;
    for (int j = b; j < e; ++j) {
        int2 sw = ev[j];
        float w = __int_as_float(sw.y);
        const float* r = t + (size_t)sw.x * 3;
        a0 += w * r[0]; a1 += w * r[1]; a2 += w * r[2];
    }
    float r0 = alpha * a0, r1 = alpha * a1, r2 = alpha * a2;
    if (prev) {
        r0 -= prev[node * 3 + 0];
        r1 -= prev[node * 3 + 1];
        r2 -= prev[node * 3 + 2];
    }
    outp[node * 3 + 0] = r0;
    outp[node * 3 + 1] = r1;
    outp[node * 3 + 2] = r2;
}

// ---------------- weight prep: fold BN(T0) into W, transpose, fp16 --------
// Wt[n*512 + sel*128 + k] = fp16( W[sel][k][n] * (sel==0 ? bnp_scale[k] : 1) )
__global__ void wprep_kernel(const float* __restrict__ W, const float* __restrict__ bnp,
                             _Float16* __restrict__ Wt) {
    int idx = blockIdx.x * 256 + threadIdx.x;   // 65536
    int n = idx >> 9, sk = idx & 511;
    int sel = sk >> 7, k = sk & 127;
    float v = W[sel * 16384 + k * 128 + n];
    if (sel == 0) v *= bnp[k];
    Wt[idx] = (_Float16)v;
}

// bias2[n] = b[n] + sum_k bnp_shift[k] * W[0][k][n]
__global__ void bias2_kernel(const float* __restrict__ W, const float* __restrict__ bnp,
                             const float* __restrict__ b, float* __restrict__ bias2) {
    int n = threadIdx.x;
    float s = b[n];
    for (int k = 0; k < 128; ++k) s += bnp[128 + k] * W[k * 128 + n];
    bias2[n] = s;
}

// ---------------- MFMA Cheb GEMM (row-major fp16 A tables) -----------------
// Block = 32 rows x 128 cols; 4 waves 2x2 (wave = 16 rows x 64 cols).
// Grid = N/32 = 1563 blocks (~6/CU). Per kt-pair: 8 A-loads batched.
template <int ACT, int STATS, int OUTH>
__global__ __launch_bounds__(256)
void gemm_mfma(const __half* __restrict__ T0, const __half* __restrict__ T1,
               const __half* __restrict__ T2, const __half* __restrict__ T3,
               const _Float16* __restrict__ Wt, const float* __restrict__ bias2,
               __half* __restrict__ outh, float* __restrict__ outf,
               float* __restrict__ stats, int N) {
    __shared__ float s_sum[128];
    __shared__ float s_sq[128];
    int tid = threadIdx.x;
    if (STATS) {
        if (tid < 128) { s_sum[tid] = 0.f; s_sq[tid] = 0.f; }
        __syncthreads();
    }
    int wave = tid >> 6, lane = tid & 63;
    int wr = wave >> 1, wc = wave & 1;
    int m = lane & 15, quad = lane >> 4;
    int row0 = blockIdx.x * 32 + wr * 16;

    size_t ra = (size_t)(min(row0 + m, N - 1)) * HDIM;

    const __half* Ts[4] = {T0, T1, T2, T3};
    f32x4 acc[4];
#pragma unroll
    for (int ct = 0; ct < 4; ++ct) acc[ct] = (f32x4){0.f, 0.f, 0.f, 0.f};

    const _Float16* Wn = Wt + (size_t)(wc * 64 + m) * 512;   // row n = wc*64+ct*16+m

#pragma unroll
    for (int ktp = 0; ktp < 2; ++ktp) {
        int ko0 = (ktp * 2) * 32 + quad * 8;
        int ko1 = (ktp * 2 + 1) * 32 + quad * 8;
        f16x8 a0[4], a1[4];
#pragma unroll
        for (int sel = 0; sel < 4; ++sel) {
            const _Float16* Tp = (const _Float16*)Ts[sel];
            a0[sel] = *(const f16x8*)(Tp + ra + ko0);
            a1[sel] = *(const f16x8*)(Tp + ra + ko1);
        }
#pragma unroll
        for (int sel = 0; sel < 4; ++sel) {
            const _Float16* Wb0 = Wn + sel * 128 + ko0;
            const _Float16* Wb1 = Wn + sel * 128 + ko1;
#pragma unroll
            for (int ct = 0; ct < 4; ++ct) {
                f16x8 b0 = *(const f16x8*)(Wb0 + (size_t)ct * 16 * 512);
                f16x8 b1 = *(const f16x8*)(Wb1 + (size_t)ct * 16 * 512);
                acc[ct] = __builtin_amdgcn_mfma_f32_16x16x32_f16(a0[sel], b0, acc[ct], 0, 0, 0);
                acc[ct] = __builtin_amdgcn_mfma_f32_16x16x32_f16(a1[sel], b1, acc[ct], 0, 0, 0);
            }
        }
    }

    // epilogue: D tile ct: row = row0 + quad*4 + r, col = wc*64 + ct*16 + m
    float csum[4] = {}, csq[4] = {};
#pragma unroll
    for (int ct = 0; ct < 4; ++ct) {
        int col = wc * 64 + ct * 16 + m;
        float bv = bias2[col];
#pragma unroll
        for (int r = 0; r < 4; ++r) {
            int drow = row0 + quad * 4 + r;
            if (drow < N) {
                float v = acc[ct][r] + bv;
                if (ACT == 1) v = v >= 0.f ? v : 0.01f * v;
                else if (ACT == 2) v = fmaxf(v, 0.f);
                if (OUTH) outh[(size_t)drow * HDIM + col] = __float2half(v);
                else      outf[(size_t)drow * HDIM + col] = v;
                if (STATS) { csum[ct] += v; csq[ct] += v * v; }
            }
        }
    }
    if (STATS) {
#pragma unroll
        for (int ct = 0; ct < 4; ++ct) {
            int col = wc * 64 + ct * 16 + m;
            atomicAdd(&s_sum[col], csum[ct]);
            atomicAdd(&s_sq[col], csq[ct]);
        }
        __syncthreads();
        if (tid < 128) {
            atomicAdd(&stats[tid], s_sum[tid]);
            atomicAdd(&stats[128 + tid], s_sq[tid]);
        }
    }
}

// ---------------- layer-1 (input dim 3) fused GEMM, grid-stride ------------
__global__ __launch_bounds__(256)
void gemm1_kernel(const float* __restrict__ x, const float* __restrict__ t1,
                  const float* __restrict__ t2, const float* __restrict__ t3,
                  const float* __restrict__ W1, const float* __restrict__ b1,
                  __half* __restrict__ out, float* __restrict__ stats, int N) {
    __shared__ float s_sum[128];
    __shared__ float s_sq[128];
    int tid = threadIdx.x;
    int c = tid & 127;
    if (tid < 128) { s_sum[tid] = 0.f; s_sq[tid] = 0.f; }
    __syncthreads();
    float wreg[12];
#pragma unroll
    for (int i = 0; i < 12; ++i) wreg[i] = W1[i * 128 + c];
    float bias = b1[c];
    const float* Ts[4] = {x, t1, t2, t3};
    float lsum = 0.f, lsq = 0.f;
    for (int row = blockIdx.x * 2 + (tid >> 7); row < N; row += gridDim.x * 2) {
        float v = bias;
#pragma unroll
        for (int k = 0; k < 4; ++k) {
            const float* t = Ts[k];
#pragma unroll
            for (int d = 0; d < 3; ++d)
                v += t[row * 3 + d] * wreg[k * 3 + d];
        }
        v = v >= 0.f ? v : 0.01f * v;   // leaky_relu
        out[(size_t)row * HDIM + c] = __float2half(v);
        lsum += v; lsq += v * v;
    }
    atomicAdd(&s_sum[c], lsum);
    atomicAdd(&s_sq[c], lsq);
    __syncthreads();
    if (tid < 128) {
        atomicAdd(&stats[tid], s_sum[tid]);
        atomicAdd(&stats[128 + tid], s_sq[tid]);
    }
}

// ---------------- BN finalize: stats -> (scale, shift) ----------------
__global__ void bnfin_kernel(const float* __restrict__ stats, const float* __restrict__ g,
                             const float* __restrict__ be, float* __restrict__ bnp, float invN) {
    int c = threadIdx.x;  // 128 threads
    float m = stats[c] * invN;
    float v = stats[128 + c] * invN - m * m;
    float sc = g[c] * rsqrtf(v + 1e-5f);
    bnp[c] = sc;
    bnp[128 + c] = be[c] - m * sc;
}

// ---------------- final: L2-normalize row + project to 3 ----------------
__global__ void final_kernel(const float* __restrict__ Z, const float* __restrict__ Wm,
                             const float* __restrict__ bm, float* __restrict__ out, int N) {
    int gid = blockIdx.x * blockDim.x + threadIdx.x;
    int node = gid >> 6;
    int lane = threadIdx.x & 63;
    if (node >= N) return;
    const float* z = Z + (size_t)node * HDIM;
    float z0 = z[lane], z1 = z[lane + 64];
    float sq = z0 * z0 + z1 * z1;
    float d0 = z0 * Wm[lane * 3 + 0] + z1 * Wm[(lane + 64) * 3 + 0];
    float d1 = z0 * Wm[lane * 3 + 1] + z1 * Wm[(lane + 64) * 3 + 1];
    float d2 = z0 * Wm[lane * 3 + 2] + z1 * Wm[(lane + 64) * 3 + 2];
#pragma unroll
    for (int off = 32; off > 0; off >>= 1) {
        sq += __shfl_down(sq, off);
        d0 += __shfl_down(d0, off);
        d1 += __shfl_down(d1, off);
        d2 += __shfl_down(d2, off);
    }
    if (lane == 0) {
        float inv = 1.f / fmaxf(sqrtf(sq), 1e-12f);
        out[node * 3 + 0] = d0 * inv + bm[0];
        out[node * 3 + 1] = d1 * inv + bm[1];
        out[node * 3 + 2] = d2 * inv + bm[2];
    }
}

// ---------------- host ----------------

extern "C" void kernel_launch(void* const* d_in, const int* in_sizes, int n_in,
                              void* d_out, int out_size, void* d_ws, size_t ws_size,
                              hipStream_t stream) {
    const float* x  = (const float*)d_in[0];
    const int*   ei = (const int*)d_in[1];
    const float* W1 = (const float*)d_in[2];
    const float* b1 = (const float*)d_in[3];
    const float* W2 = (const float*)d_in[4];
    const float* b2 = (const float*)d_in[5];
    const float* W3 = (const float*)d_in[6];
    const float* b3 = (const float*)d_in[7];
    const float* W4 = (const float*)d_in[8];
    const float* b4 = (const float*)d_in[9];
    const float* g1 = (const float*)d_in[10];
    const float* be1 = (const float*)d_in[11];
    const float* g2 = (const float*)d_in[12];
    const float* be2 = (const float*)d_in[13];
    const float* g3 = (const float*)d_in[14];
    const float* be3 = (const float*)d_in[15];
    const float* Wm = (const float*)d_in[16];
    const float* bm = (const float*)d_in[17];
    float* out = (float*)d_out;

    const int N = in_sizes[0] / 3;
    const int E = in_sizes[1] / 2;
    const size_t NH = (size_t)N * HDIM;
    const int* src = ei;
    const int* dst = ei + E;

    // ---- workspace layout ----
    char* base = (char*)d_ws;
    int* degS   = (int*)base;            base += (size_t)N * 4;
    int* degD   = (int*)base;            base += (size_t)N * 4;
    int* cursor = (int*)base;            base += (size_t)N * 4;
    int* rp     = (int*)base;            base += (size_t)(N + 2) * 4;
    int2* ev    = (int2*)base;           base += (size_t)E * 8;
    float* dinv = (float*)base;          base += (size_t)N * 4;
    __half* Za  = (__half*)base;         base += NH * 2;
    __half* Zb  = (__half*)base;         base += NH * 2;
    __half* T1  = (__half*)base;         base += NH * 2;
    __half* T2  = (__half*)base;         base += NH * 2;
    __half* T3  = (__half*)base;         base += NH * 2;
    float* Zf   = (float*)base;          base += NH * 4;   // layer-4 out, fp32
    float* x1   = (float*)base;          base += (size_t)N * 3 * 4;
    float* x2   = (float*)base;          base += (size_t)N * 3 * 4;
    float* x3   = (float*)base;          base += (size_t)N * 3 * 4;
    float* stats = (float*)base;         base += 256 * 4;
    float* bnp1  = (float*)base;         base += 256 * 4;
    float* bnp2  = (float*)base;         base += 256 * 4;
    float* bnp3  = (float*)base;         base += 256 * 4;
    _Float16* Wt = (_Float16*)base;      base += (size_t)65536 * 2;
    float* bias2 = (float*)base;         base += 128 * 4;

    const int EB = (E + 255) / 256;
    const int NB = (N + 255) / 256;
    const int GB = (N + 31) / 32;         // mfma gemm row tiles (32 rows)
    const int PB = (N + 3) / 4;           // pull128 blocks (4 nodes/block)
    const float invN = 1.f / (float)N;

    // --- CSR build + edge weights ---
    hipMemsetAsync(degS, 0, (size_t)N * 3 * 4, stream);   // degS, degD, cursor
    degs_kernel<<<EB, 256, 0, stream>>>(src, dst, degS, degD, E);
    dinv_kernel<<<NB, 256, 0, stream>>>(degS, dinv, N);
    scan_kernel<<<1, 1024, 0, stream>>>(degD, rp, N);
    scatter_kernel<<<EB, 256, 0, stream>>>(src, dst, dinv, rp, cursor, ev, E);

    // --- layer 1 (dim 3) -> Za (fp16), bnp1 ---
    pull3<<<NB, 256, 0, stream>>>(x,  nullptr, rp, ev, x1, 1.f, N);
    pull3<<<NB, 256, 0, stream>>>(x1, x,       rp, ev, x2, 2.f, N);
    pull3<<<NB, 256, 0, stream>>>(x2, x1,      rp, ev, x3, 2.f, N);
    hipMemsetAsync(stats, 0, 256 * 4, stream);
    gemm1_kernel<<<512, 256, 0, stream>>>(x, x1, x2, x3, W1, b1, Za, stats, N);
    bnfin_kernel<<<1, 128, 0, stream>>>(stats, g1, be1, bnp1, invN);

    // --- layer 2 (leaky + BN): input BN(Za,bnp1) -> Zb, bnp2 ---
    wprep_kernel<<<256, 256, 0, stream>>>(W2, bnp1, Wt);
    bias2_kernel<<<1, 128, 0, stream>>>(W2, bnp1, b2, bias2);
    pull128<1, 0><<<PB, 256, 0, stream>>>(Za, rp, ev, nullptr, bnp1, T1, 1.f, N);
    pull128<0, 1><<<PB, 256, 0, stream>>>(T1, rp, ev, Za, bnp1, T2, 2.f, N);
    pull128<0, 0><<<PB, 256, 0, stream>>>(T2, rp, ev, T1, nullptr, T3, 2.f, N);
    hipMemsetAsync(stats, 0, 256 * 4, stream);
    gemm_mfma<1, 1, 1><<<GB, 256, 0, stream>>>(Za, T1, T2, T3, Wt, bias2, Zb, nullptr, stats, N);
    bnfin_kernel<<<1, 128, 0, stream>>>(stats, g2, be2, bnp2, invN);

    // --- layer 3 (relu + BN): input BN(Zb,bnp2) -> Za, bnp3 ---
    wprep_kernel<<<256, 256, 0, stream>>>(W3, bnp2, Wt);
    bias2_kernel<<<1, 128, 0, stream>>>(W3, bnp2, b3, bias2);
    pull128<1, 0><<<PB, 256, 0, stream>>>(Zb, rp, ev, nullptr, bnp2, T1, 1.f, N);
    pull128<0, 1><<<PB, 256, 0, stream>>>(T1, rp, ev, Zb, bnp2, T2, 2.f, N);
    pull128<0, 0><<<PB, 256, 0, stream>>>(T2, rp, ev, T1, nullptr, T3, 2.f, N);
    hipMemsetAsync(stats, 0, 256 * 4, stream);
    gemm_mfma<2, 1, 1><<<GB, 256, 0, stream>>>(Zb, T1, T2, T3, Wt, bias2, Za, nullptr, stats, N);
    bnfin_kernel<<<1, 128, 0, stream>>>(stats, g3, be3, bnp3, invN);

    // --- layer 4 (no act/BN): input BN(Za,bnp3) -> Zf (fp32) ---
    wprep_kernel<<<256, 256, 0, stream>>>(W4, bnp3, Wt);
    bias2_kernel<<<1, 128, 0, stream>>>(W4, bnp3, b4, bias2);
    pull128<1, 0><<<PB, 256, 0, stream>>>(Za, rp, ev, nullptr, bnp3, T1, 1.f, N);
    pull128<0, 1><<<PB, 256, 0, stream>>>(T1, rp, ev, Za, bnp3, T2, 2.f, N);
    pull128<0, 0><<<PB, 256, 0, stream>>>(T2, rp, ev, T1, nullptr, T3, 2.f, N);
    gemm_mfma<0, 0, 0><<<GB, 256, 0, stream>>>(Za, T1, T2, T3, Wt, bias2, nullptr, Zf, nullptr, N);

    // --- normalize + project ---
    final_kernel<<<(N * 64 + 255) / 256, 256, 0, stream>>>(Zf, Wm, bm, out, N);
}

// Round 11
// 949.734 us; speedup vs baseline: 1.9270x; 1.0550x over previous
//
#include <hip/hip_runtime.h>
#include <hip/hip_fp16.h>
#include <math.h>

#define HDIM 128
#define NSLOT 32   // stats copies to spread atomic contention

typedef _Float16 f16x8 __attribute__((ext_vector_type(8)));
typedef float f32x4 __attribute__((ext_vector_type(4)));

// ---------------- degree / CSR build ----------------

__global__ void degs_kernel(const int* __restrict__ src, const int* __restrict__ dst,
                            int* __restrict__ degS, int* __restrict__ degD, int E) {
    int e = blockIdx.x * blockDim.x + threadIdx.x;
    if (e < E) {
        atomicAdd(&degS[src[e]], 1);
        atomicAdd(&degD[dst[e]], 1);
    }
}

__global__ void dinv_kernel(const int* __restrict__ degS, float* __restrict__ dinv, int N) {
    int i = blockIdx.x * blockDim.x + threadIdx.x;
    if (i < N) { int d = degS[i]; dinv[i] = d > 0 ? rsqrtf((float)d) : 0.f; }
}

// single-block exclusive scan of degD -> rp[0..N], rp[N] = E
__global__ __launch_bounds__(1024)
void scan_kernel(const int* __restrict__ deg, int* __restrict__ rp, int N) {
    __shared__ int part[1024];
    int tid = threadIdx.x;
    int chunk = (N + 1023) / 1024;
    int start = tid * chunk;
    int end = start + chunk; if (end > N) end = N;
    int s = 0;
    for (int i = start; i < end; ++i) s += deg[i];
    part[tid] = s;
    __syncthreads();
    for (int off = 1; off < 1024; off <<= 1) {
        int v = (tid >= off) ? part[tid - off] : 0;
        __syncthreads();
        part[tid] += v;
        __syncthreads();
    }
    int run = (tid == 0) ? 0 : part[tid - 1];
    for (int i = start; i < end; ++i) { rp[i] = run; run += deg[i]; }
    if (start < N && end == N) rp[N] = run;
}

__global__ void scatter_kernel(const int* __restrict__ src, const int* __restrict__ dst,
                               const float* __restrict__ dinv, const int* __restrict__ rp,
                               int* __restrict__ cursor, int2* __restrict__ ev, int E) {
    int e = blockIdx.x * blockDim.x + threadIdx.x;
    if (e >= E) return;
    int s = src[e], d = dst[e];
    float w = -dinv[s] * dinv[d];
    int pos = atomicAdd(&cursor[d], 1);
    ev[rp[d] + pos] = make_int2(s, __float_as_int(w));
}

// ---------------- pull propagation v2 (16B f16x8 gathers) -------------------
template <int GBN, int PBN>
__global__ __launch_bounds__(256)
void pull128(const __half* __restrict__ t, const int* __restrict__ rp,
             const int2* __restrict__ ev, const __half* __restrict__ prev,
             const float* __restrict__ bnp, __half* __restrict__ outp,
             float alpha, int N) {
    int node = blockIdx.x * 4 + (threadIdx.x >> 6);
    if (node >= N) return;
    int lane = threadIdx.x & 63;
    int c8 = (lane & 15) * 8;     // 8-channel group
    int slot = lane >> 4;         // edge slot 0..3
    const _Float16* tp = (const _Float16*)t;

    float scv[8], shv[8];
    if (GBN || PBN) {
#pragma unroll
        for (int i = 0; i < 8; ++i) { scv[i] = bnp[c8 + i]; shv[i] = bnp[128 + c8 + i]; }
    }

    int b = rp[node], e = rp[node + 1];
    float acc0[8] = {}, acc1[8] = {};
    int j = b;
    for (; j + 8 <= e; j += 8) {
        int2 s0 = ev[j + slot];
        int2 s1 = ev[j + 4 + slot];
        f16x8 r0 = *(const f16x8*)(tp + (size_t)s0.x * HDIM + c8);
        f16x8 r1 = *(const f16x8*)(tp + (size_t)s1.x * HDIM + c8);
        float w0 = __int_as_float(s0.y), w1 = __int_as_float(s1.y);
#pragma unroll
        for (int i = 0; i < 8; ++i) {
            float v0 = (float)r0[i], v1 = (float)r1[i];
            if (GBN) { v0 = v0 * scv[i] + shv[i]; v1 = v1 * scv[i] + shv[i]; }
            acc0[i] += w0 * v0; acc1[i] += w1 * v1;
        }
    }
    for (; j < e; j += 4) {
        int idx = j + slot;
        if (idx < e) {
            int2 s0 = ev[idx];
            f16x8 r0 = *(const f16x8*)(tp + (size_t)s0.x * HDIM + c8);
            float w0 = __int_as_float(s0.y);
#pragma unroll
            for (int i = 0; i < 8; ++i) {
                float v0 = (float)r0[i];
                if (GBN) v0 = v0 * scv[i] + shv[i];
                acc0[i] += w0 * v0;
            }
        }
    }
    float s[8];
#pragma unroll
    for (int i = 0; i < 8; ++i) {
        s[i] = acc0[i] + acc1[i];
        s[i] += __shfl_xor(s[i], 16);
        s[i] += __shfl_xor(s[i], 32);
    }
    if (lane < 16) {
        size_t o = (size_t)node * HDIM + c8;
        float r[8];
#pragma unroll
        for (int i = 0; i < 8; ++i) r[i] = alpha * s[i];
        if (!GBN) {
            f16x8 pv = *(const f16x8*)((const _Float16*)prev + o);
#pragma unroll
            for (int i = 0; i < 8; ++i) {
                float p = (float)pv[i];
                if (PBN) p = p * scv[i] + shv[i];
                r[i] -= p;
            }
        }
        f16x8 h;
#pragma unroll
        for (int i = 0; i < 8; ++i) h[i] = (_Float16)r[i];
        *(f16x8*)((_Float16*)outp + o) = h;
    }
}

__global__ void pull3(const float* __restrict__ t, const float* __restrict__ prev,
                      const int* __restrict__ rp, const int2* __restrict__ ev,
                      float* __restrict__ outp, float alpha, int N) {
    int node = blockIdx.x * blockDim.x + threadIdx.x;
    if (node >= N) return;
    int b = rp[node], e = rp[node + 1];
    float a0 = 0.f, a1 = 0.f, a2 = 0.f;
    for (int j = b; j < e; ++j) {
        int2 sw = ev[j];
        float w = __int_as_float(sw.y);
        const float* r = t + (size_t)sw.x * 3;
        a0 += w * r[0]; a1 += w * r[1]; a2 += w * r[2];
    }
    float r0 = alpha * a0, r1 = alpha * a1, r2 = alpha * a2;
    if (prev) {
        r0 -= prev[node * 3 + 0];
        r1 -= prev[node * 3 + 1];
        r2 -= prev[node * 3 + 2];
    }
    outp[node * 3 + 0] = r0;
    outp[node * 3 + 1] = r1;
    outp[node * 3 + 2] = r2;
}

// ---------------- weight prep: fold BN(T0) into W, transpose, fp16 --------
__global__ void wprep_kernel(const float* __restrict__ W, const float* __restrict__ bnp,
                             _Float16* __restrict__ Wt) {
    int idx = blockIdx.x * 256 + threadIdx.x;   // 65536
    int n = idx >> 9, sk = idx & 511;
    int sel = sk >> 7, k = sk & 127;
    float v = W[sel * 16384 + k * 128 + n];
    if (sel == 0) v *= bnp[k];
    Wt[idx] = (_Float16)v;
}

// bias2[n] = b[n] + sum_k bnp_shift[k] * W[0][k][n]
__global__ void bias2_kernel(const float* __restrict__ W, const float* __restrict__ bnp,
                             const float* __restrict__ b, float* __restrict__ bias2) {
    int n = threadIdx.x;
    float s = b[n];
    for (int k = 0; k < 128; ++k) s += bnp[128 + k] * W[k * 128 + n];
    bias2[n] = s;
}

// ---------------- MFMA Cheb GEMM (row-major fp16 A tables) -----------------
// Block = 32 rows x 128 cols; 4 waves 2x2. Stats spread over NSLOT copies.
template <int ACT, int STATS, int OUTH>
__global__ __launch_bounds__(256)
void gemm_mfma(const __half* __restrict__ T0, const __half* __restrict__ T1,
               const __half* __restrict__ T2, const __half* __restrict__ T3,
               const _Float16* __restrict__ Wt, const float* __restrict__ bias2,
               __half* __restrict__ outh, float* __restrict__ outf,
               float* __restrict__ stats, int N) {
    __shared__ float s_sum[128];
    __shared__ float s_sq[128];
    int tid = threadIdx.x;
    if (STATS) {
        if (tid < 128) { s_sum[tid] = 0.f; s_sq[tid] = 0.f; }
        __syncthreads();
    }
    int wave = tid >> 6, lane = tid & 63;
    int wr = wave >> 1, wc = wave & 1;
    int m = lane & 15, quad = lane >> 4;
    int row0 = blockIdx.x * 32 + wr * 16;

    size_t ra = (size_t)(min(row0 + m, N - 1)) * HDIM;

    const __half* Ts[4] = {T0, T1, T2, T3};
    f32x4 acc[4];
#pragma unroll
    for (int ct = 0; ct < 4; ++ct) acc[ct] = (f32x4){0.f, 0.f, 0.f, 0.f};

    const _Float16* Wn = Wt + (size_t)(wc * 64 + m) * 512;   // row n = wc*64+ct*16+m

#pragma unroll
    for (int ktp = 0; ktp < 2; ++ktp) {
        int ko0 = (ktp * 2) * 32 + quad * 8;
        int ko1 = (ktp * 2 + 1) * 32 + quad * 8;
        f16x8 a0[4], a1[4];
#pragma unroll
        for (int sel = 0; sel < 4; ++sel) {
            const _Float16* Tp = (const _Float16*)Ts[sel];
            a0[sel] = *(const f16x8*)(Tp + ra + ko0);
            a1[sel] = *(const f16x8*)(Tp + ra + ko1);
        }
#pragma unroll
        for (int sel = 0; sel < 4; ++sel) {
            const _Float16* Wb0 = Wn + sel * 128 + ko0;
            const _Float16* Wb1 = Wn + sel * 128 + ko1;
#pragma unroll
            for (int ct = 0; ct < 4; ++ct) {
                f16x8 b0 = *(const f16x8*)(Wb0 + (size_t)ct * 16 * 512);
                f16x8 b1 = *(const f16x8*)(Wb1 + (size_t)ct * 16 * 512);
                acc[ct] = __builtin_amdgcn_mfma_f32_16x16x32_f16(a0[sel], b0, acc[ct], 0, 0, 0);
                acc[ct] = __builtin_amdgcn_mfma_f32_16x16x32_f16(a1[sel], b1, acc[ct], 0, 0, 0);
            }
        }
    }

    // epilogue: D tile ct: row = row0 + quad*4 + r, col = wc*64 + ct*16 + m
    float csum[4] = {}, csq[4] = {};
#pragma unroll
    for (int ct = 0; ct < 4; ++ct) {
        int col = wc * 64 + ct * 16 + m;
        float bv = bias2[col];
#pragma unroll
        for (int r = 0; r < 4; ++r) {
            int drow = row0 + quad * 4 + r;
            if (drow < N) {
                float v = acc[ct][r] + bv;
                if (ACT == 1) v = v >= 0.f ? v : 0.01f * v;
                else if (ACT == 2) v = fmaxf(v, 0.f);
                if (OUTH) outh[(size_t)drow * HDIM + col] = __float2half(v);
                else      outf[(size_t)drow * HDIM + col] = v;
                if (STATS) { csum[ct] += v; csq[ct] += v * v; }
            }
        }
    }
    if (STATS) {
#pragma unroll
        for (int ct = 0; ct < 4; ++ct) {
            int col = wc * 64 + ct * 16 + m;
            atomicAdd(&s_sum[col], csum[ct]);
            atomicAdd(&s_sq[col], csq[ct]);
        }
        __syncthreads();
        if (tid < 128) {
            float* sp = stats + (size_t)(blockIdx.x & (NSLOT - 1)) * 256;
            atomicAdd(&sp[tid], s_sum[tid]);
            atomicAdd(&sp[128 + tid], s_sq[tid]);
        }
    }
}

// ---------------- layer-1 (input dim 3) fused GEMM, grid-stride ------------
__global__ __launch_bounds__(256)
void gemm1_kernel(const float* __restrict__ x, const float* __restrict__ t1,
                  const float* __restrict__ t2, const float* __restrict__ t3,
                  const float* __restrict__ W1, const float* __restrict__ b1,
                  __half* __restrict__ out, float* __restrict__ stats, int N) {
    __shared__ float s_sum[128];
    __shared__ float s_sq[128];
    int tid = threadIdx.x;
    int c = tid & 127;
    if (tid < 128) { s_sum[tid] = 0.f; s_sq[tid] = 0.f; }
    __syncthreads();
    float wreg[12];
#pragma unroll
    for (int i = 0; i < 12; ++i) wreg[i] = W1[i * 128 + c];
    float bias = b1[c];
    const float* Ts[4] = {x, t1, t2, t3};
    float lsum = 0.f, lsq = 0.f;
    for (int row = blockIdx.x * 2 + (tid >> 7); row < N; row += gridDim.x * 2) {
        float v = bias;
#pragma unroll
        for (int k = 0; k < 4; ++k) {
            const float* t = Ts[k];
#pragma unroll
            for (int d = 0; d < 3; ++d)
                v += t[row * 3 + d] * wreg[k * 3 + d];
        }
        v = v >= 0.f ? v : 0.01f * v;   // leaky_relu
        out[(size_t)row * HDIM + c] = __float2half(v);
        lsum += v; lsq += v * v;
    }
    atomicAdd(&s_sum[c], lsum);
    atomicAdd(&s_sq[c], lsq);
    __syncthreads();
    if (tid < 128) {
        float* sp = stats + (size_t)(blockIdx.x & (NSLOT - 1)) * 256;
        atomicAdd(&sp[tid], s_sum[tid]);
        atomicAdd(&sp[128 + tid], s_sq[tid]);
    }
}

// ---------------- BN finalize: reduce NSLOT stats copies -> (scale, shift) --
__global__ void bnfin_kernel(const float* __restrict__ stats, const float* __restrict__ g,
                             const float* __restrict__ be, float* __restrict__ bnp, float invN) {
    int c = threadIdx.x;  // 128 threads
    float s0 = 0.f, s1 = 0.f;
#pragma unroll 4
    for (int k = 0; k < NSLOT; ++k) {
        s0 += stats[k * 256 + c];
        s1 += stats[k * 256 + 128 + c];
    }
    float m = s0 * invN;
    float v = s1 * invN - m * m;
    float sc = g[c] * rsqrtf(v + 1e-5f);
    bnp[c] = sc;
    bnp[128 + c] = be[c] - m * sc;
}

// ---------------- final: L2-normalize row + project to 3 ----------------
__global__ void final_kernel(const float* __restrict__ Z, const float* __restrict__ Wm,
                             const float* __restrict__ bm, float* __restrict__ out, int N) {
    int gid = blockIdx.x * blockDim.x + threadIdx.x;
    int node = gid >> 6;
    int lane = threadIdx.x & 63;
    if (node >= N) return;
    const float* z = Z + (size_t)node * HDIM;
    float z0 = z[lane], z1 = z[lane + 64];
    float sq = z0 * z0 + z1 * z1;
    float d0 = z0 * Wm[lane * 3 + 0] + z1 * Wm[(lane + 64) * 3 + 0];
    float d1 = z0 * Wm[lane * 3 + 1] + z1 * Wm[(lane + 64) * 3 + 1];
    float d2 = z0 * Wm[lane * 3 + 2] + z1 * Wm[(lane + 64) * 3 + 2];
#pragma unroll
    for (int off = 32; off > 0; off >>= 1) {
        sq += __shfl_down(sq, off);
        d0 += __shfl_down(d0, off);
        d1 += __shfl_down(d1, off);
        d2 += __shfl_down(d2, off);
    }
    if (lane == 0) {
        float inv = 1.f / fmaxf(sqrtf(sq), 1e-12f);
        out[node * 3 + 0] = d0 * inv + bm[0];
        out[node * 3 + 1] = d1 * inv + bm[1];
        out[node * 3 + 2] = d2 * inv + bm[2];
    }
}

// ---------------- host ----------------

extern "C" void kernel_launch(void* const* d_in, const int* in_sizes, int n_in,
                              void* d_out, int out_size, void* d_ws, size_t ws_size,
                              hipStream_t stream) {
    const float* x  = (const float*)d_in[0];
    const int*   ei = (const int*)d_in[1];
    const float* W1 = (const float*)d_in[2];
    const float* b1 = (const float*)d_in[3];
    const float* W2 = (const float*)d_in[4];
    const float* b2 = (const float*)d_in[5];
    const float* W3 = (const float*)d_in[6];
    const float* b3 = (const float*)d_in[7];
    const float* W4 = (const float*)d_in[8];
    const float* b4 = (const float*)d_in[9];
    const float* g1 = (const float*)d_in[10];
    const float* be1 = (const float*)d_in[11];
    const float* g2 = (const float*)d_in[12];
    const float* be2 = (const float*)d_in[13];
    const float* g3 = (const float*)d_in[14];
    const float* be3 = (const float*)d_in[15];
    const float* Wm = (const float*)d_in[16];
    const float* bm = (const float*)d_in[17];
    float* out = (float*)d_out;

    const int N = in_sizes[0] / 3;
    const int E = in_sizes[1] / 2;
    const size_t NH = (size_t)N * HDIM;
    const int* src = ei;
    const int* dst = ei + E;

    // ---- workspace layout ----
    char* base = (char*)d_ws;
    int* degS   = (int*)base;            base += (size_t)N * 4;
    int* degD   = (int*)base;            base += (size_t)N * 4;
    int* cursor = (int*)base;            base += (size_t)N * 4;
    int* rp     = (int*)base;            base += (size_t)(N + 2) * 4;
    int2* ev    = (int2*)base;           base += (size_t)E * 8;
    float* dinv = (float*)base;          base += (size_t)N * 4;
    __half* Za  = (__half*)base;         base += NH * 2;
    __half* Zb  = (__half*)base;         base += NH * 2;
    __half* T1  = (__half*)base;         base += NH * 2;
    __half* T2  = (__half*)base;         base += NH * 2;
    __half* T3  = (__half*)base;         base += NH * 2;
    float* Zf   = (float*)base;          base += NH * 4;   // layer-4 out, fp32
    float* x1   = (float*)base;          base += (size_t)N * 3 * 4;
    float* x2   = (float*)base;          base += (size_t)N * 3 * 4;
    float* x3   = (float*)base;          base += (size_t)N * 3 * 4;
    float* stats = (float*)base;         base += (size_t)NSLOT * 256 * 4;
    float* bnp1  = (float*)base;         base += 256 * 4;
    float* bnp2  = (float*)base;         base += 256 * 4;
    float* bnp3  = (float*)base;         base += 256 * 4;
    _Float16* Wt = (_Float16*)base;      base += (size_t)65536 * 2;
    float* bias2 = (float*)base;         base += 128 * 4;

    const int EB = (E + 255) / 256;
    const int NB = (N + 255) / 256;
    const int GB = (N + 31) / 32;         // mfma gemm row tiles (32 rows)
    const int PB = (N + 3) / 4;           // pull128 blocks (4 nodes/block)
    const float invN = 1.f / (float)N;
    const size_t STB = (size_t)NSLOT * 256 * 4;

    // --- CSR build + edge weights ---
    hipMemsetAsync(degS, 0, (size_t)N * 3 * 4, stream);   // degS, degD, cursor
    degs_kernel<<<EB, 256, 0, stream>>>(src, dst, degS, degD, E);
    dinv_kernel<<<NB, 256, 0, stream>>>(degS, dinv, N);
    scan_kernel<<<1, 1024, 0, stream>>>(degD, rp, N);
    scatter_kernel<<<EB, 256, 0, stream>>>(src, dst, dinv, rp, cursor, ev, E);

    // --- layer 1 (dim 3) -> Za (fp16), bnp1 ---
    pull3<<<NB, 256, 0, stream>>>(x,  nullptr, rp, ev, x1, 1.f, N);
    pull3<<<NB, 256, 0, stream>>>(x1, x,       rp, ev, x2, 2.f, N);
    pull3<<<NB, 256, 0, stream>>>(x2, x1,      rp, ev, x3, 2.f, N);
    hipMemsetAsync(stats, 0, STB, stream);
    gemm1_kernel<<<512, 256, 0, stream>>>(x, x1, x2, x3, W1, b1, Za, stats, N);
    bnfin_kernel<<<1, 128, 0, stream>>>(stats, g1, be1, bnp1, invN);

    // --- layer 2 (leaky + BN): input BN(Za,bnp1) -> Zb, bnp2 ---
    wprep_kernel<<<256, 256, 0, stream>>>(W2, bnp1, Wt);
    bias2_kernel<<<1, 128, 0, stream>>>(W2, bnp1, b2, bias2);
    pull128<1, 0><<<PB, 256, 0, stream>>>(Za, rp, ev, nullptr, bnp1, T1, 1.f, N);
    pull128<0, 1><<<PB, 256, 0, stream>>>(T1, rp, ev, Za, bnp1, T2, 2.f, N);
    pull128<0, 0><<<PB, 256, 0, stream>>>(T2, rp, ev, T1, nullptr, T3, 2.f, N);
    hipMemsetAsync(stats, 0, STB, stream);
    gemm_mfma<1, 1, 1><<<GB, 256, 0, stream>>>(Za, T1, T2, T3, Wt, bias2, Zb, nullptr, stats, N);
    bnfin_kernel<<<1, 128, 0, stream>>>(stats, g2, be2, bnp2, invN);

    // --- layer 3 (relu + BN): input BN(Zb,bnp2) -> Za, bnp3 ---
    wprep_kernel<<<256, 256, 0, stream>>>(W3, bnp2, Wt);
    bias2_kernel<<<1, 128, 0, stream>>>(W3, bnp2, b3, bias2);
    pull128<1, 0><<<PB, 256, 0, stream>>>(Zb, rp, ev, nullptr, bnp2, T1, 1.f, N);
    pull128<0, 1><<<PB, 256, 0, stream>>>(T1, rp, ev, Zb, bnp2, T2, 2.f, N);
    pull128<0, 0><<<PB, 256, 0, stream>>>(T2, rp, ev, T1, nullptr, T3, 2.f, N);
    hipMemsetAsync(stats, 0, STB, stream);
    gemm_mfma<2, 1, 1><<<GB, 256, 0, stream>>>(Zb, T1, T2, T3, Wt, bias2, Za, nullptr, stats, N);
    bnfin_kernel<<<1, 128, 0, stream>>>(stats, g3, be3, bnp3, invN);

    // --- layer 4 (no act/BN): input BN(Za,bnp3) -> Zf (fp32) ---
    wprep_kernel<<<256, 256, 0, stream>>>(W4, bnp3, Wt);
    bias2_kernel<<<1, 128, 0, stream>>>(W4, bnp3, b4, bias2);
    pull128<1, 0><<<PB, 256, 0, stream>>>(Za, rp, ev, nullptr, bnp3, T1, 1.f, N);
    pull128<0, 1><<<PB, 256, 0, stream>>>(T1, rp, ev, Za, bnp3, T2, 2.f, N);
    pull128<0, 0><<<PB, 256, 0, stream>>>(T2, rp, ev, T1, nullptr, T3, 2.f, N);
    gemm_mfma<0, 0, 0><<<GB, 256, 0, stream>>>(Za, T1, T2, T3, Wt, bias2, nullptr, Zf, nullptr, N);

    // --- normalize + project ---
    final_kernel<<<(N * 64 + 255) / 256, 256, 0, stream>>>(Zf, Wm, bm, out, N);
}

// Round 12
// 882.932 us; speedup vs baseline: 2.0728x; 1.0757x over previous
//
#include <hip/hip_runtime.h>
#include <hip/hip_fp16.h>
#include <math.h>

#define HDIM 128
#define NSLOT 32   // stats copies to spread atomic contention

typedef _Float16 f16x8 __attribute__((ext_vector_type(8)));
typedef float f32x4 __attribute__((ext_vector_type(4)));

// ---------------- degree / CSR build ----------------

__global__ void degs_kernel(const int* __restrict__ src, const int* __restrict__ dst,
                            int* __restrict__ degS, int* __restrict__ degD, int E) {
    int e = blockIdx.x * blockDim.x + threadIdx.x;
    if (e < E) {
        atomicAdd(&degS[src[e]], 1);
        atomicAdd(&degD[dst[e]], 1);
    }
}

__global__ void dinv_kernel(const int* __restrict__ degS, float* __restrict__ dinv, int N) {
    int i = blockIdx.x * blockDim.x + threadIdx.x;
    if (i < N) { int d = degS[i]; dinv[i] = d > 0 ? rsqrtf((float)d) : 0.f; }
}

// ---- 3-phase multi-block exclusive scan of degD -> rp[0..N] ----
__global__ void scanp1_kernel(const int* __restrict__ deg, int* __restrict__ bsum, int N) {
    __shared__ int sdata[256];
    int i = blockIdx.x * 256 + threadIdx.x;
    sdata[threadIdx.x] = i < N ? deg[i] : 0;
    __syncthreads();
    for (int off = 128; off > 0; off >>= 1) {
        if (threadIdx.x < off) sdata[threadIdx.x] += sdata[threadIdx.x + off];
        __syncthreads();
    }
    if (threadIdx.x == 0) bsum[blockIdx.x] = sdata[0];
}

__global__ __launch_bounds__(1024)
void scanp2_kernel(int* __restrict__ bsum, int nb) {
    __shared__ int part[1024];
    int tid = threadIdx.x;
    int v = tid < nb ? bsum[tid] : 0;
    part[tid] = v;
    __syncthreads();
    for (int off = 1; off < 1024; off <<= 1) {
        int t = tid >= off ? part[tid - off] : 0;
        __syncthreads();
        part[tid] += t;
        __syncthreads();
    }
    if (tid < nb) bsum[tid] = part[tid] - v;   // exclusive
}

__global__ void scanp3_kernel(const int* __restrict__ deg, const int* __restrict__ bsum,
                              int* __restrict__ rp, int N, int E) {
    __shared__ int part[256];
    int tid = threadIdx.x;
    int i = blockIdx.x * 256 + tid;
    int v = i < N ? deg[i] : 0;
    part[tid] = v;
    __syncthreads();
    for (int off = 1; off < 256; off <<= 1) {
        int t = tid >= off ? part[tid - off] : 0;
        __syncthreads();
        part[tid] += t;
        __syncthreads();
    }
    if (i < N) rp[i] = bsum[blockIdx.x] + part[tid] - v;
    if (i == 0) rp[N] = E;
}

__global__ void scatter_kernel(const int* __restrict__ src, const int* __restrict__ dst,
                               const float* __restrict__ dinv, const int* __restrict__ rp,
                               int* __restrict__ cursor, int2* __restrict__ ev, int E) {
    int e = blockIdx.x * blockDim.x + threadIdx.x;
    if (e >= E) return;
    int s = src[e], d = dst[e];
    float w = -dinv[s] * dinv[d];
    int pos = atomicAdd(&cursor[d], 1);
    ev[rp[d] + pos] = make_int2(s, __float_as_int(w));
}

// ---------------- pull propagation v2 (16B f16x8 gathers) -------------------
template <int GBN, int PBN>
__global__ __launch_bounds__(256)
void pull128(const __half* __restrict__ t, const int* __restrict__ rp,
             const int2* __restrict__ ev, const __half* __restrict__ prev,
             const float* __restrict__ bnp, __half* __restrict__ outp,
             float alpha, int N) {
    int node = blockIdx.x * 4 + (threadIdx.x >> 6);
    if (node >= N) return;
    int lane = threadIdx.x & 63;
    int c8 = (lane & 15) * 8;     // 8-channel group
    int slot = lane >> 4;         // edge slot 0..3
    const _Float16* tp = (const _Float16*)t;

    float scv[8], shv[8];
    if (GBN || PBN) {
#pragma unroll
        for (int i = 0; i < 8; ++i) { scv[i] = bnp[c8 + i]; shv[i] = bnp[128 + c8 + i]; }
    }

    int b = rp[node], e = rp[node + 1];
    float acc0[8] = {}, acc1[8] = {};
    int j = b;
    for (; j + 8 <= e; j += 8) {
        int2 s0 = ev[j + slot];
        int2 s1 = ev[j + 4 + slot];
        f16x8 r0 = *(const f16x8*)(tp + (size_t)s0.x * HDIM + c8);
        f16x8 r1 = *(const f16x8*)(tp + (size_t)s1.x * HDIM + c8);
        float w0 = __int_as_float(s0.y), w1 = __int_as_float(s1.y);
#pragma unroll
        for (int i = 0; i < 8; ++i) {
            float v0 = (float)r0[i], v1 = (float)r1[i];
            if (GBN) { v0 = v0 * scv[i] + shv[i]; v1 = v1 * scv[i] + shv[i]; }
            acc0[i] += w0 * v0; acc1[i] += w1 * v1;
        }
    }
    for (; j < e; j += 4) {
        int idx = j + slot;
        if (idx < e) {
            int2 s0 = ev[idx];
            f16x8 r0 = *(const f16x8*)(tp + (size_t)s0.x * HDIM + c8);
            float w0 = __int_as_float(s0.y);
#pragma unroll
            for (int i = 0; i < 8; ++i) {
                float v0 = (float)r0[i];
                if (GBN) v0 = v0 * scv[i] + shv[i];
                acc0[i] += w0 * v0;
            }
        }
    }
    float s[8];
#pragma unroll
    for (int i = 0; i < 8; ++i) {
        s[i] = acc0[i] + acc1[i];
        s[i] += __shfl_xor(s[i], 16);
        s[i] += __shfl_xor(s[i], 32);
    }
    if (lane < 16) {
        size_t o = (size_t)node * HDIM + c8;
        float r[8];
#pragma unroll
        for (int i = 0; i < 8; ++i) r[i] = alpha * s[i];
        if (!GBN) {
            f16x8 pv = *(const f16x8*)((const _Float16*)prev + o);
#pragma unroll
            for (int i = 0; i < 8; ++i) {
                float p = (float)pv[i];
                if (PBN) p = p * scv[i] + shv[i];
                r[i] -= p;
            }
        }
        f16x8 h;
#pragma unroll
        for (int i = 0; i < 8; ++i) h[i] = (_Float16)r[i];
        *(f16x8*)((_Float16*)outp + o) = h;
    }
}

__global__ void pull3(const float* __restrict__ t, const float* __restrict__ prev,
                      const int* __restrict__ rp, const int2* __restrict__ ev,
                      float* __restrict__ outp, float alpha, int N) {
    int node = blockIdx.x * blockDim.x + threadIdx.x;
    if (node >= N) return;
    int b = rp[node], e = rp[node + 1];
    float a0 = 0.f, a1 = 0.f, a2 = 0.f;
    for (int j = b; j < e; ++j) {
        int2 sw = ev[j];
        float w = __int_as_float(sw.y);
        const float* r = t + (size_t)sw.x * 3;
        a0 += w * r[0]; a1 += w * r[1]; a2 += w * r[2];
    }
    float r0 = alpha * a0, r1 = alpha * a1, r2 = alpha * a2;
    if (prev) {
        r0 -= prev[node * 3 + 0];
        r1 -= prev[node * 3 + 1];
        r2 -= prev[node * 3 + 2];
    }
    outp[node * 3 + 0] = r0;
    outp[node * 3 + 1] = r1;
    outp[node * 3 + 2] = r2;
}

// ---------------- weight prep: fold BN(T0) into W, transpose, fp16 --------
__global__ void wprep_kernel(const float* __restrict__ W, const float* __restrict__ bnp,
                             _Float16* __restrict__ Wt) {
    int idx = blockIdx.x * 256 + threadIdx.x;   // 65536
    int n = idx >> 9, sk = idx & 511;
    int sel = sk >> 7, k = sk & 127;
    float v = W[sel * 16384 + k * 128 + n];
    if (sel == 0) v *= bnp[k];
    Wt[idx] = (_Float16)v;
}

// bias2[n] = b[n] + sum_k bnp_shift[k] * W[0][k][n]
__global__ void bias2_kernel(const float* __restrict__ W, const float* __restrict__ bnp,
                             const float* __restrict__ b, float* __restrict__ bias2) {
    int n = threadIdx.x;
    float s = b[n];
    for (int k = 0; k < 128; ++k) s += bnp[128 + k] * W[k * 128 + n];
    bias2[n] = s;
}

// ---------------- MFMA Cheb GEMM (row-major fp16 A tables) -----------------
// Block = 32 rows x 128 cols; 4 waves 2x2. Stats spread over NSLOT copies.
template <int ACT, int STATS, int OUTH>
__global__ __launch_bounds__(256)
void gemm_mfma(const __half* __restrict__ T0, const __half* __restrict__ T1,
               const __half* __restrict__ T2, const __half* __restrict__ T3,
               const _Float16* __restrict__ Wt, const float* __restrict__ bias2,
               __half* __restrict__ outh, float* __restrict__ outf,
               float* __restrict__ stats, int N) {
    __shared__ float s_sum[128];
    __shared__ float s_sq[128];
    int tid = threadIdx.x;
    if (STATS) {
        if (tid < 128) { s_sum[tid] = 0.f; s_sq[tid] = 0.f; }
        __syncthreads();
    }
    int wave = tid >> 6, lane = tid & 63;
    int wr = wave >> 1, wc = wave & 1;
    int m = lane & 15, quad = lane >> 4;
    int row0 = blockIdx.x * 32 + wr * 16;

    size_t ra = (size_t)(min(row0 + m, N - 1)) * HDIM;

    const __half* Ts[4] = {T0, T1, T2, T3};
    f32x4 acc[4];
#pragma unroll
    for (int ct = 0; ct < 4; ++ct) acc[ct] = (f32x4){0.f, 0.f, 0.f, 0.f};

    const _Float16* Wn = Wt + (size_t)(wc * 64 + m) * 512;   // row n = wc*64+ct*16+m

#pragma unroll
    for (int ktp = 0; ktp < 2; ++ktp) {
        int ko0 = (ktp * 2) * 32 + quad * 8;
        int ko1 = (ktp * 2 + 1) * 32 + quad * 8;
        f16x8 a0[4], a1[4];
#pragma unroll
        for (int sel = 0; sel < 4; ++sel) {
            const _Float16* Tp = (const _Float16*)Ts[sel];
            a0[sel] = *(const f16x8*)(Tp + ra + ko0);
            a1[sel] = *(const f16x8*)(Tp + ra + ko1);
        }
#pragma unroll
        for (int sel = 0; sel < 4; ++sel) {
            const _Float16* Wb0 = Wn + sel * 128 + ko0;
            const _Float16* Wb1 = Wn + sel * 128 + ko1;
#pragma unroll
            for (int ct = 0; ct < 4; ++ct) {
                f16x8 b0 = *(const f16x8*)(Wb0 + (size_t)ct * 16 * 512);
                f16x8 b1 = *(const f16x8*)(Wb1 + (size_t)ct * 16 * 512);
                acc[ct] = __builtin_amdgcn_mfma_f32_16x16x32_f16(a0[sel], b0, acc[ct], 0, 0, 0);
                acc[ct] = __builtin_amdgcn_mfma_f32_16x16x32_f16(a1[sel], b1, acc[ct], 0, 0, 0);
            }
        }
    }

    // epilogue: D tile ct: row = row0 + quad*4 + r, col = wc*64 + ct*16 + m
    float csum[4] = {}, csq[4] = {};
#pragma unroll
    for (int ct = 0; ct < 4; ++ct) {
        int col = wc * 64 + ct * 16 + m;
        float bv = bias2[col];
#pragma unroll
        for (int r = 0; r < 4; ++r) {
            int drow = row0 + quad * 4 + r;
            if (drow < N) {
                float v = acc[ct][r] + bv;
                if (ACT == 1) v = v >= 0.f ? v : 0.01f * v;
                else if (ACT == 2) v = fmaxf(v, 0.f);
                if (OUTH) outh[(size_t)drow * HDIM + col] = __float2half(v);
                else      outf[(size_t)drow * HDIM + col] = v;
                if (STATS) { csum[ct] += v; csq[ct] += v * v; }
            }
        }
    }
    if (STATS) {
#pragma unroll
        for (int ct = 0; ct < 4; ++ct) {
            int col = wc * 64 + ct * 16 + m;
            atomicAdd(&s_sum[col], csum[ct]);
            atomicAdd(&s_sq[col], csq[ct]);
        }
        __syncthreads();
        if (tid < 128) {
            float* sp = stats + (size_t)(blockIdx.x & (NSLOT - 1)) * 256;
            atomicAdd(&sp[tid], s_sum[tid]);
            atomicAdd(&sp[128 + tid], s_sq[tid]);
        }
    }
}

// ---------------- layer-1 (input dim 3) fused GEMM, grid-stride ------------
__global__ __launch_bounds__(256)
void gemm1_kernel(const float* __restrict__ x, const float* __restrict__ t1,
                  const float* __restrict__ t2, const float* __restrict__ t3,
                  const float* __restrict__ W1, const float* __restrict__ b1,
                  __half* __restrict__ out, float* __restrict__ stats, int N) {
    __shared__ float s_sum[128];
    __shared__ float s_sq[128];
    int tid = threadIdx.x;
    int c = tid & 127;
    if (tid < 128) { s_sum[tid] = 0.f; s_sq[tid] = 0.f; }
    __syncthreads();
    float wreg[12];
#pragma unroll
    for (int i = 0; i < 12; ++i) wreg[i] = W1[i * 128 + c];
    float bias = b1[c];
    const float* Ts[4] = {x, t1, t2, t3};
    float lsum = 0.f, lsq = 0.f;
    for (int row = blockIdx.x * 2 + (tid >> 7); row < N; row += gridDim.x * 2) {
        float v = bias;
#pragma unroll
        for (int k = 0; k < 4; ++k) {
            const float* t = Ts[k];
#pragma unroll
            for (int d = 0; d < 3; ++d)
                v += t[row * 3 + d] * wreg[k * 3 + d];
        }
        v = v >= 0.f ? v : 0.01f * v;   // leaky_relu
        out[(size_t)row * HDIM + c] = __float2half(v);
        lsum += v; lsq += v * v;
    }
    atomicAdd(&s_sum[c], lsum);
    atomicAdd(&s_sq[c], lsq);
    __syncthreads();
    if (tid < 128) {
        float* sp = stats + (size_t)(blockIdx.x & (NSLOT - 1)) * 256;
        atomicAdd(&sp[tid], s_sum[tid]);
        atomicAdd(&sp[128 + tid], s_sq[tid]);
    }
}

// ---------------- BN finalize: reduce NSLOT stats copies -> (scale, shift) --
__global__ void bnfin_kernel(const float* __restrict__ stats, const float* __restrict__ g,
                             const float* __restrict__ be, float* __restrict__ bnp, float invN) {
    int c = threadIdx.x;  // 128 threads
    float s0 = 0.f, s1 = 0.f;
#pragma unroll 4
    for (int k = 0; k < NSLOT; ++k) {
        s0 += stats[k * 256 + c];
        s1 += stats[k * 256 + 128 + c];
    }
    float m = s0 * invN;
    float v = s1 * invN - m * m;
    float sc = g[c] * rsqrtf(v + 1e-5f);
    bnp[c] = sc;
    bnp[128 + c] = be[c] - m * sc;
}

// ---------------- final: L2-normalize row + project to 3 ----------------
__global__ void final_kernel(const float* __restrict__ Z, const float* __restrict__ Wm,
                             const float* __restrict__ bm, float* __restrict__ out, int N) {
    int gid = blockIdx.x * blockDim.x + threadIdx.x;
    int node = gid >> 6;
    int lane = threadIdx.x & 63;
    if (node >= N) return;
    const float* z = Z + (size_t)node * HDIM;
    float z0 = z[lane], z1 = z[lane + 64];
    float sq = z0 * z0 + z1 * z1;
    float d0 = z0 * Wm[lane * 3 + 0] + z1 * Wm[(lane + 64) * 3 + 0];
    float d1 = z0 * Wm[lane * 3 + 1] + z1 * Wm[(lane + 64) * 3 + 1];
    float d2 = z0 * Wm[lane * 3 + 2] + z1 * Wm[(lane + 64) * 3 + 2];
#pragma unroll
    for (int off = 32; off > 0; off >>= 1) {
        sq += __shfl_down(sq, off);
        d0 += __shfl_down(d0, off);
        d1 += __shfl_down(d1, off);
        d2 += __shfl_down(d2, off);
    }
    if (lane == 0) {
        float inv = 1.f / fmaxf(sqrtf(sq), 1e-12f);
        out[node * 3 + 0] = d0 * inv + bm[0];
        out[node * 3 + 1] = d1 * inv + bm[1];
        out[node * 3 + 2] = d2 * inv + bm[2];
    }
}

// ---------------- host ----------------

extern "C" void kernel_launch(void* const* d_in, const int* in_sizes, int n_in,
                              void* d_out, int out_size, void* d_ws, size_t ws_size,
                              hipStream_t stream) {
    const float* x  = (const float*)d_in[0];
    const int*   ei = (const int*)d_in[1];
    const float* W1 = (const float*)d_in[2];
    const float* b1 = (const float*)d_in[3];
    const float* W2 = (const float*)d_in[4];
    const float* b2 = (const float*)d_in[5];
    const float* W3 = (const float*)d_in[6];
    const float* b3 = (const float*)d_in[7];
    const float* W4 = (const float*)d_in[8];
    const float* b4 = (const float*)d_in[9];
    const float* g1 = (const float*)d_in[10];
    const float* be1 = (const float*)d_in[11];
    const float* g2 = (const float*)d_in[12];
    const float* be2 = (const float*)d_in[13];
    const float* g3 = (const float*)d_in[14];
    const float* be3 = (const float*)d_in[15];
    const float* Wm = (const float*)d_in[16];
    const float* bm = (const float*)d_in[17];
    float* out = (float*)d_out;

    const int N = in_sizes[0] / 3;
    const int E = in_sizes[1] / 2;
    const size_t NH = (size_t)N * HDIM;
    const int* src = ei;
    const int* dst = ei + E;

    // ---- workspace layout ----
    char* base = (char*)d_ws;
    int* degS   = (int*)base;            base += (size_t)N * 4;
    int* degD   = (int*)base;            base += (size_t)N * 4;
    int* cursor = (int*)base;            base += (size_t)N * 4;
    int* rp     = (int*)base;            base += (size_t)(N + 2) * 4;
    int* bsum   = (int*)base;            base += (size_t)1024 * 4;
    int2* ev    = (int2*)base;           base += (size_t)E * 8;
    float* dinv = (float*)base;          base += (size_t)N * 4;
    __half* Za  = (__half*)base;         base += NH * 2;
    __half* Zb  = (__half*)base;         base += NH * 2;
    __half* T1  = (__half*)base;         base += NH * 2;
    __half* T2  = (__half*)base;         base += NH * 2;
    __half* T3  = (__half*)base;         base += NH * 2;
    float* Zf   = (float*)base;          base += NH * 4;   // layer-4 out, fp32
    float* x1   = (float*)base;          base += (size_t)N * 3 * 4;
    float* x2   = (float*)base;          base += (size_t)N * 3 * 4;
    float* x3   = (float*)base;          base += (size_t)N * 3 * 4;
    float* stats = (float*)base;         base += (size_t)NSLOT * 256 * 4;
    float* bnp1  = (float*)base;         base += 256 * 4;
    float* bnp2  = (float*)base;         base += 256 * 4;
    float* bnp3  = (float*)base;         base += 256 * 4;
    _Float16* Wt = (_Float16*)base;      base += (size_t)65536 * 2;
    float* bias2 = (float*)base;         base += 128 * 4;

    const int EB = (E + 255) / 256;
    const int NB = (N + 255) / 256;
    const int GB = (N + 31) / 32;         // mfma gemm row tiles (32 rows)
    const int PB = (N + 3) / 4;           // pull128 blocks (4 nodes/block)
    const float invN = 1.f / (float)N;
    const size_t STB = (size_t)NSLOT * 256 * 4;

    // --- CSR build + edge weights ---
    hipMemsetAsync(degS, 0, (size_t)N * 3 * 4, stream);   // degS, degD, cursor
    degs_kernel<<<EB, 256, 0, stream>>>(src, dst, degS, degD, E);
    dinv_kernel<<<NB, 256, 0, stream>>>(degS, dinv, N);
    scanp1_kernel<<<NB, 256, 0, stream>>>(degD, bsum, N);
    scanp2_kernel<<<1, 1024, 0, stream>>>(bsum, NB);
    scanp3_kernel<<<NB, 256, 0, stream>>>(degD, bsum, rp, N, E);
    scatter_kernel<<<EB, 256, 0, stream>>>(src, dst, dinv, rp, cursor, ev, E);

    // --- layer 1 (dim 3) -> Za (fp16), bnp1 ---
    pull3<<<NB, 256, 0, stream>>>(x,  nullptr, rp, ev, x1, 1.f, N);
    pull3<<<NB, 256, 0, stream>>>(x1, x,       rp, ev, x2, 2.f, N);
    pull3<<<NB, 256, 0, stream>>>(x2, x1,      rp, ev, x3, 2.f, N);
    hipMemsetAsync(stats, 0, STB, stream);
    gemm1_kernel<<<512, 256, 0, stream>>>(x, x1, x2, x3, W1, b1, Za, stats, N);
    bnfin_kernel<<<1, 128, 0, stream>>>(stats, g1, be1, bnp1, invN);

    // --- layer 2 (leaky + BN): input BN(Za,bnp1) -> Zb, bnp2 ---
    wprep_kernel<<<256, 256, 0, stream>>>(W2, bnp1, Wt);
    bias2_kernel<<<1, 128, 0, stream>>>(W2, bnp1, b2, bias2);
    pull128<1, 0><<<PB, 256, 0, stream>>>(Za, rp, ev, nullptr, bnp1, T1, 1.f, N);
    pull128<0, 1><<<PB, 256, 0, stream>>>(T1, rp, ev, Za, bnp1, T2, 2.f, N);
    pull128<0, 0><<<PB, 256, 0, stream>>>(T2, rp, ev, T1, nullptr, T3, 2.f, N);
    hipMemsetAsync(stats, 0, STB, stream);
    gemm_mfma<1, 1, 1><<<GB, 256, 0, stream>>>(Za, T1, T2, T3, Wt, bias2, Zb, nullptr, stats, N);
    bnfin_kernel<<<1, 128, 0, stream>>>(stats, g2, be2, bnp2, invN);

    // --- layer 3 (relu + BN): input BN(Zb,bnp2) -> Za, bnp3 ---
    wprep_kernel<<<256, 256, 0, stream>>>(W3, bnp2, Wt);
    bias2_kernel<<<1, 128, 0, stream>>>(W3, bnp2, b3, bias2);
    pull128<1, 0><<<PB, 256, 0, stream>>>(Zb, rp, ev, nullptr, bnp2, T1, 1.f, N);
    pull128<0, 1><<<PB, 256, 0, stream>>>(T1, rp, ev, Zb, bnp2, T2, 2.f, N);
    pull128<0, 0><<<PB, 256, 0, stream>>>(T2, rp, ev, T1, nullptr, T3, 2.f, N);
    hipMemsetAsync(stats, 0, STB, stream);
    gemm_mfma<2, 1, 1><<<GB, 256, 0, stream>>>(Zb, T1, T2, T3, Wt, bias2, Za, nullptr, stats, N);
    bnfin_kernel<<<1, 128, 0, stream>>>(stats, g3, be3, bnp3, invN);

    // --- layer 4 (no act/BN): input BN(Za,bnp3) -> Zf (fp32) ---
    wprep_kernel<<<256, 256, 0, stream>>>(W4, bnp3, Wt);
    bias2_kernel<<<1, 128, 0, stream>>>(W4, bnp3, b4, bias2);
    pull128<1, 0><<<PB, 256, 0, stream>>>(Za, rp, ev, nullptr, bnp3, T1, 1.f, N);
    pull128<0, 1><<<PB, 256, 0, stream>>>(T1, rp, ev, Za, bnp3, T2, 2.f, N);
    pull128<0, 0><<<PB, 256, 0, stream>>>(T2, rp, ev, T1, nullptr, T3, 2.f, N);
    gemm_mfma<0, 0, 0><<<GB, 256, 0, stream>>>(Za, T1, T2, T3, Wt, bias2, nullptr, Zf, nullptr, N);

    // --- normalize + project ---
    final_kernel<<<(N * 64 + 255) / 256, 256, 0, stream>>>(Zf, Wm, bm, out, N);
}

// Round 13
// 788.347 us; speedup vs baseline: 2.3215x; 1.1200x over previous
//
#include <hip/hip_runtime.h>
#include <hip/hip_fp16.h>
#include <math.h>

#define HDIM 128
#define NSLOT 32   // stats copies to spread atomic contention

typedef _Float16 f16x8 __attribute__((ext_vector_type(8)));
typedef float f32x4 __attribute__((ext_vector_type(4)));

// ---------------- degree / CSR build ----------------

__global__ void degs_kernel(const int* __restrict__ src, const int* __restrict__ dst,
                            int* __restrict__ degS, int* __restrict__ degD, int E) {
    int e = blockIdx.x * blockDim.x + threadIdx.x;
    if (e < E) {
        atomicAdd(&degS[src[e]], 1);
        atomicAdd(&degD[dst[e]], 1);
    }
}

__global__ void dinv_kernel(const int* __restrict__ degS, float* __restrict__ dinv, int N) {
    int i = blockIdx.x * blockDim.x + threadIdx.x;
    if (i < N) { int d = degS[i]; dinv[i] = d > 0 ? rsqrtf((float)d) : 0.f; }
}

// ---- 3-phase multi-block exclusive scan of degD -> rp[0..N] ----
__global__ void scanp1_kernel(const int* __restrict__ deg, int* __restrict__ bsum, int N) {
    __shared__ int sdata[256];
    int i = blockIdx.x * 256 + threadIdx.x;
    sdata[threadIdx.x] = i < N ? deg[i] : 0;
    __syncthreads();
    for (int off = 128; off > 0; off >>= 1) {
        if (threadIdx.x < off) sdata[threadIdx.x] += sdata[threadIdx.x + off];
        __syncthreads();
    }
    if (threadIdx.x == 0) bsum[blockIdx.x] = sdata[0];
}

__global__ __launch_bounds__(1024)
void scanp2_kernel(int* __restrict__ bsum, int nb) {
    __shared__ int part[1024];
    int tid = threadIdx.x;
    int v = tid < nb ? bsum[tid] : 0;
    part[tid] = v;
    __syncthreads();
    for (int off = 1; off < 1024; off <<= 1) {
        int t = tid >= off ? part[tid - off] : 0;
        __syncthreads();
        part[tid] += t;
        __syncthreads();
    }
    if (tid < nb) bsum[tid] = part[tid] - v;   // exclusive
}

__global__ void scanp3_kernel(const int* __restrict__ deg, const int* __restrict__ bsum,
                              int* __restrict__ rp, int N, int E) {
    __shared__ int part[256];
    int tid = threadIdx.x;
    int i = blockIdx.x * 256 + tid;
    int v = i < N ? deg[i] : 0;
    part[tid] = v;
    __syncthreads();
    for (int off = 1; off < 256; off <<= 1) {
        int t = tid >= off ? part[tid - off] : 0;
        __syncthreads();
        part[tid] += t;
        __syncthreads();
    }
    if (i < N) rp[i] = bsum[blockIdx.x] + part[tid] - v;
    if (i == 0) rp[N] = E;
}

__global__ void scatter_kernel(const int* __restrict__ src, const int* __restrict__ dst,
                               const float* __restrict__ dinv, const int* __restrict__ rp,
                               int* __restrict__ cursor, int2* __restrict__ ev, int E) {
    int e = blockIdx.x * blockDim.x + threadIdx.x;
    if (e >= E) return;
    int s = src[e], d = dst[e];
    float w = -dinv[s] * dinv[d];
    int pos = atomicAdd(&cursor[d], 1);
    ev[rp[d] + pos] = make_int2(s, __float_as_int(w));
}

// ---------------- pull propagation v2 (16B f16x8 gathers) -------------------
template <int GBN, int PBN>
__global__ __launch_bounds__(256)
void pull128(const __half* __restrict__ t, const int* __restrict__ rp,
             const int2* __restrict__ ev, const __half* __restrict__ prev,
             const float* __restrict__ bnp, __half* __restrict__ outp,
             float alpha, int N) {
    int node = blockIdx.x * 4 + (threadIdx.x >> 6);
    if (node >= N) return;
    int lane = threadIdx.x & 63;
    int c8 = (lane & 15) * 8;     // 8-channel group
    int slot = lane >> 4;         // edge slot 0..3
    const _Float16* tp = (const _Float16*)t;

    float scv[8], shv[8];
    if (GBN || PBN) {
#pragma unroll
        for (int i = 0; i < 8; ++i) { scv[i] = bnp[c8 + i]; shv[i] = bnp[128 + c8 + i]; }
    }

    int b = rp[node], e = rp[node + 1];
    float acc0[8] = {}, acc1[8] = {};
    int j = b;
    for (; j + 8 <= e; j += 8) {
        int2 s0 = ev[j + slot];
        int2 s1 = ev[j + 4 + slot];
        f16x8 r0 = *(const f16x8*)(tp + (size_t)s0.x * HDIM + c8);
        f16x8 r1 = *(const f16x8*)(tp + (size_t)s1.x * HDIM + c8);
        float w0 = __int_as_float(s0.y), w1 = __int_as_float(s1.y);
#pragma unroll
        for (int i = 0; i < 8; ++i) {
            float v0 = (float)r0[i], v1 = (float)r1[i];
            if (GBN) { v0 = v0 * scv[i] + shv[i]; v1 = v1 * scv[i] + shv[i]; }
            acc0[i] += w0 * v0; acc1[i] += w1 * v1;
        }
    }
    for (; j < e; j += 4) {
        int idx = j + slot;
        if (idx < e) {
            int2 s0 = ev[idx];
            f16x8 r0 = *(const f16x8*)(tp + (size_t)s0.x * HDIM + c8);
            float w0 = __int_as_float(s0.y);
#pragma unroll
            for (int i = 0; i < 8; ++i) {
                float v0 = (float)r0[i];
                if (GBN) v0 = v0 * scv[i] + shv[i];
                acc0[i] += w0 * v0;
            }
        }
    }
    float s[8];
#pragma unroll
    for (int i = 0; i < 8; ++i) {
        s[i] = acc0[i] + acc1[i];
        s[i] += __shfl_xor(s[i], 16);
        s[i] += __shfl_xor(s[i], 32);
    }
    if (lane < 16) {
        size_t o = (size_t)node * HDIM + c8;
        float r[8];
#pragma unroll
        for (int i = 0; i < 8; ++i) r[i] = alpha * s[i];
        if (!GBN) {
            f16x8 pv = *(const f16x8*)((const _Float16*)prev + o);
#pragma unroll
            for (int i = 0; i < 8; ++i) {
                float p = (float)pv[i];
                if (PBN) p = p * scv[i] + shv[i];
                r[i] -= p;
            }
        }
        f16x8 h;
#pragma unroll
        for (int i = 0; i < 8; ++i) h[i] = (_Float16)r[i];
        *(f16x8*)((_Float16*)outp + o) = h;
    }
}

__global__ void pull3(const float* __restrict__ t, const float* __restrict__ prev,
                      const int* __restrict__ rp, const int2* __restrict__ ev,
                      float* __restrict__ outp, float alpha, int N) {
    int node = blockIdx.x * blockDim.x + threadIdx.x;
    if (node >= N) return;
    int b = rp[node], e = rp[node + 1];
    float a0 = 0.f, a1 = 0.f, a2 = 0.f;
    for (int j = b; j < e; ++j) {
        int2 sw = ev[j];
        float w = __int_as_float(sw.y);
        const float* r = t + (size_t)sw.x * 3;
        a0 += w * r[0]; a1 += w * r[1]; a2 += w * r[2];
    }
    float r0 = alpha * a0, r1 = alpha * a1, r2 = alpha * a2;
    if (prev) {
        r0 -= prev[node * 3 + 0];
        r1 -= prev[node * 3 + 1];
        r2 -= prev[node * 3 + 2];
    }
    outp[node * 3 + 0] = r0;
    outp[node * 3 + 1] = r1;
    outp[node * 3 + 2] = r2;
}

// ---------------- weight prep: fold BN(T0), k-chunk-major fp16 --------------
// Layout: Wt[((k>>3)*128 + n)*8 + (k&7)], k = sel*128 + kk (global 0..511).
// A B-frag load (16 lanes x 16B contiguous per quad) touches 8 cache lines
// instead of 64 with the old n-major layout.
__global__ void wprep_kernel(const float* __restrict__ W, const float* __restrict__ bnp,
                             _Float16* __restrict__ Wt) {
    int idx = blockIdx.x * 256 + threadIdx.x;   // 65536 = n(128) x k(512)
    int n = idx >> 9, k = idx & 511;
    int sel = k >> 7, kk = k & 127;
    float v = W[sel * 16384 + kk * 128 + n];
    if (sel == 0) v *= bnp[kk];
    Wt[(size_t)((k >> 3) * 128 + n) * 8 + (k & 7)] = (_Float16)v;
}

// bias2[n] = b[n] + sum_k bnp_shift[k] * W[0][k][n]
__global__ void bias2_kernel(const float* __restrict__ W, const float* __restrict__ bnp,
                             const float* __restrict__ b, float* __restrict__ bias2) {
    int n = threadIdx.x;
    float s = b[n];
    for (int k = 0; k < 128; ++k) s += bnp[128 + k] * W[k * 128 + n];
    bias2[n] = s;
}

// ---------------- MFMA Cheb GEMM (row-major A, chunk-major B) ---------------
// Block = 32 rows x 128 cols; 4 waves 2x2. Stats spread over NSLOT copies.
template <int ACT, int STATS, int OUTH>
__global__ __launch_bounds__(256)
void gemm_mfma(const __half* __restrict__ T0, const __half* __restrict__ T1,
               const __half* __restrict__ T2, const __half* __restrict__ T3,
               const _Float16* __restrict__ Wt, const float* __restrict__ bias2,
               __half* __restrict__ outh, float* __restrict__ outf,
               float* __restrict__ stats, int N) {
    __shared__ float s_sum[128];
    __shared__ float s_sq[128];
    int tid = threadIdx.x;
    if (STATS) {
        if (tid < 128) { s_sum[tid] = 0.f; s_sq[tid] = 0.f; }
        __syncthreads();
    }
    int wave = tid >> 6, lane = tid & 63;
    int wr = wave >> 1, wc = wave & 1;
    int m = lane & 15, quad = lane >> 4;
    int row0 = blockIdx.x * 32 + wr * 16;

    size_t ra = (size_t)(min(row0 + m, N - 1)) * HDIM;
    int nbase = wc * 64 + m;

    const __half* Ts[4] = {T0, T1, T2, T3};
    f32x4 acc[4];
#pragma unroll
    for (int ct = 0; ct < 4; ++ct) acc[ct] = (f32x4){0.f, 0.f, 0.f, 0.f};

#pragma unroll
    for (int ktp = 0; ktp < 2; ++ktp) {
        int ko0 = (ktp * 2) * 32 + quad * 8;
        int ko1 = (ktp * 2 + 1) * 32 + quad * 8;
        f16x8 a0[4], a1[4];
#pragma unroll
        for (int sel = 0; sel < 4; ++sel) {
            const _Float16* Tp = (const _Float16*)Ts[sel];
            a0[sel] = *(const f16x8*)(Tp + ra + ko0);
            a1[sel] = *(const f16x8*)(Tp + ra + ko1);
        }
#pragma unroll
        for (int sel = 0; sel < 4; ++sel) {
            int c0 = sel * 16 + ktp * 8 + quad;       // k-chunk of ko0
            int c1 = c0 + 4;                          // k-chunk of ko1
#pragma unroll
            for (int ct = 0; ct < 4; ++ct) {
                f16x8 b0 = *(const f16x8*)(Wt + ((size_t)c0 * 128 + nbase + ct * 16) * 8);
                f16x8 b1 = *(const f16x8*)(Wt + ((size_t)c1 * 128 + nbase + ct * 16) * 8);
                acc[ct] = __builtin_amdgcn_mfma_f32_16x16x32_f16(a0[sel], b0, acc[ct], 0, 0, 0);
                acc[ct] = __builtin_amdgcn_mfma_f32_16x16x32_f16(a1[sel], b1, acc[ct], 0, 0, 0);
            }
        }
    }

    // epilogue: D tile ct: row = row0 + quad*4 + r, col = wc*64 + ct*16 + m
    float csum[4] = {}, csq[4] = {};
#pragma unroll
    for (int ct = 0; ct < 4; ++ct) {
        int col = wc * 64 + ct * 16 + m;
        float bv = bias2[col];
#pragma unroll
        for (int r = 0; r < 4; ++r) {
            int drow = row0 + quad * 4 + r;
            if (drow < N) {
                float v = acc[ct][r] + bv;
                if (ACT == 1) v = v >= 0.f ? v : 0.01f * v;
                else if (ACT == 2) v = fmaxf(v, 0.f);
                if (OUTH) outh[(size_t)drow * HDIM + col] = __float2half(v);
                else      outf[(size_t)drow * HDIM + col] = v;
                if (STATS) { csum[ct] += v; csq[ct] += v * v; }
            }
        }
    }
    if (STATS) {
#pragma unroll
        for (int ct = 0; ct < 4; ++ct) {
            int col = wc * 64 + ct * 16 + m;
            atomicAdd(&s_sum[col], csum[ct]);
            atomicAdd(&s_sq[col], csq[ct]);
        }
        __syncthreads();
        if (tid < 128) {
            float* sp = stats + (size_t)(blockIdx.x & (NSLOT - 1)) * 256;
            atomicAdd(&sp[tid], s_sum[tid]);
            atomicAdd(&sp[128 + tid], s_sq[tid]);
        }
    }
}

// ---------------- layer-1 (input dim 3) fused GEMM, grid-stride ------------
__global__ __launch_bounds__(256)
void gemm1_kernel(const float* __restrict__ x, const float* __restrict__ t1,
                  const float* __restrict__ t2, const float* __restrict__ t3,
                  const float* __restrict__ W1, const float* __restrict__ b1,
                  __half* __restrict__ out, float* __restrict__ stats, int N) {
    __shared__ float s_sum[128];
    __shared__ float s_sq[128];
    int tid = threadIdx.x;
    int c = tid & 127;
    if (tid < 128) { s_sum[tid] = 0.f; s_sq[tid] = 0.f; }
    __syncthreads();
    float wreg[12];
#pragma unroll
    for (int i = 0; i < 12; ++i) wreg[i] = W1[i * 128 + c];
    float bias = b1[c];
    const float* Ts[4] = {x, t1, t2, t3};
    float lsum = 0.f, lsq = 0.f;
    for (int row = blockIdx.x * 2 + (tid >> 7); row < N; row += gridDim.x * 2) {
        float v = bias;
#pragma unroll
        for (int k = 0; k < 4; ++k) {
            const float* t = Ts[k];
#pragma unroll
            for (int d = 0; d < 3; ++d)
                v += t[row * 3 + d] * wreg[k * 3 + d];
        }
        v = v >= 0.f ? v : 0.01f * v;   // leaky_relu
        out[(size_t)row * HDIM + c] = __float2half(v);
        lsum += v; lsq += v * v;
    }
    atomicAdd(&s_sum[c], lsum);
    atomicAdd(&s_sq[c], lsq);
    __syncthreads();
    if (tid < 128) {
        float* sp = stats + (size_t)(blockIdx.x & (NSLOT - 1)) * 256;
        atomicAdd(&sp[tid], s_sum[tid]);
        atomicAdd(&sp[128 + tid], s_sq[tid]);
    }
}

// ---------------- BN finalize: reduce NSLOT stats copies -> (scale, shift) --
__global__ void bnfin_kernel(const float* __restrict__ stats, const float* __restrict__ g,
                             const float* __restrict__ be, float* __restrict__ bnp, float invN) {
    int c = threadIdx.x;  // 128 threads
    float s0 = 0.f, s1 = 0.f;
#pragma unroll 4
    for (int k = 0; k < NSLOT; ++k) {
        s0 += stats[k * 256 + c];
        s1 += stats[k * 256 + 128 + c];
    }
    float m = s0 * invN;
    float v = s1 * invN - m * m;
    float sc = g[c] * rsqrtf(v + 1e-5f);
    bnp[c] = sc;
    bnp[128 + c] = be[c] - m * sc;
}

// ---------------- final: L2-normalize row + project to 3 ----------------
__global__ void final_kernel(const float* __restrict__ Z, const float* __restrict__ Wm,
                             const float* __restrict__ bm, float* __restrict__ out, int N) {
    int gid = blockIdx.x * blockDim.x + threadIdx.x;
    int node = gid >> 6;
    int lane = threadIdx.x & 63;
    if (node >= N) return;
    const float* z = Z + (size_t)node * HDIM;
    float z0 = z[lane], z1 = z[lane + 64];
    float sq = z0 * z0 + z1 * z1;
    float d0 = z0 * Wm[lane * 3 + 0] + z1 * Wm[(lane + 64) * 3 + 0];
    float d1 = z0 * Wm[lane * 3 + 1] + z1 * Wm[(lane + 64) * 3 + 1];
    float d2 = z0 * Wm[lane * 3 + 2] + z1 * Wm[(lane + 64) * 3 + 2];
#pragma unroll
    for (int off = 32; off > 0; off >>= 1) {
        sq += __shfl_down(sq, off);
        d0 += __shfl_down(d0, off);
        d1 += __shfl_down(d1, off);
        d2 += __shfl_down(d2, off);
    }
    if (lane == 0) {
        float inv = 1.f / fmaxf(sqrtf(sq), 1e-12f);
        out[node * 3 + 0] = d0 * inv + bm[0];
        out[node * 3 + 1] = d1 * inv + bm[1];
        out[node * 3 + 2] = d2 * inv + bm[2];
    }
}

// ---------------- host ----------------

extern "C" void kernel_launch(void* const* d_in, const int* in_sizes, int n_in,
                              void* d_out, int out_size, void* d_ws, size_t ws_size,
                              hipStream_t stream) {
    const float* x  = (const float*)d_in[0];
    const int*   ei = (const int*)d_in[1];
    const float* W1 = (const float*)d_in[2];
    const float* b1 = (const float*)d_in[3];
    const float* W2 = (const float*)d_in[4];
    const float* b2 = (const float*)d_in[5];
    const float* W3 = (const float*)d_in[6];
    const float* b3 = (const float*)d_in[7];
    const float* W4 = (const float*)d_in[8];
    const float* b4 = (const float*)d_in[9];
    const float* g1 = (const float*)d_in[10];
    const float* be1 = (const float*)d_in[11];
    const float* g2 = (const float*)d_in[12];
    const float* be2 = (const float*)d_in[13];
    const float* g3 = (const float*)d_in[14];
    const float* be3 = (const float*)d_in[15];
    const float* Wm = (const float*)d_in[16];
    const float* bm = (const float*)d_in[17];
    float* out = (float*)d_out;

    const int N = in_sizes[0] / 3;
    const int E = in_sizes[1] / 2;
    const size_t NH = (size_t)N * HDIM;
    const int* src = ei;
    const int* dst = ei + E;

    // ---- workspace layout ----
    char* base = (char*)d_ws;
    int* degS   = (int*)base;            base += (size_t)N * 4;
    int* degD   = (int*)base;            base += (size_t)N * 4;
    int* cursor = (int*)base;            base += (size_t)N * 4;
    int* rp     = (int*)base;            base += (size_t)(N + 2) * 4;
    int* bsum   = (int*)base;            base += (size_t)1024 * 4;
    int2* ev    = (int2*)base;           base += (size_t)E * 8;
    float* dinv = (float*)base;          base += (size_t)N * 4;
    __half* Za  = (__half*)base;         base += NH * 2;
    __half* Zb  = (__half*)base;         base += NH * 2;
    __half* T1  = (__half*)base;         base += NH * 2;
    __half* T2  = (__half*)base;         base += NH * 2;
    __half* T3  = (__half*)base;         base += NH * 2;
    float* Zf   = (float*)base;          base += NH * 4;   // layer-4 out, fp32
    float* x1   = (float*)base;          base += (size_t)N * 3 * 4;
    float* x2   = (float*)base;          base += (size_t)N * 3 * 4;
    float* x3   = (float*)base;          base += (size_t)N * 3 * 4;
    float* stats = (float*)base;         base += (size_t)NSLOT * 256 * 4;
    float* bnp1  = (float*)base;         base += 256 * 4;
    float* bnp2  = (float*)base;         base += 256 * 4;
    float* bnp3  = (float*)base;         base += 256 * 4;
    _Float16* Wt = (_Float16*)base;      base += (size_t)65536 * 2;
    float* bias2 = (float*)base;         base += 128 * 4;

    const int EB = (E + 255) / 256;
    const int NB = (N + 255) / 256;
    const int GB = (N + 31) / 32;         // mfma gemm row tiles (32 rows)
    const int PB = (N + 3) / 4;           // pull128 blocks (4 nodes/block)
    const float invN = 1.f / (float)N;
    const size_t STB = (size_t)NSLOT * 256 * 4;

    // --- CSR build + edge weights ---
    hipMemsetAsync(degS, 0, (size_t)N * 3 * 4, stream);   // degS, degD, cursor
    degs_kernel<<<EB, 256, 0, stream>>>(src, dst, degS, degD, E);
    dinv_kernel<<<NB, 256, 0, stream>>>(degS, dinv, N);
    scanp1_kernel<<<NB, 256, 0, stream>>>(degD, bsum, N);
    scanp2_kernel<<<1, 1024, 0, stream>>>(bsum, NB);
    scanp3_kernel<<<NB, 256, 0, stream>>>(degD, bsum, rp, N, E);
    scatter_kernel<<<EB, 256, 0, stream>>>(src, dst, dinv, rp, cursor, ev, E);

    // --- layer 1 (dim 3) -> Za (fp16), bnp1 ---
    pull3<<<NB, 256, 0, stream>>>(x,  nullptr, rp, ev, x1, 1.f, N);
    pull3<<<NB, 256, 0, stream>>>(x1, x,       rp, ev, x2, 2.f, N);
    pull3<<<NB, 256, 0, stream>>>(x2, x1,      rp, ev, x3, 2.f, N);
    hipMemsetAsync(stats, 0, STB, stream);
    gemm1_kernel<<<512, 256, 0, stream>>>(x, x1, x2, x3, W1, b1, Za, stats, N);
    bnfin_kernel<<<1, 128, 0, stream>>>(stats, g1, be1, bnp1, invN);

    // --- layer 2 (leaky + BN): input BN(Za,bnp1) -> Zb, bnp2 ---
    wprep_kernel<<<256, 256, 0, stream>>>(W2, bnp1, Wt);
    bias2_kernel<<<1, 128, 0, stream>>>(W2, bnp1, b2, bias2);
    pull128<1, 0><<<PB, 256, 0, stream>>>(Za, rp, ev, nullptr, bnp1, T1, 1.f, N);
    pull128<0, 1><<<PB, 256, 0, stream>>>(T1, rp, ev, Za, bnp1, T2, 2.f, N);
    pull128<0, 0><<<PB, 256, 0, stream>>>(T2, rp, ev, T1, nullptr, T3, 2.f, N);
    hipMemsetAsync(stats, 0, STB, stream);
    gemm_mfma<1, 1, 1><<<GB, 256, 0, stream>>>(Za, T1, T2, T3, Wt, bias2, Zb, nullptr, stats, N);
    bnfin_kernel<<<1, 128, 0, stream>>>(stats, g2, be2, bnp2, invN);

    // --- layer 3 (relu + BN): input BN(Zb,bnp2) -> Za, bnp3 ---
    wprep_kernel<<<256, 256, 0, stream>>>(W3, bnp2, Wt);
    bias2_kernel<<<1, 128, 0, stream>>>(W3, bnp2, b3, bias2);
    pull128<1, 0><<<PB, 256, 0, stream>>>(Zb, rp, ev, nullptr, bnp2, T1, 1.f, N);
    pull128<0, 1><<<PB, 256, 0, stream>>>(T1, rp, ev, Zb, bnp2, T2, 2.f, N);
    pull128<0, 0><<<PB, 256, 0, stream>>>(T2, rp, ev, T1, nullptr, T3, 2.f, N);
    hipMemsetAsync(stats, 0, STB, stream);
    gemm_mfma<2, 1, 1><<<GB, 256, 0, stream>>>(Zb, T1, T2, T3, Wt, bias2, Za, nullptr, stats, N);
    bnfin_kernel<<<1, 128, 0, stream>>>(stats, g3, be3, bnp3, invN);

    // --- layer 4 (no act/BN): input BN(Za,bnp3) -> Zf (fp32) ---
    wprep_kernel<<<256, 256, 0, stream>>>(W4, bnp3, Wt);
    bias2_kernel<<<1, 128, 0, stream>>>(W4, bnp3, b4, bias2);
    pull128<1, 0><<<PB, 256, 0, stream>>>(Za, rp, ev, nullptr, bnp3, T1, 1.f, N);
    pull128<0, 1><<<PB, 256, 0, stream>>>(T1, rp, ev, Za, bnp3, T2, 2.f, N);
    pull128<0, 0><<<PB, 256, 0, stream>>>(T2, rp, ev, T1, nullptr, T3, 2.f, N);
    gemm_mfma<0, 0, 0><<<GB, 256, 0, stream>>>(Za, T1, T2, T3, Wt, bias2, nullptr, Zf, nullptr, N);

    // --- normalize + project ---
    final_kernel<<<(N * 64 + 255) / 256, 256, 0, stream>>>(Zf, Wm, bm, out, N);
}

// Round 14
// 769.174 us; speedup vs baseline: 2.3793x; 1.0249x over previous
//
#include <hip/hip_runtime.h>
#include <hip/hip_fp16.h>
#include <math.h>

#define HDIM 128
#define NSLOT 32    // stats copies to spread atomic contention
#define SEGSZ 6272  // histogram segment size (LDS ints)
#define NSLICE 32   // edge slices for histogram

typedef _Float16 f16x8 __attribute__((ext_vector_type(8)));
typedef float f32x4 __attribute__((ext_vector_type(4)));

// ---------------- degree histograms via LDS segments (no global atomics) ----
// Block (seg, slice): LDS histograms of src/dst within segment over edge slice,
// flushed non-atomically to partial arrays partS/partD[slice][node].
__global__ __launch_bounds__(256)
void hist_kernel(const int* __restrict__ src, const int* __restrict__ dst,
                 int* __restrict__ partS, int* __restrict__ partD,
                 int nseg, int N, int E) {
    __shared__ int hS[SEGSZ];
    __shared__ int hD[SEGSZ];
    int tid = threadIdx.x;
    int seg = blockIdx.x % nseg;
    int slice = blockIdx.x / nseg;
    int seg0 = seg * SEGSZ;
    for (int i = tid; i < SEGSZ; i += 256) { hS[i] = 0; hD[i] = 0; }
    __syncthreads();
    int chunk = (E + NSLICE - 1) / NSLICE;
    int e0 = slice * chunk;
    int e1 = min(E, e0 + chunk);
    for (int e = e0 + tid; e < e1; e += 256) {
        int s = src[e] - seg0;
        int d = dst[e] - seg0;
        if ((unsigned)s < SEGSZ) atomicAdd(&hS[s], 1);
        if ((unsigned)d < SEGSZ) atomicAdd(&hD[d], 1);
    }
    __syncthreads();
    for (int i = tid; i < SEGSZ; i += 256) {
        int node = seg0 + i;
        if (node < N) {
            partS[(size_t)slice * N + node] = hS[i];
            partD[(size_t)slice * N + node] = hD[i];
        }
    }
}

// reduce partials -> dinv (fused rsqrt) and degD
__global__ void reduce_kernel(const int* __restrict__ partS, const int* __restrict__ partD,
                              float* __restrict__ dinv, int* __restrict__ degD, int N) {
    int i = blockIdx.x * blockDim.x + threadIdx.x;
    if (i >= N) return;
    int sS = 0, sD = 0;
#pragma unroll 8
    for (int k = 0; k < NSLICE; ++k) {
        sS += partS[(size_t)k * N + i];
        sD += partD[(size_t)k * N + i];
    }
    dinv[i] = sS > 0 ? rsqrtf((float)sS) : 0.f;
    degD[i] = sD;
}

// ---- 3-phase multi-block exclusive scan of degD -> rp[0..N] ----
__global__ void scanp1_kernel(const int* __restrict__ deg, int* __restrict__ bsum, int N) {
    __shared__ int sdata[256];
    int i = blockIdx.x * 256 + threadIdx.x;
    sdata[threadIdx.x] = i < N ? deg[i] : 0;
    __syncthreads();
    for (int off = 128; off > 0; off >>= 1) {
        if (threadIdx.x < off) sdata[threadIdx.x] += sdata[threadIdx.x + off];
        __syncthreads();
    }
    if (threadIdx.x == 0) bsum[blockIdx.x] = sdata[0];
}

__global__ __launch_bounds__(1024)
void scanp2_kernel(int* __restrict__ bsum, int nb) {
    __shared__ int part[1024];
    int tid = threadIdx.x;
    int v = tid < nb ? bsum[tid] : 0;
    part[tid] = v;
    __syncthreads();
    for (int off = 1; off < 1024; off <<= 1) {
        int t = tid >= off ? part[tid - off] : 0;
        __syncthreads();
        part[tid] += t;
        __syncthreads();
    }
    if (tid < nb) bsum[tid] = part[tid] - v;   // exclusive
}

__global__ void scanp3_kernel(const int* __restrict__ deg, const int* __restrict__ bsum,
                              int* __restrict__ rp, int N, int E) {
    __shared__ int part[256];
    int tid = threadIdx.x;
    int i = blockIdx.x * 256 + tid;
    int v = i < N ? deg[i] : 0;
    part[tid] = v;
    __syncthreads();
    for (int off = 1; off < 256; off <<= 1) {
        int t = tid >= off ? part[tid - off] : 0;
        __syncthreads();
        part[tid] += t;
        __syncthreads();
    }
    if (i < N) rp[i] = bsum[blockIdx.x] + part[tid] - v;
    if (i == 0) rp[N] = E;
}

__global__ void scatter_kernel(const int* __restrict__ src, const int* __restrict__ dst,
                               const float* __restrict__ dinv, const int* __restrict__ rp,
                               int* __restrict__ cursor, int2* __restrict__ ev, int E) {
    int e = blockIdx.x * blockDim.x + threadIdx.x;
    if (e >= E) return;
    int s = src[e], d = dst[e];
    float w = -dinv[s] * dinv[d];
    int pos = atomicAdd(&cursor[d], 1);
    ev[rp[d] + pos] = make_int2(s, __float_as_int(w));
}

// ---------------- pull propagation v2 (16B f16x8 gathers) -------------------
template <int GBN, int PBN>
__global__ __launch_bounds__(256)
void pull128(const __half* __restrict__ t, const int* __restrict__ rp,
             const int2* __restrict__ ev, const __half* __restrict__ prev,
             const float* __restrict__ bnp, __half* __restrict__ outp,
             float alpha, int N) {
    int node = blockIdx.x * 4 + (threadIdx.x >> 6);
    if (node >= N) return;
    int lane = threadIdx.x & 63;
    int c8 = (lane & 15) * 8;     // 8-channel group
    int slot = lane >> 4;         // edge slot 0..3
    const _Float16* tp = (const _Float16*)t;

    float scv[8], shv[8];
    if (GBN || PBN) {
#pragma unroll
        for (int i = 0; i < 8; ++i) { scv[i] = bnp[c8 + i]; shv[i] = bnp[128 + c8 + i]; }
    }

    int b = rp[node], e = rp[node + 1];
    float acc0[8] = {}, acc1[8] = {};
    int j = b;
    for (; j + 8 <= e; j += 8) {
        int2 s0 = ev[j + slot];
        int2 s1 = ev[j + 4 + slot];
        f16x8 r0 = *(const f16x8*)(tp + (size_t)s0.x * HDIM + c8);
        f16x8 r1 = *(const f16x8*)(tp + (size_t)s1.x * HDIM + c8);
        float w0 = __int_as_float(s0.y), w1 = __int_as_float(s1.y);
#pragma unroll
        for (int i = 0; i < 8; ++i) {
            float v0 = (float)r0[i], v1 = (float)r1[i];
            if (GBN) { v0 = v0 * scv[i] + shv[i]; v1 = v1 * scv[i] + shv[i]; }
            acc0[i] += w0 * v0; acc1[i] += w1 * v1;
        }
    }
    for (; j < e; j += 4) {
        int idx = j + slot;
        if (idx < e) {
            int2 s0 = ev[idx];
            f16x8 r0 = *(const f16x8*)(tp + (size_t)s0.x * HDIM + c8);
            float w0 = __int_as_float(s0.y);
#pragma unroll
            for (int i = 0; i < 8; ++i) {
                float v0 = (float)r0[i];
                if (GBN) v0 = v0 * scv[i] + shv[i];
                acc0[i] += w0 * v0;
            }
        }
    }
    float s[8];
#pragma unroll
    for (int i = 0; i < 8; ++i) {
        s[i] = acc0[i] + acc1[i];
        s[i] += __shfl_xor(s[i], 16);
        s[i] += __shfl_xor(s[i], 32);
    }
    if (lane < 16) {
        size_t o = (size_t)node * HDIM + c8;
        float r[8];
#pragma unroll
        for (int i = 0; i < 8; ++i) r[i] = alpha * s[i];
        if (!GBN) {
            f16x8 pv = *(const f16x8*)((const _Float16*)prev + o);
#pragma unroll
            for (int i = 0; i < 8; ++i) {
                float p = (float)pv[i];
                if (PBN) p = p * scv[i] + shv[i];
                r[i] -= p;
            }
        }
        f16x8 h;
#pragma unroll
        for (int i = 0; i < 8; ++i) h[i] = (_Float16)r[i];
        *(f16x8*)((_Float16*)outp + o) = h;
    }
}

__global__ void pull3(const float* __restrict__ t, const float* __restrict__ prev,
                      const int* __restrict__ rp, const int2* __restrict__ ev,
                      float* __restrict__ outp, float alpha, int N) {
    int node = blockIdx.x * blockDim.x + threadIdx.x;
    if (node >= N) return;
    int b = rp[node], e = rp[node + 1];
    float a0 = 0.f, a1 = 0.f, a2 = 0.f;
    for (int j = b; j < e; ++j) {
        int2 sw = ev[j];
        float w = __int_as_float(sw.y);
        const float* r = t + (size_t)sw.x * 3;
        a0 += w * r[0]; a1 += w * r[1]; a2 += w * r[2];
    }
    float r0 = alpha * a0, r1 = alpha * a1, r2 = alpha * a2;
    if (prev) {
        r0 -= prev[node * 3 + 0];
        r1 -= prev[node * 3 + 1];
        r2 -= prev[node * 3 + 2];
    }
    outp[node * 3 + 0] = r0;
    outp[node * 3 + 1] = r1;
    outp[node * 3 + 2] = r2;
}

// ---------------- weight prep: fold BN(T0), k-chunk-major fp16 --------------
// Layout: Wt[((k>>3)*128 + n)*8 + (k&7)], k = sel*128 + kk (global 0..511).
__global__ void wprep_kernel(const float* __restrict__ W, const float* __restrict__ bnp,
                             _Float16* __restrict__ Wt) {
    int idx = blockIdx.x * 256 + threadIdx.x;   // 65536 = n(128) x k(512)
    int n = idx >> 9, k = idx & 511;
    int sel = k >> 7, kk = k & 127;
    float v = W[sel * 16384 + kk * 128 + n];
    if (sel == 0) v *= bnp[kk];
    Wt[(size_t)((k >> 3) * 128 + n) * 8 + (k & 7)] = (_Float16)v;
}

// bias2[n] = b[n] + sum_k bnp_shift[k] * W[0][k][n]
__global__ void bias2_kernel(const float* __restrict__ W, const float* __restrict__ bnp,
                             const float* __restrict__ b, float* __restrict__ bias2) {
    int n = threadIdx.x;
    float s = b[n];
    for (int k = 0; k < 128; ++k) s += bnp[128 + k] * W[k * 128 + n];
    bias2[n] = s;
}

// ---------------- MFMA Cheb GEMM (row-major A, chunk-major B) ---------------
template <int ACT, int STATS, int OUTH>
__global__ __launch_bounds__(256)
void gemm_mfma(const __half* __restrict__ T0, const __half* __restrict__ T1,
               const __half* __restrict__ T2, const __half* __restrict__ T3,
               const _Float16* __restrict__ Wt, const float* __restrict__ bias2,
               __half* __restrict__ outh, float* __restrict__ outf,
               float* __restrict__ stats, int N) {
    __shared__ float s_sum[128];
    __shared__ float s_sq[128];
    int tid = threadIdx.x;
    if (STATS) {
        if (tid < 128) { s_sum[tid] = 0.f; s_sq[tid] = 0.f; }
        __syncthreads();
    }
    int wave = tid >> 6, lane = tid & 63;
    int wr = wave >> 1, wc = wave & 1;
    int m = lane & 15, quad = lane >> 4;
    int row0 = blockIdx.x * 32 + wr * 16;

    size_t ra = (size_t)(min(row0 + m, N - 1)) * HDIM;
    int nbase = wc * 64 + m;

    const __half* Ts[4] = {T0, T1, T2, T3};
    f32x4 acc[4];
#pragma unroll
    for (int ct = 0; ct < 4; ++ct) acc[ct] = (f32x4){0.f, 0.f, 0.f, 0.f};

#pragma unroll
    for (int ktp = 0; ktp < 2; ++ktp) {
        int ko0 = (ktp * 2) * 32 + quad * 8;
        int ko1 = (ktp * 2 + 1) * 32 + quad * 8;
        f16x8 a0[4], a1[4];
#pragma unroll
        for (int sel = 0; sel < 4; ++sel) {
            const _Float16* Tp = (const _Float16*)Ts[sel];
            a0[sel] = *(const f16x8*)(Tp + ra + ko0);
            a1[sel] = *(const f16x8*)(Tp + ra + ko1);
        }
#pragma unroll
        for (int sel = 0; sel < 4; ++sel) {
            int c0 = sel * 16 + ktp * 8 + quad;       // k-chunk of ko0
            int c1 = c0 + 4;                          // k-chunk of ko1
#pragma unroll
            for (int ct = 0; ct < 4; ++ct) {
                f16x8 b0 = *(const f16x8*)(Wt + ((size_t)c0 * 128 + nbase + ct * 16) * 8);
                f16x8 b1 = *(const f16x8*)(Wt + ((size_t)c1 * 128 + nbase + ct * 16) * 8);
                acc[ct] = __builtin_amdgcn_mfma_f32_16x16x32_f16(a0[sel], b0, acc[ct], 0, 0, 0);
                acc[ct] = __builtin_amdgcn_mfma_f32_16x16x32_f16(a1[sel], b1, acc[ct], 0, 0, 0);
            }
        }
    }

    // epilogue: D tile ct: row = row0 + quad*4 + r, col = wc*64 + ct*16 + m
    float csum[4] = {}, csq[4] = {};
#pragma unroll
    for (int ct = 0; ct < 4; ++ct) {
        int col = wc * 64 + ct * 16 + m;
        float bv = bias2[col];
#pragma unroll
        for (int r = 0; r < 4; ++r) {
            int drow = row0 + quad * 4 + r;
            if (drow < N) {
                float v = acc[ct][r] + bv;
                if (ACT == 1) v = v >= 0.f ? v : 0.01f * v;
                else if (ACT == 2) v = fmaxf(v, 0.f);
                if (OUTH) outh[(size_t)drow * HDIM + col] = __float2half(v);
                else      outf[(size_t)drow * HDIM + col] = v;
                if (STATS) { csum[ct] += v; csq[ct] += v * v; }
            }
        }
    }
    if (STATS) {
#pragma unroll
        for (int ct = 0; ct < 4; ++ct) {
            int col = wc * 64 + ct * 16 + m;
            atomicAdd(&s_sum[col], csum[ct]);
            atomicAdd(&s_sq[col], csq[ct]);
        }
        __syncthreads();
        if (tid < 128) {
            float* sp = stats + (size_t)(blockIdx.x & (NSLOT - 1)) * 256;
            atomicAdd(&sp[tid], s_sum[tid]);
            atomicAdd(&sp[128 + tid], s_sq[tid]);
        }
    }
}

// ---------------- layer-1 (input dim 3) fused GEMM, grid-stride ------------
__global__ __launch_bounds__(256)
void gemm1_kernel(const float* __restrict__ x, const float* __restrict__ t1,
                  const float* __restrict__ t2, const float* __restrict__ t3,
                  const float* __restrict__ W1, const float* __restrict__ b1,
                  __half* __restrict__ out, float* __restrict__ stats, int N) {
    __shared__ float s_sum[128];
    __shared__ float s_sq[128];
    int tid = threadIdx.x;
    int c = tid & 127;
    if (tid < 128) { s_sum[tid] = 0.f; s_sq[tid] = 0.f; }
    __syncthreads();
    float wreg[12];
#pragma unroll
    for (int i = 0; i < 12; ++i) wreg[i] = W1[i * 128 + c];
    float bias = b1[c];
    const float* Ts[4] = {x, t1, t2, t3};
    float lsum = 0.f, lsq = 0.f;
    for (int row = blockIdx.x * 2 + (tid >> 7); row < N; row += gridDim.x * 2) {
        float v = bias;
#pragma unroll
        for (int k = 0; k < 4; ++k) {
            const float* t = Ts[k];
#pragma unroll
            for (int d = 0; d < 3; ++d)
                v += t[row * 3 + d] * wreg[k * 3 + d];
        }
        v = v >= 0.f ? v : 0.01f * v;   // leaky_relu
        out[(size_t)row * HDIM + c] = __float2half(v);
        lsum += v; lsq += v * v;
    }
    atomicAdd(&s_sum[c], lsum);
    atomicAdd(&s_sq[c], lsq);
    __syncthreads();
    if (tid < 128) {
        float* sp = stats + (size_t)(blockIdx.x & (NSLOT - 1)) * 256;
        atomicAdd(&sp[tid], s_sum[tid]);
        atomicAdd(&sp[128 + tid], s_sq[tid]);
    }
}

// ---------------- BN finalize: reduce NSLOT stats copies -> (scale, shift) --
__global__ void bnfin_kernel(const float* __restrict__ stats, const float* __restrict__ g,
                             const float* __restrict__ be, float* __restrict__ bnp, float invN) {
    int c = threadIdx.x;  // 128 threads
    float s0 = 0.f, s1 = 0.f;
#pragma unroll 4
    for (int k = 0; k < NSLOT; ++k) {
        s0 += stats[k * 256 + c];
        s1 += stats[k * 256 + 128 + c];
    }
    float m = s0 * invN;
    float v = s1 * invN - m * m;
    float sc = g[c] * rsqrtf(v + 1e-5f);
    bnp[c] = sc;
    bnp[128 + c] = be[c] - m * sc;
}

// ---------------- final: L2-normalize row + project to 3 ----------------
__global__ void final_kernel(const float* __restrict__ Z, const float* __restrict__ Wm,
                             const float* __restrict__ bm, float* __restrict__ out, int N) {
    int gid = blockIdx.x * blockDim.x + threadIdx.x;
    int node = gid >> 6;
    int lane = threadIdx.x & 63;
    if (node >= N) return;
    const float* z = Z + (size_t)node * HDIM;
    float z0 = z[lane], z1 = z[lane + 64];
    float sq = z0 * z0 + z1 * z1;
    float d0 = z0 * Wm[lane * 3 + 0] + z1 * Wm[(lane + 64) * 3 + 0];
    float d1 = z0 * Wm[lane * 3 + 1] + z1 * Wm[(lane + 64) * 3 + 1];
    float d2 = z0 * Wm[lane * 3 + 2] + z1 * Wm[(lane + 64) * 3 + 2];
#pragma unroll
    for (int off = 32; off > 0; off >>= 1) {
        sq += __shfl_down(sq, off);
        d0 += __shfl_down(d0, off);
        d1 += __shfl_down(d1, off);
        d2 += __shfl_down(d2, off);
    }
    if (lane == 0) {
        float inv = 1.f / fmaxf(sqrtf(sq), 1e-12f);
        out[node * 3 + 0] = d0 * inv + bm[0];
        out[node * 3 + 1] = d1 * inv + bm[1];
        out[node * 3 + 2] = d2 * inv + bm[2];
    }
}

// ---------------- host ----------------

extern "C" void kernel_launch(void* const* d_in, const int* in_sizes, int n_in,
                              void* d_out, int out_size, void* d_ws, size_t ws_size,
                              hipStream_t stream) {
    const float* x  = (const float*)d_in[0];
    const int*   ei = (const int*)d_in[1];
    const float* W1 = (const float*)d_in[2];
    const float* b1 = (const float*)d_in[3];
    const float* W2 = (const float*)d_in[4];
    const float* b2 = (const float*)d_in[5];
    const float* W3 = (const float*)d_in[6];
    const float* b3 = (const float*)d_in[7];
    const float* W4 = (const float*)d_in[8];
    const float* b4 = (const float*)d_in[9];
    const float* g1 = (const float*)d_in[10];
    const float* be1 = (const float*)d_in[11];
    const float* g2 = (const float*)d_in[12];
    const float* be2 = (const float*)d_in[13];
    const float* g3 = (const float*)d_in[14];
    const float* be3 = (const float*)d_in[15];
    const float* Wm = (const float*)d_in[16];
    const float* bm = (const float*)d_in[17];
    float* out = (float*)d_out;

    const int N = in_sizes[0] / 3;
    const int E = in_sizes[1] / 2;
    const size_t NH = (size_t)N * HDIM;
    const int* src = ei;
    const int* dst = ei + E;

    // ---- workspace layout ----
    char* base = (char*)d_ws;
    int* partS  = (int*)base;            base += (size_t)NSLICE * N * 4;
    int* partD  = (int*)base;            base += (size_t)NSLICE * N * 4;
    int* degD   = (int*)base;            base += (size_t)N * 4;
    int* cursor = (int*)base;            base += (size_t)N * 4;
    int* rp     = (int*)base;            base += (size_t)(N + 2) * 4;
    int* bsum   = (int*)base;            base += (size_t)1024 * 4;
    int2* ev    = (int2*)base;           base += (size_t)E * 8;
    float* dinv = (float*)base;          base += (size_t)N * 4;
    __half* Za  = (__half*)base;         base += NH * 2;
    __half* Zb  = (__half*)base;         base += NH * 2;
    __half* T1  = (__half*)base;         base += NH * 2;
    __half* T2  = (__half*)base;         base += NH * 2;
    __half* T3  = (__half*)base;         base += NH * 2;
    float* Zf   = (float*)base;          base += NH * 4;   // layer-4 out, fp32
    float* x1   = (float*)base;          base += (size_t)N * 3 * 4;
    float* x2   = (float*)base;          base += (size_t)N * 3 * 4;
    float* x3   = (float*)base;          base += (size_t)N * 3 * 4;
    float* stats = (float*)base;         base += (size_t)NSLOT * 256 * 4;
    float* bnp1  = (float*)base;         base += 256 * 4;
    float* bnp2  = (float*)base;         base += 256 * 4;
    float* bnp3  = (float*)base;         base += 256 * 4;
    _Float16* Wt = (_Float16*)base;      base += (size_t)65536 * 2;
    float* bias2 = (float*)base;         base += 128 * 4;

    const int EB = (E + 255) / 256;
    const int NB = (N + 255) / 256;
    const int GB = (N + 31) / 32;         // mfma gemm row tiles (32 rows)
    const int PB = (N + 3) / 4;           // pull128 blocks (4 nodes/block)
    const int NSEG = (N + SEGSZ - 1) / SEGSZ;
    const float invN = 1.f / (float)N;
    const size_t STB = (size_t)NSLOT * 256 * 4;

    // --- CSR build + edge weights ---
    hipMemsetAsync(cursor, 0, (size_t)N * 4, stream);
    hist_kernel<<<NSEG * NSLICE, 256, 0, stream>>>(src, dst, partS, partD, NSEG, N, E);
    reduce_kernel<<<NB, 256, 0, stream>>>(partS, partD, dinv, degD, N);
    scanp1_kernel<<<NB, 256, 0, stream>>>(degD, bsum, N);
    scanp2_kernel<<<1, 1024, 0, stream>>>(bsum, NB);
    scanp3_kernel<<<NB, 256, 0, stream>>>(degD, bsum, rp, N, E);
    scatter_kernel<<<EB, 256, 0, stream>>>(src, dst, dinv, rp, cursor, ev, E);

    // --- layer 1 (dim 3) -> Za (fp16), bnp1 ---
    pull3<<<NB, 256, 0, stream>>>(x,  nullptr, rp, ev, x1, 1.f, N);
    pull3<<<NB, 256, 0, stream>>>(x1, x,       rp, ev, x2, 2.f, N);
    pull3<<<NB, 256, 0, stream>>>(x2, x1,      rp, ev, x3, 2.f, N);
    hipMemsetAsync(stats, 0, STB, stream);
    gemm1_kernel<<<512, 256, 0, stream>>>(x, x1, x2, x3, W1, b1, Za, stats, N);
    bnfin_kernel<<<1, 128, 0, stream>>>(stats, g1, be1, bnp1, invN);

    // --- layer 2 (leaky + BN): input BN(Za,bnp1) -> Zb, bnp2 ---
    wprep_kernel<<<256, 256, 0, stream>>>(W2, bnp1, Wt);
    bias2_kernel<<<1, 128, 0, stream>>>(W2, bnp1, b2, bias2);
    pull128<1, 0><<<PB, 256, 0, stream>>>(Za, rp, ev, nullptr, bnp1, T1, 1.f, N);
    pull128<0, 1><<<PB, 256, 0, stream>>>(T1, rp, ev, Za, bnp1, T2, 2.f, N);
    pull128<0, 0><<<PB, 256, 0, stream>>>(T2, rp, ev, T1, nullptr, T3, 2.f, N);
    hipMemsetAsync(stats, 0, STB, stream);
    gemm_mfma<1, 1, 1><<<GB, 256, 0, stream>>>(Za, T1, T2, T3, Wt, bias2, Zb, nullptr, stats, N);
    bnfin_kernel<<<1, 128, 0, stream>>>(stats, g2, be2, bnp2, invN);

    // --- layer 3 (relu + BN): input BN(Zb,bnp2) -> Za, bnp3 ---
    wprep_kernel<<<256, 256, 0, stream>>>(W3, bnp2, Wt);
    bias2_kernel<<<1, 128, 0, stream>>>(W3, bnp2, b3, bias2);
    pull128<1, 0><<<PB, 256, 0, stream>>>(Zb, rp, ev, nullptr, bnp2, T1, 1.f, N);
    pull128<0, 1><<<PB, 256, 0, stream>>>(T1, rp, ev, Zb, bnp2, T2, 2.f, N);
    pull128<0, 0><<<PB, 256, 0, stream>>>(T2, rp, ev, T1, nullptr, T3, 2.f, N);
    hipMemsetAsync(stats, 0, STB, stream);
    gemm_mfma<2, 1, 1><<<GB, 256, 0, stream>>>(Zb, T1, T2, T3, Wt, bias2, Za, nullptr, stats, N);
    bnfin_kernel<<<1, 128, 0, stream>>>(stats, g3, be3, bnp3, invN);

    // --- layer 4 (no act/BN): input BN(Za,bnp3) -> Zf (fp32) ---
    wprep_kernel<<<256, 256, 0, stream>>>(W4, bnp3, Wt);
    bias2_kernel<<<1, 128, 0, stream>>>(W4, bnp3, b4, bias2);
    pull128<1, 0><<<PB, 256, 0, stream>>>(Za, rp, ev, nullptr, bnp3, T1, 1.f, N);
    pull128<0, 1><<<PB, 256, 0, stream>>>(T1, rp, ev, Za, bnp3, T2, 2.f, N);
    pull128<0, 0><<<PB, 256, 0, stream>>>(T2, rp, ev, T1, nullptr, T3, 2.f, N);
    gemm_mfma<0, 0, 0><<<GB, 256, 0, stream>>>(Za, T1, T2, T3, Wt, bias2, nullptr, Zf, nullptr, N);

    // --- normalize + project ---
    final_kernel<<<(N * 64 + 255) / 256, 256, 0, stream>>>(Zf, Wm, bm, out, N);
}

// Round 15
// 762.985 us; speedup vs baseline: 2.3986x; 1.0081x over previous
//
#include <hip/hip_runtime.h>
#include <hip/hip_fp16.h>
#include <math.h>

#define HDIM 128
#define NSLOT 32    // stats copies to spread atomic contention
#define SEGSZ 6272  // histogram segment size (LDS ints)
#define NSLICE 64   // edge slices for histogram

typedef _Float16 f16x8 __attribute__((ext_vector_type(8)));
typedef float f32x4 __attribute__((ext_vector_type(4)));

// ---------------- degree histograms via LDS segments (no global atomics) ----
__global__ __launch_bounds__(256)
void hist_kernel(const int* __restrict__ src, const int* __restrict__ dst,
                 int* __restrict__ partS, int* __restrict__ partD,
                 int nseg, int N, int E) {
    __shared__ int hS[SEGSZ];
    __shared__ int hD[SEGSZ];
    int tid = threadIdx.x;
    int seg = blockIdx.x % nseg;
    int slice = blockIdx.x / nseg;
    int seg0 = seg * SEGSZ;
    for (int i = tid; i < SEGSZ; i += 256) { hS[i] = 0; hD[i] = 0; }
    __syncthreads();
    int chunk = (E + NSLICE - 1) / NSLICE;
    int e0 = slice * chunk;
    int e1 = min(E, e0 + chunk);
    for (int e = e0 + tid; e < e1; e += 256) {
        int s = src[e] - seg0;
        int d = dst[e] - seg0;
        if ((unsigned)s < SEGSZ) atomicAdd(&hS[s], 1);
        if ((unsigned)d < SEGSZ) atomicAdd(&hD[d], 1);
    }
    __syncthreads();
    for (int i = tid; i < SEGSZ; i += 256) {
        int node = seg0 + i;
        if (node < N) {
            partS[(size_t)slice * N + node] = hS[i];
            partD[(size_t)slice * N + node] = hD[i];
        }
    }
}

// reduce partials -> dinv (fused rsqrt) and degD
__global__ void reduce_kernel(const int* __restrict__ partS, const int* __restrict__ partD,
                              float* __restrict__ dinv, int* __restrict__ degD, int N) {
    int i = blockIdx.x * blockDim.x + threadIdx.x;
    if (i >= N) return;
    int sS = 0, sD = 0;
#pragma unroll 8
    for (int k = 0; k < NSLICE; ++k) {
        sS += partS[(size_t)k * N + i];
        sD += partD[(size_t)k * N + i];
    }
    dinv[i] = sS > 0 ? rsqrtf((float)sS) : 0.f;
    degD[i] = sD;
}

// ---- 3-phase multi-block exclusive scan of degD -> rp[0..N] ----
__global__ void scanp1_kernel(const int* __restrict__ deg, int* __restrict__ bsum, int N) {
    __shared__ int sdata[256];
    int i = blockIdx.x * 256 + threadIdx.x;
    sdata[threadIdx.x] = i < N ? deg[i] : 0;
    __syncthreads();
    for (int off = 128; off > 0; off >>= 1) {
        if (threadIdx.x < off) sdata[threadIdx.x] += sdata[threadIdx.x + off];
        __syncthreads();
    }
    if (threadIdx.x == 0) bsum[blockIdx.x] = sdata[0];
}

__global__ __launch_bounds__(1024)
void scanp2_kernel(int* __restrict__ bsum, int nb) {
    __shared__ int part[1024];
    int tid = threadIdx.x;
    int v = tid < nb ? bsum[tid] : 0;
    part[tid] = v;
    __syncthreads();
    for (int off = 1; off < 1024; off <<= 1) {
        int t = tid >= off ? part[tid - off] : 0;
        __syncthreads();
        part[tid] += t;
        __syncthreads();
    }
    if (tid < nb) bsum[tid] = part[tid] - v;   // exclusive
}

__global__ void scanp3_kernel(const int* __restrict__ deg, const int* __restrict__ bsum,
                              int* __restrict__ rp, int N, int E) {
    __shared__ int part[256];
    int tid = threadIdx.x;
    int i = blockIdx.x * 256 + tid;
    int v = i < N ? deg[i] : 0;
    part[tid] = v;
    __syncthreads();
    for (int off = 1; off < 256; off <<= 1) {
        int t = tid >= off ? part[tid - off] : 0;
        __syncthreads();
        part[tid] += t;
        __syncthreads();
    }
    if (i < N) rp[i] = bsum[blockIdx.x] + part[tid] - v;
    if (i == 0) rp[N] = E;
}

__global__ void scatter_kernel(const int* __restrict__ src, const int* __restrict__ dst,
                               const float* __restrict__ dinv, const int* __restrict__ rp,
                               int* __restrict__ cursor, int2* __restrict__ ev, int E) {
    int e = blockIdx.x * blockDim.x + threadIdx.x;
    if (e >= E) return;
    int s = src[e], d = dst[e];
    float w = -dinv[s] * dinv[d];
    int pos = atomicAdd(&cursor[d], 1);
    ev[rp[d] + pos] = make_int2(s, __float_as_int(w));
}

// ---------------- pull propagation v2 (16B f16x8 gathers) -------------------
template <int GBN, int PBN>
__global__ __launch_bounds__(256)
void pull128(const __half* __restrict__ t, const int* __restrict__ rp,
             const int2* __restrict__ ev, const __half* __restrict__ prev,
             const float* __restrict__ bnp, __half* __restrict__ outp,
             float alpha, int N) {
    int node = blockIdx.x * 4 + (threadIdx.x >> 6);
    if (node >= N) return;
    int lane = threadIdx.x & 63;
    int c8 = (lane & 15) * 8;     // 8-channel group
    int slot = lane >> 4;         // edge slot 0..3
    const _Float16* tp = (const _Float16*)t;

    float scv[8], shv[8];
    if (GBN || PBN) {
#pragma unroll
        for (int i = 0; i < 8; ++i) { scv[i] = bnp[c8 + i]; shv[i] = bnp[128 + c8 + i]; }
    }

    int b = rp[node], e = rp[node + 1];
    float acc0[8] = {}, acc1[8] = {};
    int j = b;
    for (; j + 8 <= e; j += 8) {
        int2 s0 = ev[j + slot];
        int2 s1 = ev[j + 4 + slot];
        f16x8 r0 = *(const f16x8*)(tp + (size_t)s0.x * HDIM + c8);
        f16x8 r1 = *(const f16x8*)(tp + (size_t)s1.x * HDIM + c8);
        float w0 = __int_as_float(s0.y), w1 = __int_as_float(s1.y);
#pragma unroll
        for (int i = 0; i < 8; ++i) {
            float v0 = (float)r0[i], v1 = (float)r1[i];
            if (GBN) { v0 = v0 * scv[i] + shv[i]; v1 = v1 * scv[i] + shv[i]; }
            acc0[i] += w0 * v0; acc1[i] += w1 * v1;
        }
    }
    for (; j < e; j += 4) {
        int idx = j + slot;
        if (idx < e) {
            int2 s0 = ev[idx];
            f16x8 r0 = *(const f16x8*)(tp + (size_t)s0.x * HDIM + c8);
            float w0 = __int_as_float(s0.y);
#pragma unroll
            for (int i = 0; i < 8; ++i) {
                float v0 = (float)r0[i];
                if (GBN) v0 = v0 * scv[i] + shv[i];
                acc0[i] += w0 * v0;
            }
        }
    }
    float s[8];
#pragma unroll
    for (int i = 0; i < 8; ++i) {
        s[i] = acc0[i] + acc1[i];
        s[i] += __shfl_xor(s[i], 16);
        s[i] += __shfl_xor(s[i], 32);
    }
    if (lane < 16) {
        size_t o = (size_t)node * HDIM + c8;
        float r[8];
#pragma unroll
        for (int i = 0; i < 8; ++i) r[i] = alpha * s[i];
        if (!GBN) {
            f16x8 pv = *(const f16x8*)((const _Float16*)prev + o);
#pragma unroll
            for (int i = 0; i < 8; ++i) {
                float p = (float)pv[i];
                if (PBN) p = p * scv[i] + shv[i];
                r[i] -= p;
            }
        }
        f16x8 h;
#pragma unroll
        for (int i = 0; i < 8; ++i) h[i] = (_Float16)r[i];
        *(f16x8*)((_Float16*)outp + o) = h;
    }
}

__global__ void pull3(const float* __restrict__ t, const float* __restrict__ prev,
                      const int* __restrict__ rp, const int2* __restrict__ ev,
                      float* __restrict__ outp, float alpha, int N) {
    int node = blockIdx.x * blockDim.x + threadIdx.x;
    if (node >= N) return;
    int b = rp[node], e = rp[node + 1];
    float a0 = 0.f, a1 = 0.f, a2 = 0.f;
    for (int j = b; j < e; ++j) {
        int2 sw = ev[j];
        float w = __int_as_float(sw.y);
        const float* r = t + (size_t)sw.x * 3;
        a0 += w * r[0]; a1 += w * r[1]; a2 += w * r[2];
    }
    float r0 = alpha * a0, r1 = alpha * a1, r2 = alpha * a2;
    if (prev) {
        r0 -= prev[node * 3 + 0];
        r1 -= prev[node * 3 + 1];
        r2 -= prev[node * 3 + 2];
    }
    outp[node * 3 + 0] = r0;
    outp[node * 3 + 1] = r1;
    outp[node * 3 + 2] = r2;
}

// ---------------- weight prep: fold BN(T0), k-chunk-major fp16 --------------
__global__ void wprep_kernel(const float* __restrict__ W, const float* __restrict__ bnp,
                             _Float16* __restrict__ Wt) {
    int idx = blockIdx.x * 256 + threadIdx.x;   // 65536 = n(128) x k(512)
    int n = idx >> 9, k = idx & 511;
    int sel = k >> 7, kk = k & 127;
    float v = W[sel * 16384 + kk * 128 + n];
    if (sel == 0) v *= bnp[kk];
    Wt[(size_t)((k >> 3) * 128 + n) * 8 + (k & 7)] = (_Float16)v;
}

// bias2[n] = b[n] + sum_k bnp_shift[k] * W[0][k][n]
__global__ void bias2_kernel(const float* __restrict__ W, const float* __restrict__ bnp,
                             const float* __restrict__ b, float* __restrict__ bias2) {
    int n = threadIdx.x;
    float s = b[n];
    for (int k = 0; k < 128; ++k) s += bnp[128 + k] * W[k * 128 + n];
    bias2[n] = s;
}

// ---------------- MFMA Cheb GEMM (row-major A, chunk-major B) ---------------
// Block = 32 rows x 128 cols; 4 waves 2x2. ALL 16 A-loads batched upfront
// (16 x 16B in flight per wave -> ~2x HBM bytes-in-flight vs kt-pair batch).
template <int ACT, int STATS, int OUTH>
__global__ __launch_bounds__(256)
void gemm_mfma(const __half* __restrict__ T0, const __half* __restrict__ T1,
               const __half* __restrict__ T2, const __half* __restrict__ T3,
               const _Float16* __restrict__ Wt, const float* __restrict__ bias2,
               __half* __restrict__ outh, float* __restrict__ outf,
               float* __restrict__ stats, int N) {
    __shared__ float s_sum[128];
    __shared__ float s_sq[128];
    int tid = threadIdx.x;
    if (STATS) {
        if (tid < 128) { s_sum[tid] = 0.f; s_sq[tid] = 0.f; }
        __syncthreads();
    }
    int wave = tid >> 6, lane = tid & 63;
    int wr = wave >> 1, wc = wave & 1;
    int m = lane & 15, quad = lane >> 4;
    int row0 = blockIdx.x * 32 + wr * 16;

    size_t ra = (size_t)(min(row0 + m, N - 1)) * HDIM;
    int nbase = wc * 64 + m;

    const __half* Ts[4] = {T0, T1, T2, T3};
    f32x4 acc[4];
#pragma unroll
    for (int ct = 0; ct < 4; ++ct) acc[ct] = (f32x4){0.f, 0.f, 0.f, 0.f};

    // batch all 16 A fragment loads (4 kt x 4 sel)
    f16x8 a[16];
#pragma unroll
    for (int kt = 0; kt < 4; ++kt) {
        int ko = kt * 32 + quad * 8;
#pragma unroll
        for (int sel = 0; sel < 4; ++sel)
            a[kt * 4 + sel] = *(const f16x8*)((const _Float16*)Ts[sel] + ra + ko);
    }

#pragma unroll
    for (int kt = 0; kt < 4; ++kt) {
#pragma unroll
        for (int sel = 0; sel < 4; ++sel) {
            int c0 = sel * 16 + kt * 4 + quad;        // k-chunk index
#pragma unroll
            for (int ct = 0; ct < 4; ++ct) {
                f16x8 b0 = *(const f16x8*)(Wt + ((size_t)c0 * 128 + nbase + ct * 16) * 8);
                acc[ct] = __builtin_amdgcn_mfma_f32_16x16x32_f16(a[kt * 4 + sel], b0, acc[ct], 0, 0, 0);
            }
        }
    }

    // epilogue: D tile ct: row = row0 + quad*4 + r, col = wc*64 + ct*16 + m
    float csum[4] = {}, csq[4] = {};
#pragma unroll
    for (int ct = 0; ct < 4; ++ct) {
        int col = wc * 64 + ct * 16 + m;
        float bv = bias2[col];
#pragma unroll
        for (int r = 0; r < 4; ++r) {
            int drow = row0 + quad * 4 + r;
            if (drow < N) {
                float v = acc[ct][r] + bv;
                if (ACT == 1) v = v >= 0.f ? v : 0.01f * v;
                else if (ACT == 2) v = fmaxf(v, 0.f);
                if (OUTH) outh[(size_t)drow * HDIM + col] = __float2half(v);
                else      outf[(size_t)drow * HDIM + col] = v;
                if (STATS) { csum[ct] += v; csq[ct] += v * v; }
            }
        }
    }
    if (STATS) {
#pragma unroll
        for (int ct = 0; ct < 4; ++ct) {
            int col = wc * 64 + ct * 16 + m;
            atomicAdd(&s_sum[col], csum[ct]);
            atomicAdd(&s_sq[col], csq[ct]);
        }
        __syncthreads();
        if (tid < 128) {
            float* sp = stats + (size_t)(blockIdx.x & (NSLOT - 1)) * 256;
            atomicAdd(&sp[tid], s_sum[tid]);
            atomicAdd(&sp[128 + tid], s_sq[tid]);
        }
    }
}

// ---------------- layer-1 (input dim 3) fused GEMM, grid-stride ------------
__global__ __launch_bounds__(256)
void gemm1_kernel(const float* __restrict__ x, const float* __restrict__ t1,
                  const float* __restrict__ t2, const float* __restrict__ t3,
                  const float* __restrict__ W1, const float* __restrict__ b1,
                  __half* __restrict__ out, float* __restrict__ stats, int N) {
    __shared__ float s_sum[128];
    __shared__ float s_sq[128];
    int tid = threadIdx.x;
    int c = tid & 127;
    if (tid < 128) { s_sum[tid] = 0.f; s_sq[tid] = 0.f; }
    __syncthreads();
    float wreg[12];
#pragma unroll
    for (int i = 0; i < 12; ++i) wreg[i] = W1[i * 128 + c];
    float bias = b1[c];
    const float* Ts[4] = {x, t1, t2, t3};
    float lsum = 0.f, lsq = 0.f;
    for (int row = blockIdx.x * 2 + (tid >> 7); row < N; row += gridDim.x * 2) {
        float v = bias;
#pragma unroll
        for (int k = 0; k < 4; ++k) {
            const float* t = Ts[k];
#pragma unroll
            for (int d = 0; d < 3; ++d)
                v += t[row * 3 + d] * wreg[k * 3 + d];
        }
        v = v >= 0.f ? v : 0.01f * v;   // leaky_relu
        out[(size_t)row * HDIM + c] = __float2half(v);
        lsum += v; lsq += v * v;
    }
    atomicAdd(&s_sum[c], lsum);
    atomicAdd(&s_sq[c], lsq);
    __syncthreads();
    if (tid < 128) {
        float* sp = stats + (size_t)(blockIdx.x & (NSLOT - 1)) * 256;
        atomicAdd(&sp[tid], s_sum[tid]);
        atomicAdd(&sp[128 + tid], s_sq[tid]);
    }
}

// ---------------- BN finalize: reduce NSLOT stats copies -> (scale, shift) --
__global__ void bnfin_kernel(const float* __restrict__ stats, const float* __restrict__ g,
                             const float* __restrict__ be, float* __restrict__ bnp, float invN) {
    int c = threadIdx.x;  // 128 threads
    float s0 = 0.f, s1 = 0.f;
#pragma unroll 4
    for (int k = 0; k < NSLOT; ++k) {
        s0 += stats[k * 256 + c];
        s1 += stats[k * 256 + 128 + c];
    }
    float m = s0 * invN;
    float v = s1 * invN - m * m;
    float sc = g[c] * rsqrtf(v + 1e-5f);
    bnp[c] = sc;
    bnp[128 + c] = be[c] - m * sc;
}

// ---------------- final: L2-normalize row + project to 3 ----------------
__global__ void final_kernel(const float* __restrict__ Z, const float* __restrict__ Wm,
                             const float* __restrict__ bm, float* __restrict__ out, int N) {
    int gid = blockIdx.x * blockDim.x + threadIdx.x;
    int node = gid >> 6;
    int lane = threadIdx.x & 63;
    if (node >= N) return;
    const float* z = Z + (size_t)node * HDIM;
    float z0 = z[lane], z1 = z[lane + 64];
    float sq = z0 * z0 + z1 * z1;
    float d0 = z0 * Wm[lane * 3 + 0] + z1 * Wm[(lane + 64) * 3 + 0];
    float d1 = z0 * Wm[lane * 3 + 1] + z1 * Wm[(lane + 64) * 3 + 1];
    float d2 = z0 * Wm[lane * 3 + 2] + z1 * Wm[(lane + 64) * 3 + 2];
#pragma unroll
    for (int off = 32; off > 0; off >>= 1) {
        sq += __shfl_down(sq, off);
        d0 += __shfl_down(d0, off);
        d1 += __shfl_down(d1, off);
        d2 += __shfl_down(d2, off);
    }
    if (lane == 0) {
        float inv = 1.f / fmaxf(sqrtf(sq), 1e-12f);
        out[node * 3 + 0] = d0 * inv + bm[0];
        out[node * 3 + 1] = d1 * inv + bm[1];
        out[node * 3 + 2] = d2 * inv + bm[2];
    }
}

// ---------------- host ----------------

extern "C" void kernel_launch(void* const* d_in, const int* in_sizes, int n_in,
                              void* d_out, int out_size, void* d_ws, size_t ws_size,
                              hipStream_t stream) {
    const float* x  = (const float*)d_in[0];
    const int*   ei = (const int*)d_in[1];
    const float* W1 = (const float*)d_in[2];
    const float* b1 = (const float*)d_in[3];
    const float* W2 = (const float*)d_in[4];
    const float* b2 = (const float*)d_in[5];
    const float* W3 = (const float*)d_in[6];
    const float* b3 = (const float*)d_in[7];
    const float* W4 = (const float*)d_in[8];
    const float* b4 = (const float*)d_in[9];
    const float* g1 = (const float*)d_in[10];
    const float* be1 = (const float*)d_in[11];
    const float* g2 = (const float*)d_in[12];
    const float* be2 = (const float*)d_in[13];
    const float* g3 = (const float*)d_in[14];
    const float* be3 = (const float*)d_in[15];
    const float* Wm = (const float*)d_in[16];
    const float* bm = (const float*)d_in[17];
    float* out = (float*)d_out;

    const int N = in_sizes[0] / 3;
    const int E = in_sizes[1] / 2;
    const size_t NH = (size_t)N * HDIM;
    const int* src = ei;
    const int* dst = ei + E;

    // ---- workspace layout ----
    char* base = (char*)d_ws;
    int* partS  = (int*)base;            base += (size_t)NSLICE * N * 4;
    int* partD  = (int*)base;            base += (size_t)NSLICE * N * 4;
    int* degD   = (int*)base;            base += (size_t)N * 4;
    int* cursor = (int*)base;            base += (size_t)N * 4;
    int* rp     = (int*)base;            base += (size_t)(N + 2) * 4;
    int* bsum   = (int*)base;            base += (size_t)1024 * 4;
    int2* ev    = (int2*)base;           base += (size_t)E * 8;
    float* dinv = (float*)base;          base += (size_t)N * 4;
    __half* Za  = (__half*)base;         base += NH * 2;
    __half* Zb  = (__half*)base;         base += NH * 2;
    __half* T1  = (__half*)base;         base += NH * 2;
    __half* T2  = (__half*)base;         base += NH * 2;
    __half* T3  = (__half*)base;         base += NH * 2;
    float* Zf   = (float*)base;          base += NH * 4;   // layer-4 out, fp32
    float* x1   = (float*)base;          base += (size_t)N * 3 * 4;
    float* x2   = (float*)base;          base += (size_t)N * 3 * 4;
    float* x3   = (float*)base;          base += (size_t)N * 3 * 4;
    float* stats = (float*)base;         base += (size_t)NSLOT * 256 * 4;
    float* bnp1  = (float*)base;         base += 256 * 4;
    float* bnp2  = (float*)base;         base += 256 * 4;
    float* bnp3  = (float*)base;         base += 256 * 4;
    _Float16* Wt = (_Float16*)base;      base += (size_t)65536 * 2;
    float* bias2 = (float*)base;         base += 128 * 4;

    const int EB = (E + 255) / 256;
    const int NB = (N + 255) / 256;
    const int GB = (N + 31) / 32;         // mfma gemm row tiles (32 rows)
    const int PB = (N + 3) / 4;           // pull128 blocks (4 nodes/block)
    const int NSEG = (N + SEGSZ - 1) / SEGSZ;
    const float invN = 1.f / (float)N;
    const size_t STB = (size_t)NSLOT * 256 * 4;

    // --- CSR build + edge weights ---
    hipMemsetAsync(cursor, 0, (size_t)N * 4, stream);
    hist_kernel<<<NSEG * NSLICE, 256, 0, stream>>>(src, dst, partS, partD, NSEG, N, E);
    reduce_kernel<<<NB, 256, 0, stream>>>(partS, partD, dinv, degD, N);
    scanp1_kernel<<<NB, 256, 0, stream>>>(degD, bsum, N);
    scanp2_kernel<<<1, 1024, 0, stream>>>(bsum, NB);
    scanp3_kernel<<<NB, 256, 0, stream>>>(degD, bsum, rp, N, E);
    scatter_kernel<<<EB, 256, 0, stream>>>(src, dst, dinv, rp, cursor, ev, E);

    // --- layer 1 (dim 3) -> Za (fp16), bnp1 ---
    pull3<<<NB, 256, 0, stream>>>(x,  nullptr, rp, ev, x1, 1.f, N);
    pull3<<<NB, 256, 0, stream>>>(x1, x,       rp, ev, x2, 2.f, N);
    pull3<<<NB, 256, 0, stream>>>(x2, x1,      rp, ev, x3, 2.f, N);
    hipMemsetAsync(stats, 0, STB, stream);
    gemm1_kernel<<<512, 256, 0, stream>>>(x, x1, x2, x3, W1, b1, Za, stats, N);
    bnfin_kernel<<<1, 128, 0, stream>>>(stats, g1, be1, bnp1, invN);

    // --- layer 2 (leaky + BN): input BN(Za,bnp1) -> Zb, bnp2 ---
    wprep_kernel<<<256, 256, 0, stream>>>(W2, bnp1, Wt);
    bias2_kernel<<<1, 128, 0, stream>>>(W2, bnp1, b2, bias2);
    pull128<1, 0><<<PB, 256, 0, stream>>>(Za, rp, ev, nullptr, bnp1, T1, 1.f, N);
    pull128<0, 1><<<PB, 256, 0, stream>>>(T1, rp, ev, Za, bnp1, T2, 2.f, N);
    pull128<0, 0><<<PB, 256, 0, stream>>>(T2, rp, ev, T1, nullptr, T3, 2.f, N);
    hipMemsetAsync(stats, 0, STB, stream);
    gemm_mfma<1, 1, 1><<<GB, 256, 0, stream>>>(Za, T1, T2, T3, Wt, bias2, Zb, nullptr, stats, N);
    bnfin_kernel<<<1, 128, 0, stream>>>(stats, g2, be2, bnp2, invN);

    // --- layer 3 (relu + BN): input BN(Zb,bnp2) -> Za, bnp3 ---
    wprep_kernel<<<256, 256, 0, stream>>>(W3, bnp2, Wt);
    bias2_kernel<<<1, 128, 0, stream>>>(W3, bnp2, b3, bias2);
    pull128<1, 0><<<PB, 256, 0, stream>>>(Zb, rp, ev, nullptr, bnp2, T1, 1.f, N);
    pull128<0, 1><<<PB, 256, 0, stream>>>(T1, rp, ev, Zb, bnp2, T2, 2.f, N);
    pull128<0, 0><<<PB, 256, 0, stream>>>(T2, rp, ev, T1, nullptr, T3, 2.f, N);
    hipMemsetAsync(stats, 0, STB, stream);
    gemm_mfma<2, 1, 1><<<GB, 256, 0, stream>>>(Zb, T1, T2, T3, Wt, bias2, Za, nullptr, stats, N);
    bnfin_kernel<<<1, 128, 0, stream>>>(stats, g3, be3, bnp3, invN);

    // --- layer 4 (no act/BN): input BN(Za,bnp3) -> Zf (fp32) ---
    wprep_kernel<<<256, 256, 0, stream>>>(W4, bnp3, Wt);
    bias2_kernel<<<1, 128, 0, stream>>>(W4, bnp3, b4, bias2);
    pull128<1, 0><<<PB, 256, 0, stream>>>(Za, rp, ev, nullptr, bnp3, T1, 1.f, N);
    pull128<0, 1><<<PB, 256, 0, stream>>>(T1, rp, ev, Za, bnp3, T2, 2.f, N);
    pull128<0, 0><<<PB, 256, 0, stream>>>(T2, rp, ev, T1, nullptr, T3, 2.f, N);
    gemm_mfma<0, 0, 0><<<GB, 256, 0, stream>>>(Za, T1, T2, T3, Wt, bias2, nullptr, Zf, nullptr, N);

    // --- normalize + project ---
    final_kernel<<<(N * 64 + 255) / 256, 256, 0, stream>>>(Zf, Wm, bm, out, N);
}

// Round 16
// 732.400 us; speedup vs baseline: 2.4988x; 1.0418x over previous
//
#include <hip/hip_runtime.h>
#include <hip/hip_fp16.h>
#include <math.h>

#define HDIM 128
#define NSLOT 32    // stats copies to spread atomic contention
#define SEGSZ 6272  // histogram segment size (LDS ints)
#define NSLICE 64   // edge slices for histogram

typedef _Float16 f16x8 __attribute__((ext_vector_type(8)));
typedef float f32x4 __attribute__((ext_vector_type(4)));

// ---------------- degree histograms via LDS segments (no global atomics) ----
__global__ __launch_bounds__(256)
void hist_kernel(const int* __restrict__ src, const int* __restrict__ dst,
                 int* __restrict__ partS, int* __restrict__ partD,
                 int nseg, int N, int E) {
    __shared__ int hS[SEGSZ];
    __shared__ int hD[SEGSZ];
    int tid = threadIdx.x;
    int seg = blockIdx.x % nseg;
    int slice = blockIdx.x / nseg;
    int seg0 = seg * SEGSZ;
    for (int i = tid; i < SEGSZ; i += 256) { hS[i] = 0; hD[i] = 0; }
    __syncthreads();
    int chunk = (E + NSLICE - 1) / NSLICE;
    int e0 = slice * chunk;
    int e1 = min(E, e0 + chunk);
    for (int e = e0 + tid; e < e1; e += 256) {
        int s = src[e] - seg0;
        int d = dst[e] - seg0;
        if ((unsigned)s < SEGSZ) atomicAdd(&hS[s], 1);
        if ((unsigned)d < SEGSZ) atomicAdd(&hD[d], 1);
    }
    __syncthreads();
    for (int i = tid; i < SEGSZ; i += 256) {
        int node = seg0 + i;
        if (node < N) {
            partS[(size_t)slice * N + node] = hS[i];
            partD[(size_t)slice * N + node] = hD[i];
        }
    }
}

// reduce partials -> dinv (fused rsqrt) and degD
__global__ void reduce_kernel(const int* __restrict__ partS, const int* __restrict__ partD,
                              float* __restrict__ dinv, int* __restrict__ degD, int N) {
    int i = blockIdx.x * blockDim.x + threadIdx.x;
    if (i >= N) return;
    int sS = 0, sD = 0;
#pragma unroll 8
    for (int k = 0; k < NSLICE; ++k) {
        sS += partS[(size_t)k * N + i];
        sD += partD[(size_t)k * N + i];
    }
    dinv[i] = sS > 0 ? rsqrtf((float)sS) : 0.f;
    degD[i] = sD;
}

// ---- 3-phase multi-block exclusive scan of degD -> rp[0..N] ----
__global__ void scanp1_kernel(const int* __restrict__ deg, int* __restrict__ bsum, int N) {
    __shared__ int sdata[256];
    int i = blockIdx.x * 256 + threadIdx.x;
    sdata[threadIdx.x] = i < N ? deg[i] : 0;
    __syncthreads();
    for (int off = 128; off > 0; off >>= 1) {
        if (threadIdx.x < off) sdata[threadIdx.x] += sdata[threadIdx.x + off];
        __syncthreads();
    }
    if (threadIdx.x == 0) bsum[blockIdx.x] = sdata[0];
}

__global__ __launch_bounds__(1024)
void scanp2_kernel(int* __restrict__ bsum, int nb) {
    __shared__ int part[1024];
    int tid = threadIdx.x;
    int v = tid < nb ? bsum[tid] : 0;
    part[tid] = v;
    __syncthreads();
    for (int off = 1; off < 1024; off <<= 1) {
        int t = tid >= off ? part[tid - off] : 0;
        __syncthreads();
        part[tid] += t;
        __syncthreads();
    }
    if (tid < nb) bsum[tid] = part[tid] - v;   // exclusive
}

__global__ void scanp3_kernel(const int* __restrict__ deg, const int* __restrict__ bsum,
                              int* __restrict__ rp, int N, int E) {
    __shared__ int part[256];
    int tid = threadIdx.x;
    int i = blockIdx.x * 256 + tid;
    int v = i < N ? deg[i] : 0;
    part[tid] = v;
    __syncthreads();
    for (int off = 1; off < 256; off <<= 1) {
        int t = tid >= off ? part[tid - off] : 0;
        __syncthreads();
        part[tid] += t;
        __syncthreads();
    }
    if (i < N) rp[i] = bsum[blockIdx.x] + part[tid] - v;
    if (i == 0) rp[N] = E;
}

__global__ void scatter_kernel(const int* __restrict__ src, const int* __restrict__ dst,
                               const float* __restrict__ dinv, const int* __restrict__ rp,
                               int* __restrict__ cursor, int2* __restrict__ ev, int E) {
    int e = blockIdx.x * blockDim.x + threadIdx.x;
    if (e >= E) return;
    int s = src[e], d = dst[e];
    float w = -dinv[s] * dinv[d];
    int pos = atomicAdd(&cursor[d], 1);
    ev[rp[d] + pos] = make_int2(s, __float_as_int(w));
}

// ---------------- pure pull: out = L * g(t) ---------------------------------
// Chebyshev recursion folded into GEMM weights -> no prev, no alpha.
// GBN: apply BN (scale/shift) to gathered rows.
template <int GBN>
__global__ __launch_bounds__(256)
void pull128(const __half* __restrict__ t, const int* __restrict__ rp,
             const int2* __restrict__ ev, const float* __restrict__ bnp,
             __half* __restrict__ outp, int N) {
    int node = blockIdx.x * 4 + (threadIdx.x >> 6);
    if (node >= N) return;
    int lane = threadIdx.x & 63;
    int c8 = (lane & 15) * 8;     // 8-channel group
    int slot = lane >> 4;         // edge slot 0..3
    const _Float16* tp = (const _Float16*)t;

    float scv[8], shv[8];
    if (GBN) {
#pragma unroll
        for (int i = 0; i < 8; ++i) { scv[i] = bnp[c8 + i]; shv[i] = bnp[128 + c8 + i]; }
    }

    int b = rp[node], e = rp[node + 1];
    float acc0[8] = {}, acc1[8] = {};
    int j = b;
    for (; j + 8 <= e; j += 8) {
        int2 s0 = ev[j + slot];
        int2 s1 = ev[j + 4 + slot];
        f16x8 r0 = *(const f16x8*)(tp + (size_t)s0.x * HDIM + c8);
        f16x8 r1 = *(const f16x8*)(tp + (size_t)s1.x * HDIM + c8);
        float w0 = __int_as_float(s0.y), w1 = __int_as_float(s1.y);
#pragma unroll
        for (int i = 0; i < 8; ++i) {
            float v0 = (float)r0[i], v1 = (float)r1[i];
            if (GBN) { v0 = v0 * scv[i] + shv[i]; v1 = v1 * scv[i] + shv[i]; }
            acc0[i] += w0 * v0; acc1[i] += w1 * v1;
        }
    }
    for (; j < e; j += 4) {
        int idx = j + slot;
        if (idx < e) {
            int2 s0 = ev[idx];
            f16x8 r0 = *(const f16x8*)(tp + (size_t)s0.x * HDIM + c8);
            float w0 = __int_as_float(s0.y);
#pragma unroll
            for (int i = 0; i < 8; ++i) {
                float v0 = (float)r0[i];
                if (GBN) v0 = v0 * scv[i] + shv[i];
                acc0[i] += w0 * v0;
            }
        }
    }
    float s[8];
#pragma unroll
    for (int i = 0; i < 8; ++i) {
        s[i] = acc0[i] + acc1[i];
        s[i] += __shfl_xor(s[i], 16);
        s[i] += __shfl_xor(s[i], 32);
    }
    if (lane < 16) {
        size_t o = (size_t)node * HDIM + c8;
        f16x8 h;
#pragma unroll
        for (int i = 0; i < 8; ++i) h[i] = (_Float16)s[i];
        *(f16x8*)((_Float16*)outp + o) = h;
    }
}

__global__ void pull3(const float* __restrict__ t, const float* __restrict__ prev,
                      const int* __restrict__ rp, const int2* __restrict__ ev,
                      float* __restrict__ outp, float alpha, int N) {
    int node = blockIdx.x * blockDim.x + threadIdx.x;
    if (node >= N) return;
    int b = rp[node], e = rp[node + 1];
    float a0 = 0.f, a1 = 0.f, a2 = 0.f;
    for (int j = b; j < e; ++j) {
        int2 sw = ev[j];
        float w = __int_as_float(sw.y);
        const float* r = t + (size_t)sw.x * 3;
        a0 += w * r[0]; a1 += w * r[1]; a2 += w * r[2];
    }
    float r0 = alpha * a0, r1 = alpha * a1, r2 = alpha * a2;
    if (prev) {
        r0 -= prev[node * 3 + 0];
        r1 -= prev[node * 3 + 1];
        r2 -= prev[node * 3 + 2];
    }
    outp[node * 3 + 0] = r0;
    outp[node * 3 + 1] = r1;
    outp[node * 3 + 2] = r2;
}

// ---------------- weight prep: Chebyshev-fold + BN-fold, k-chunk-major fp16 -
// Z = x@(W0-W2)*BN + U1@(W1-3W3) + U2@(2W2) + U3@(4W3) + bias2
// Layout: Wt[((k>>3)*128 + n)*8 + (k&7)], k = sel*128 + kk.
__global__ void wprep_kernel(const float* __restrict__ W, const float* __restrict__ bnp,
                             _Float16* __restrict__ Wt) {
    int idx = blockIdx.x * 256 + threadIdx.x;   // 65536 = n(128) x k(512)
    int n = idx >> 9, k = idx & 511;
    int sel = k >> 7, kk = k & 127;
    int o = kk * 128 + n;
    float v;
    if (sel == 0)      v = (W[o] - W[2 * 16384 + o]) * bnp[kk];
    else if (sel == 1) v = W[16384 + o] - 3.f * W[3 * 16384 + o];
    else if (sel == 2) v = 2.f * W[2 * 16384 + o];
    else               v = 4.f * W[3 * 16384 + o];
    Wt[(size_t)((k >> 3) * 128 + n) * 8 + (k & 7)] = (_Float16)v;
}

// bias2[n] = b[n] + sum_k bnp_shift[k] * (W0[k][n] - W2[k][n])
__global__ void bias2_kernel(const float* __restrict__ W, const float* __restrict__ bnp,
                             const float* __restrict__ b, float* __restrict__ bias2) {
    int n = threadIdx.x;
    float s = b[n];
    for (int k = 0; k < 128; ++k)
        s += bnp[128 + k] * (W[k * 128 + n] - W[2 * 16384 + k * 128 + n]);
    bias2[n] = s;
}

// ---------------- MFMA Cheb GEMM with LDS-staged A --------------------------
// Block = 32 rows x 128 cols, 4 waves 2x2. Wave w stages sel-w table into LDS
// (8 x 16B loads -> ds_writes: loads must all drain before writes, forcing
// 8-deep MLP). Fragments read from padded LDS; B from L2-hot Wt.
template <int ACT, int STATS, int OUTH>
__global__ __launch_bounds__(256)
void gemm_mfma(const __half* __restrict__ T0, const __half* __restrict__ T1,
               const __half* __restrict__ T2, const __half* __restrict__ T3,
               const _Float16* __restrict__ Wt, const float* __restrict__ bias2,
               __half* __restrict__ outh, float* __restrict__ outf,
               float* __restrict__ stats, int N) {
    __shared__ __align__(16) _Float16 As[4][32][136];
    __shared__ float s_sum[128];
    __shared__ float s_sq[128];
    int tid = threadIdx.x;
    int wave = tid >> 6, lane = tid & 63;
    int row0 = blockIdx.x * 32;

    if (STATS && tid < 128) { s_sum[tid] = 0.f; s_sq[tid] = 0.f; }

    // ---- stage A: wave w loads table w (32 rows x 128 ch fp16 = 8 KB) ----
    {
        const __half* Ts[4] = {T0, T1, T2, T3};
        const _Float16* Tp = (const _Float16*)Ts[wave];
        int lr = lane >> 4;           // row-sub 0..3
        int ko = (lane & 15) * 8;     // k offset (halves)
        f16x8 v[8];
#pragma unroll
        for (int t = 0; t < 8; ++t) {
            int gr = min(row0 + t * 4 + lr, N - 1);
            v[t] = *(const f16x8*)(Tp + (size_t)gr * HDIM + ko);
        }
#pragma unroll
        for (int t = 0; t < 8; ++t)
            *(f16x8*)&As[wave][t * 4 + lr][ko] = v[t];
    }
    __syncthreads();

    int wr = wave >> 1, wc = wave & 1;
    int m = lane & 15, quad = lane >> 4;
    int nbase = wc * 64 + m;

    f32x4 acc[4];
#pragma unroll
    for (int ct = 0; ct < 4; ++ct) acc[ct] = (f32x4){0.f, 0.f, 0.f, 0.f};

#pragma unroll
    for (int kt = 0; kt < 4; ++kt) {
#pragma unroll
        for (int sel = 0; sel < 4; ++sel) {
            f16x8 a = *(const f16x8*)&As[sel][wr * 16 + m][kt * 32 + quad * 8];
            int c0 = sel * 16 + kt * 4 + quad;        // k-chunk index
#pragma unroll
            for (int ct = 0; ct < 4; ++ct) {
                f16x8 b0 = *(const f16x8*)(Wt + ((size_t)c0 * 128 + nbase + ct * 16) * 8);
                acc[ct] = __builtin_amdgcn_mfma_f32_16x16x32_f16(a, b0, acc[ct], 0, 0, 0);
            }
        }
    }

    // epilogue: D tile ct: row = row0 + wr*16 + quad*4 + r, col = wc*64 + ct*16 + m
    float csum[4] = {}, csq[4] = {};
#pragma unroll
    for (int ct = 0; ct < 4; ++ct) {
        int col = wc * 64 + ct * 16 + m;
        float bv = bias2[col];
#pragma unroll
        for (int r = 0; r < 4; ++r) {
            int drow = row0 + wr * 16 + quad * 4 + r;
            if (drow < N) {
                float v = acc[ct][r] + bv;
                if (ACT == 1) v = v >= 0.f ? v : 0.01f * v;
                else if (ACT == 2) v = fmaxf(v, 0.f);
                if (OUTH) outh[(size_t)drow * HDIM + col] = __float2half(v);
                else      outf[(size_t)drow * HDIM + col] = v;
                if (STATS) { csum[ct] += v; csq[ct] += v * v; }
            }
        }
    }
    if (STATS) {
#pragma unroll
        for (int ct = 0; ct < 4; ++ct) {
            int col = wc * 64 + ct * 16 + m;
            atomicAdd(&s_sum[col], csum[ct]);
            atomicAdd(&s_sq[col], csq[ct]);
        }
        __syncthreads();
        if (tid < 128) {
            float* sp = stats + (size_t)(blockIdx.x & (NSLOT - 1)) * 256;
            atomicAdd(&sp[tid], s_sum[tid]);
            atomicAdd(&sp[128 + tid], s_sq[tid]);
        }
    }
}

// ---------------- layer-1 (input dim 3) fused GEMM, grid-stride ------------
__global__ __launch_bounds__(256)
void gemm1_kernel(const float* __restrict__ x, const float* __restrict__ t1,
                  const float* __restrict__ t2, const float* __restrict__ t3,
                  const float* __restrict__ W1, const float* __restrict__ b1,
                  __half* __restrict__ out, float* __restrict__ stats, int N) {
    __shared__ float s_sum[128];
    __shared__ float s_sq[128];
    int tid = threadIdx.x;
    int c = tid & 127;
    if (tid < 128) { s_sum[tid] = 0.f; s_sq[tid] = 0.f; }
    __syncthreads();
    float wreg[12];
#pragma unroll
    for (int i = 0; i < 12; ++i) wreg[i] = W1[i * 128 + c];
    float bias = b1[c];
    const float* Ts[4] = {x, t1, t2, t3};
    float lsum = 0.f, lsq = 0.f;
    for (int row = blockIdx.x * 2 + (tid >> 7); row < N; row += gridDim.x * 2) {
        float v = bias;
#pragma unroll
        for (int k = 0; k < 4; ++k) {
            const float* t = Ts[k];
#pragma unroll
            for (int d = 0; d < 3; ++d)
                v += t[row * 3 + d] * wreg[k * 3 + d];
        }
        v = v >= 0.f ? v : 0.01f * v;   // leaky_relu
        out[(size_t)row * HDIM + c] = __float2half(v);
        lsum += v; lsq += v * v;
    }
    atomicAdd(&s_sum[c], lsum);
    atomicAdd(&s_sq[c], lsq);
    __syncthreads();
    if (tid < 128) {
        float* sp = stats + (size_t)(blockIdx.x & (NSLOT - 1)) * 256;
        atomicAdd(&sp[tid], s_sum[tid]);
        atomicAdd(&sp[128 + tid], s_sq[tid]);
    }
}

// ---------------- BN finalize: reduce NSLOT stats copies -> (scale, shift) --
__global__ void bnfin_kernel(const float* __restrict__ stats, const float* __restrict__ g,
                             const float* __restrict__ be, float* __restrict__ bnp, float invN) {
    int c = threadIdx.x;  // 128 threads
    float s0 = 0.f, s1 = 0.f;
#pragma unroll 4
    for (int k = 0; k < NSLOT; ++k) {
        s0 += stats[k * 256 + c];
        s1 += stats[k * 256 + 128 + c];
    }
    float m = s0 * invN;
    float v = s1 * invN - m * m;
    float sc = g[c] * rsqrtf(v + 1e-5f);
    bnp[c] = sc;
    bnp[128 + c] = be[c] - m * sc;
}

// ---------------- final: L2-normalize row + project to 3 ----------------
__global__ void final_kernel(const float* __restrict__ Z, const float* __restrict__ Wm,
                             const float* __restrict__ bm, float* __restrict__ out, int N) {
    int gid = blockIdx.x * blockDim.x + threadIdx.x;
    int node = gid >> 6;
    int lane = threadIdx.x & 63;
    if (node >= N) return;
    const float* z = Z + (size_t)node * HDIM;
    float z0 = z[lane], z1 = z[lane + 64];
    float sq = z0 * z0 + z1 * z1;
    float d0 = z0 * Wm[lane * 3 + 0] + z1 * Wm[(lane + 64) * 3 + 0];
    float d1 = z0 * Wm[lane * 3 + 1] + z1 * Wm[(lane + 64) * 3 + 1];
    float d2 = z0 * Wm[lane * 3 + 2] + z1 * Wm[(lane + 64) * 3 + 2];
#pragma unroll
    for (int off = 32; off > 0; off >>= 1) {
        sq += __shfl_down(sq, off);
        d0 += __shfl_down(d0, off);
        d1 += __shfl_down(d1, off);
        d2 += __shfl_down(d2, off);
    }
    if (lane == 0) {
        float inv = 1.f / fmaxf(sqrtf(sq), 1e-12f);
        out[node * 3 + 0] = d0 * inv + bm[0];
        out[node * 3 + 1] = d1 * inv + bm[1];
        out[node * 3 + 2] = d2 * inv + bm[2];
    }
}

// ---------------- host ----------------

extern "C" void kernel_launch(void* const* d_in, const int* in_sizes, int n_in,
                              void* d_out, int out_size, void* d_ws, size_t ws_size,
                              hipStream_t stream) {
    const float* x  = (const float*)d_in[0];
    const int*   ei = (const int*)d_in[1];
    const float* W1 = (const float*)d_in[2];
    const float* b1 = (const float*)d_in[3];
    const float* W2 = (const float*)d_in[4];
    const float* b2 = (const float*)d_in[5];
    const float* W3 = (const float*)d_in[6];
    const float* b3 = (const float*)d_in[7];
    const float* W4 = (const float*)d_in[8];
    const float* b4 = (const float*)d_in[9];
    const float* g1 = (const float*)d_in[10];
    const float* be1 = (const float*)d_in[11];
    const float* g2 = (const float*)d_in[12];
    const float* be2 = (const float*)d_in[13];
    const float* g3 = (const float*)d_in[14];
    const float* be3 = (const float*)d_in[15];
    const float* Wm = (const float*)d_in[16];
    const float* bm = (const float*)d_in[17];
    float* out = (float*)d_out;

    const int N = in_sizes[0] / 3;
    const int E = in_sizes[1] / 2;
    const size_t NH = (size_t)N * HDIM;
    const int* src = ei;
    const int* dst = ei + E;

    // ---- workspace layout ----
    char* base = (char*)d_ws;
    int* partS  = (int*)base;            base += (size_t)NSLICE * N * 4;
    int* partD  = (int*)base;            base += (size_t)NSLICE * N * 4;
    int* degD   = (int*)base;            base += (size_t)N * 4;
    int* cursor = (int*)base;            base += (size_t)N * 4;
    int* rp     = (int*)base;            base += (size_t)(N + 2) * 4;
    int* bsum   = (int*)base;            base += (size_t)1024 * 4;
    int2* ev    = (int2*)base;           base += (size_t)E * 8;
    float* dinv = (float*)base;          base += (size_t)N * 4;
    __half* Za  = (__half*)base;         base += NH * 2;
    __half* Zb  = (__half*)base;         base += NH * 2;
    __half* T1  = (__half*)base;         base += NH * 2;
    __half* T2  = (__half*)base;         base += NH * 2;
    __half* T3  = (__half*)base;         base += NH * 2;
    float* Zf   = (float*)base;          base += NH * 4;   // layer-4 out, fp32
    float* x1   = (float*)base;          base += (size_t)N * 3 * 4;
    float* x2   = (float*)base;          base += (size_t)N * 3 * 4;
    float* x3   = (float*)base;          base += (size_t)N * 3 * 4;
    float* stats = (float*)base;         base += (size_t)NSLOT * 256 * 4;
    float* bnp1  = (float*)base;         base += 256 * 4;
    float* bnp2  = (float*)base;         base += 256 * 4;
    float* bnp3  = (float*)base;         base += 256 * 4;
    _Float16* Wt = (_Float16*)base;      base += (size_t)65536 * 2;
    float* bias2 = (float*)base;         base += 128 * 4;

    const int EB = (E + 255) / 256;
    const int NB = (N + 255) / 256;
    const int GB = (N + 31) / 32;         // mfma gemm row tiles (32 rows)
    const int PB = (N + 3) / 4;           // pull128 blocks (4 nodes/block)
    const int NSEG = (N + SEGSZ - 1) / SEGSZ;
    const float invN = 1.f / (float)N;
    const size_t STB = (size_t)NSLOT * 256 * 4;

    // --- CSR build + edge weights ---
    hipMemsetAsync(cursor, 0, (size_t)N * 4, stream);
    hist_kernel<<<NSEG * NSLICE, 256, 0, stream>>>(src, dst, partS, partD, NSEG, N, E);
    reduce_kernel<<<NB, 256, 0, stream>>>(partS, partD, dinv, degD, N);
    scanp1_kernel<<<NB, 256, 0, stream>>>(degD, bsum, N);
    scanp2_kernel<<<1, 1024, 0, stream>>>(bsum, NB);
    scanp3_kernel<<<NB, 256, 0, stream>>>(degD, bsum, rp, N, E);
    scatter_kernel<<<EB, 256, 0, stream>>>(src, dst, dinv, rp, cursor, ev, E);

    // --- layer 1 (dim 3) -> Za (fp16), bnp1 ---
    pull3<<<NB, 256, 0, stream>>>(x,  nullptr, rp, ev, x1, 1.f, N);
    pull3<<<NB, 256, 0, stream>>>(x1, x,       rp, ev, x2, 2.f, N);
    pull3<<<NB, 256, 0, stream>>>(x2, x1,      rp, ev, x3, 2.f, N);
    hipMemsetAsync(stats, 0, STB, stream);
    gemm1_kernel<<<512, 256, 0, stream>>>(x, x1, x2, x3, W1, b1, Za, stats, N);
    bnfin_kernel<<<1, 128, 0, stream>>>(stats, g1, be1, bnp1, invN);

    // --- layer 2 (leaky + BN): U-chain from BN(Za,bnp1) -> Zb, bnp2 ---
    wprep_kernel<<<256, 256, 0, stream>>>(W2, bnp1, Wt);
    bias2_kernel<<<1, 128, 0, stream>>>(W2, bnp1, b2, bias2);
    pull128<1><<<PB, 256, 0, stream>>>(Za, rp, ev, bnp1, T1, N);
    pull128<0><<<PB, 256, 0, stream>>>(T1, rp, ev, nullptr, T2, N);
    pull128<0><<<PB, 256, 0, stream>>>(T2, rp, ev, nullptr, T3, N);
    hipMemsetAsync(stats, 0, STB, stream);
    gemm_mfma<1, 1, 1><<<GB, 256, 0, stream>>>(Za, T1, T2, T3, Wt, bias2, Zb, nullptr, stats, N);
    bnfin_kernel<<<1, 128, 0, stream>>>(stats, g2, be2, bnp2, invN);

    // --- layer 3 (relu + BN): U-chain from BN(Zb,bnp2) -> Za, bnp3 ---
    wprep_kernel<<<256, 256, 0, stream>>>(W3, bnp2, Wt);
    bias2_kernel<<<1, 128, 0, stream>>>(W3, bnp2, b3, bias2);
    pull128<1><<<PB, 256, 0, stream>>>(Zb, rp, ev, bnp2, T1, N);
    pull128<0><<<PB, 256, 0, stream>>>(T1, rp, ev, nullptr, T2, N);
    pull128<0><<<PB, 256, 0, stream>>>(T2, rp, ev, nullptr, T3, N);
    hipMemsetAsync(stats, 0, STB, stream);
    gemm_mfma<2, 1, 1><<<GB, 256, 0, stream>>>(Zb, T1, T2, T3, Wt, bias2, Za, nullptr, stats, N);
    bnfin_kernel<<<1, 128, 0, stream>>>(stats, g3, be3, bnp3, invN);

    // --- layer 4 (no act/BN): U-chain from BN(Za,bnp3) -> Zf (fp32) ---
    wprep_kernel<<<256, 256, 0, stream>>>(W4, bnp3, Wt);
    bias2_kernel<<<1, 128, 0, stream>>>(W4, bnp3, b4, bias2);
    pull128<1><<<PB, 256, 0, stream>>>(Za, rp, ev, bnp3, T1, N);
    pull128<0><<<PB, 256, 0, stream>>>(T1, rp, ev, nullptr, T2, N);
    pull128<0><<<PB, 256, 0, stream>>>(T2, rp, ev, nullptr, T3, N);
    gemm_mfma<0, 0, 0><<<GB, 256, 0, stream>>>(Za, T1, T2, T3, Wt, bias2, nullptr, Zf, nullptr, N);

    // --- normalize + project ---
    final_kernel<<<(N * 64 + 255) / 256, 256, 0, stream>>>(Zf, Wm, bm, out, N);
}